// Round 3
// baseline (41461.621 us; speedup 1.0000x reference)
//
#include <hip/hip_runtime.h>

#define VN 512
#define EN 32768
#define FN 8
#define HN 128
#define G3 384
#define LN 3
#define TP 16
#define NROWS (VN*VN)   // 262144

// ---------------- generic int fill ----------------
__global__ void k_fill(int* __restrict__ p, int val, int n) {
    int i = blockIdx.x * 256 + threadIdx.x;
    if (i < n) p[i] = val;
}

// ---------------- edge canonicalize (+ int64 detection) ----------------
__global__ void k_edges(const void* __restrict__ raw, int* __restrict__ uo, int* __restrict__ vo) {
    const int* r32 = (const int*)raw;
    const long long* r64 = (const long long*)raw;
    int acc = 0;
    #pragma unroll
    for (int i = 1; i < 128; i += 2) acc |= r32[i];
    bool is64 = (acc == 0);
    int e = blockIdx.x * 256 + threadIdx.x;
    if (e < EN) {
        int u, v;
        if (is64) { u = (int)r64[2*e]; v = (int)r64[2*e+1]; }
        else      { u = r32[2*e];      v = r32[2*e+1]; }
        uo[e] = u; vo[e] = v;
    }
}

// ---------------- pack Wcat[l][g][k] (k<128:w1, <256:w2, else w3) and Wsum ----------------
__global__ void k_pack(const float* __restrict__ w1, const float* __restrict__ w2,
                       const float* __restrict__ w3, const float* __restrict__ wih,
                       float* __restrict__ wcat, float* __restrict__ wsum) {
    int t = blockIdx.x * 256 + threadIdx.x;
    if (t < 3*128*384) {
        int l = t / (128*384); int rem = t % (128*384);
        int g = rem / 384;     int k = rem % 384;
        const float* w = (k < 128) ? w1 : (k < 256 ? w2 : w3);
        int kk = k & 127;
        wcat[t] = w[((long)l*128 + g)*128 + kk];
    }
    if (t < 384*128) {
        int g = t / 128, k = t % 128;
        wsum[t] = wih[g*256 + k] + wih[g*256 + 128 + k];
    }
}

// ---------------- winner map: map[u*512+v] = max edge id ----------------
__global__ void k_map(const int* __restrict__ uA, const int* __restrict__ vA, int* __restrict__ map) {
    int e = blockIdx.x * 256 + threadIdx.x;
    if (e < EN) atomicMax(&map[uA[e]*VN + vA[e]], e);
}

// ---------------- embed: x[a,b,h] = sum_f adj[a,b,f]*emb[h,f] ----------------
__global__ __launch_bounds__(256) void k_embed(const float* __restrict__ adj,
                                               const float* __restrict__ emb,
                                               float* __restrict__ x) {
    __shared__ float semb[HN][FN];
    __shared__ float sadj[2][FN];
    int tid = threadIdx.x;
    for (int i = tid; i < HN*FN; i += 256) semb[i/FN][i%FN] = emb[i];
    if (tid < 16) sadj[tid>>3][tid&7] = adj[(long)blockIdx.x*16 + tid];
    __syncthreads();
    int p = tid >> 7;
    int h = tid & 127;
    float acc = 0.f;
    #pragma unroll
    for (int f = 0; f < FN; f++) acc += sadj[p][f]*semb[h][f];
    long row = (long)blockIdx.x*2 + p;
    x[row*HN + h] = acc;
}

// ---------------- col_sum[b,h] = sum_a x[a,b,h]; nnz[b] = count over (a,h) ----------------
__global__ __launch_bounds__(512) void k_colsum(const float* __restrict__ x,
                                                float* __restrict__ colsum, int* __restrict__ nnz) {
    int b = blockIdx.x;
    int tid = threadIdx.x;
    int h = tid & 127, q = tid >> 7;
    float s = 0.f; int c = 0;
    for (int a = q*128; a < q*128 + 128; a++) {
        float v = x[((long)a*VN + b)*HN + h];
        s += v; c += (v != 0.f) ? 1 : 0;
    }
    __shared__ float ss[4][128];
    __shared__ int sc[8];
    ss[q][h] = s;
    #pragma unroll
    for (int off = 32; off; off >>= 1) c += __shfl_down(c, off);
    if ((tid & 63) == 0) sc[tid>>6] = c;
    __syncthreads();
    if (tid < 128) colsum[b*HN + tid] = ss[0][tid]+ss[1][tid]+ss[2][tid]+ss[3][tid];
    if (tid == 0) { int t = 0; for (int i = 0; i < 8; i++) t += sc[i]; nnz[b] = t; }
}

// ---------------- per-edge GEMM inputs: in3 = [x_uv, e_in, e_out] ----------------
__global__ __launch_bounds__(256) void k_edgein(const float* __restrict__ x,
    const int* __restrict__ uA, const int* __restrict__ vA,
    const float* __restrict__ colsum, const int* __restrict__ nnz, float* __restrict__ in3) {
    int w = threadIdx.x >> 6;
    int lane = threadIdx.x & 63;
    int e = blockIdx.x*4 + w;
    int u = uA[e], v = vA[e];
    const float* xuv = x + ((long)u*VN + v)*HN;
    const float* xvu = x + ((long)v*VN + u)*HN;
    float xu0 = xuv[lane], xu1 = xuv[lane+64];
    float xv0 = xvu[lane], xv1 = xvu[lane+64];
    int cnt_vu = __popcll(__ballot(xv0 != 0.f)) + __popcll(__ballot(xv1 != 0.f));
    int cnt_uv = __popcll(__ballot(xu0 != 0.f)) + __popcll(__ballot(xu1 != 0.f));
    float nin  = (float)(nnz[u] - cnt_vu) * (1.f/128.f); if (nin  == 0.f) nin  = 1.f;
    float nout = (float)(nnz[v] - cnt_uv) * (1.f/128.f); if (nout == 0.f) nout = 1.f;
    float* o = in3 + (long)e*G3;
    o[lane]        = xu0;  o[lane+64]      = xu1;
    o[128+lane]    = (colsum[u*HN+lane]    - xv0)/nin;
    o[128+lane+64] = (colsum[u*HN+lane+64] - xv1)/nin;
    o[256+lane]    = (colsum[v*HN+lane]    - xu0)/nout;
    o[256+lane+64] = (colsum[v*HN+lane+64] - xu1)/nout;
}

// ---------------- msg GEMM: msg[e][g] = relu(sum_k in3[e][k]*Wcat[g][k]) ----------------
__global__ __launch_bounds__(256) void k_msggemm(const float* __restrict__ in3,
    const float* __restrict__ wcat, float* __restrict__ msg) {
    const int tid = threadIdx.x;
    const int tn = tid & 31;
    const int tm = tid >> 5;
    const long m0 = (long)blockIdx.x * 64;
    __shared__ float As[64][32];
    __shared__ float Bs[128][32];
    float acc[8][4];
    #pragma unroll
    for (int i = 0; i < 8; i++) { acc[i][0]=acc[i][1]=acc[i][2]=acc[i][3]=0.f; }
    for (int kc = 0; kc < 384; kc += 32) {
        #pragma unroll
        for (int i = 0; i < 2; i++) {
            int idx = tid*2 + i;
            int r = idx >> 3, kv = idx & 7;
            *(float4*)&As[r][kv*4] = *(const float4*)&in3[(m0 + r)*G3 + kc + kv*4];
        }
        #pragma unroll
        for (int i = 0; i < 4; i++) {
            int idx = tid*4 + i;
            int gg = idx >> 3, kv = idx & 7;
            float4 t = *(const float4*)&wcat[(long)gg*G3 + kc + kv*4];
            int kvs = kv ^ ((gg>>2)&7);
            *(float4*)&Bs[gg][kvs*4] = t;
        }
        __syncthreads();
        #pragma unroll
        for (int k4 = 0; k4 < 8; k4++) {
            float4 av[8], bv[4];
            #pragma unroll
            for (int i = 0; i < 8; i++) av[i] = *(const float4*)&As[tm*8+i][k4*4];
            #pragma unroll
            for (int j = 0; j < 4; j++) {
                int n = tn*4 + j;
                int kvs = k4 ^ ((n>>2)&7);
                bv[j] = *(const float4*)&Bs[n][kvs*4];
            }
            #pragma unroll
            for (int i = 0; i < 8; i++)
                #pragma unroll
                for (int j = 0; j < 4; j++)
                    acc[i][j] += av[i].x*bv[j].x + av[i].y*bv[j].y + av[i].z*bv[j].z + av[i].w*bv[j].w;
        }
        __syncthreads();
    }
    #pragma unroll
    for (int i = 0; i < 8; i++) {
        long r = m0 + tm*8 + i;
        float4 o;
        o.x = fmaxf(acc[i][0], 0.f); o.y = fmaxf(acc[i][1], 0.f);
        o.z = fmaxf(acc[i][2], 0.f); o.w = fmaxf(acc[i][3], 0.f);
        *(float4*)&msg[r*HN + tn*4] = o;
    }
}

// ---------------- corr[e][g] = (msg[e] - x_uv[e]) @ wl[g]  (wl = wih[:, 0:128]) ----------------
// x_uv[e] == in3[e][0:128], so no gather needed.
__global__ __launch_bounds__(384) void k_corr(const float* __restrict__ in3,
    const float* __restrict__ msg, const float* __restrict__ wih, float* __restrict__ corr) {
    int g = threadIdx.x;
    int eb = blockIdx.x * 16;
    float4 w4[32];
    #pragma unroll
    for (int i = 0; i < 32; i++) w4[i] = *(const float4*)&wih[(long)g*256 + i*4];
    __shared__ float D[16][HN];
    for (int idx = g; idx < 16*HN; idx += 384) {
        int e = idx >> 7, k = idx & 127;
        D[e][k] = msg[(long)(eb+e)*HN + k] - in3[(long)(eb+e)*G3 + k];
    }
    __syncthreads();
    #pragma unroll 4
    for (int e = 0; e < 16; e++) {
        float acc = 0.f;
        #pragma unroll
        for (int k4 = 0; k4 < 32; k4++) {
            float4 d = *(const float4*)&D[e][k4*4];
            acc += d.x*w4[k4].x + d.y*w4[k4].y + d.z*w4[k4].z + d.w*w4[k4].w;
        }
        corr[(long)(eb+e)*G3 + g] = acc;
    }
}

// ---------------- fused xi + GRU scan ----------------
// Block a (512 blocks, 384 threads). Per 16-step panel:
//   stage x rows -> LDS; xi[t'][g] = bih[g] + dot(wsum[g], x_row[t']) (+corr via map);
//   then 16 sequential gate steps (whh row in VGPRs). Writes h over x in place.
__global__ __launch_bounds__(384, 3) void k_scanf(
    float* __restrict__ x, const float* __restrict__ wsum,
    const float* __restrict__ bih, const float* __restrict__ whh,
    const float* __restrict__ bhh, const float* __restrict__ corr,
    const int* __restrict__ map) {
    const int g = threadIdx.x;
    const int a = blockIdx.x;
    float4 w4[32];
    #pragma unroll
    for (int i = 0; i < 32; i++) w4[i] = *(const float4*)&whh[(long)g*HN + i*4];
    const float bh = bhh[g];
    const float bi = bih[g];

    __shared__ float xP[TP][HN];     // 8 KB
    __shared__ float xiP[TP][G3];    // 24 KB
    __shared__ float hS[HN];
    __shared__ float ghS[G3];
    __shared__ int   eS[TP];

    if (g < HN) hS[g] = 0.f;

    float* xbase = x + (long)a*VN*HN;
    const long rowbase = (long)a*VN;
    const float4* wsum4 = (const float4*)(wsum + (long)g*HN);

    for (int p0 = 0; p0 < VN; p0 += TP) {
        // stage x panel (prev panel's gate reads of xiP/xP are behind the last step barrier)
        for (int idx = g; idx < TP*HN/4; idx += 384) {
            ((float4*)xP)[idx] = *(const float4*)&xbase[(long)p0*HN + idx*4];
        }
        if (g < TP) eS[g] = map[rowbase + p0 + g];
        __syncthreads();
        // xi panel GEMM
        #pragma unroll
        for (int tb = 0; tb < TP; tb += 8) {
            float acc[8];
            #pragma unroll
            for (int j = 0; j < 8; j++) acc[j] = bi;
            #pragma unroll
            for (int k4 = 0; k4 < 32; k4++) {
                float4 wv = wsum4[k4];
                #pragma unroll
                for (int j = 0; j < 8; j++) {
                    float4 xv = *(const float4*)&xP[tb+j][k4*4];
                    acc[j] += wv.x*xv.x + wv.y*xv.y + wv.z*xv.z + wv.w*xv.w;
                }
            }
            #pragma unroll
            for (int j = 0; j < 8; j++) {
                int e = eS[tb+j];
                if (e >= 0) acc[j] += corr[(long)e*G3 + g];
                xiP[tb+j][g] = acc[j];
            }
        }
        __syncthreads();
        // sequential gate steps
        for (int t = 0; t < TP; t++) {
            float4 s4 = {0.f, 0.f, 0.f, 0.f};
            #pragma unroll
            for (int k4 = 0; k4 < 32; k4++) {
                float4 hv = *(const float4*)&hS[k4*4];
                s4.x += w4[k4].x*hv.x; s4.y += w4[k4].y*hv.y;
                s4.z += w4[k4].z*hv.z; s4.w += w4[k4].w*hv.w;
            }
            ghS[g] = (s4.x + s4.y) + (s4.z + s4.w) + bh;
            __syncthreads();
            if (g < HN) {
                float hr = ghS[g], hz = ghS[HN+g], hn = ghS[2*HN+g];
                float xr = xiP[t][g], xz = xiP[t][HN+g], xn = xiP[t][2*HN+g];
                float r = 1.f/(1.f + expf(-(xr + hr)));
                float z = 1.f/(1.f + expf(-(xz + hz)));
                float n = tanhf(xn + r*hn);
                float hnew = (1.f - z)*n + z*hS[g];
                hS[g] = hnew;
                xbase[((long)p0 + t)*HN + g] = hnew;
            }
            __syncthreads();
        }
    }
}

extern "C" void kernel_launch(void* const* d_in, const int* in_sizes, int n_in,
                              void* d_out, int out_size, void* d_ws, size_t ws_size,
                              hipStream_t stream) {
    const float* adj   = (const float*)d_in[0];
    const void*  edges = d_in[1];
    const float* emb   = (const float*)d_in[2];
    const float* w1    = (const float*)d_in[3];
    const float* w2    = (const float*)d_in[4];
    const float* w3    = (const float*)d_in[5];
    const float* wih   = (const float*)d_in[6];
    const float* whh   = (const float*)d_in[7];
    const float* bih   = (const float*)d_in[8];
    const float* bhh   = (const float*)d_in[9];

    float* x = (float*)d_out;          // x lives in d_out; scan updates it in place

    char* p = (char*)d_ws;
    auto alloc = [&](size_t bytes) { char* r = p; p += (bytes + 255) & ~255UL; return r; };
    float* in3    = (float*)alloc((size_t)EN*G3*4);        // 50.3 MB
    float* msg    = (float*)alloc((size_t)EN*HN*4);        // 16.8 MB
    float* corr   = (float*)alloc((size_t)EN*G3*4);        // 50.3 MB
    float* colsum = (float*)alloc((size_t)VN*HN*4);
    int*   nnz    = (int*)  alloc((size_t)VN*4);
    int*   map    = (int*)  alloc((size_t)NROWS*4);
    int*   uA     = (int*)  alloc((size_t)EN*4);
    int*   vA     = (int*)  alloc((size_t)EN*4);
    float* wcat   = (float*)alloc((size_t)LN*HN*G3*4);
    float* wsum   = (float*)alloc((size_t)G3*HN*4);

    k_edges<<<EN/256, 256, 0, stream>>>(edges, uA, vA);
    k_pack<<<(3*128*384 + 255)/256, 256, 0, stream>>>(w1, w2, w3, wih, wcat, wsum);
    k_fill<<<NROWS/256, 256, 0, stream>>>(map, -1, NROWS);
    k_map<<<EN/256, 256, 0, stream>>>(uA, vA, map);
    k_embed<<<NROWS/2, 256, 0, stream>>>(adj, emb, x);

    for (int l = 0; l < LN; l++) {
        k_colsum<<<VN, 512, 0, stream>>>(x, colsum, nnz);
        k_edgein<<<EN/4, 256, 0, stream>>>(x, uA, vA, colsum, nnz, in3);
        k_msggemm<<<EN/64, 256, 0, stream>>>(in3, wcat + (long)l*HN*G3, msg);
        k_corr<<<EN/16, 384, 0, stream>>>(in3, msg, wih, corr);
        k_scanf<<<VN, 384, 0, stream>>>(x, wsum, bih, whh, bhh, corr, map);
    }
}

// Round 4
// 10774.332 us; speedup vs baseline: 3.8482x; 3.8482x over previous
//
#include <hip/hip_runtime.h>

#define VN 512
#define EN 32768
#define FN 8
#define HN 128
#define G3 384
#define LN 3
#define TP 16
#define NROWS (VN*VN)   // 262144

// ---------------- generic int fill ----------------
__global__ void k_fill(int* __restrict__ p, int val, int n) {
    int i = blockIdx.x * 256 + threadIdx.x;
    if (i < n) p[i] = val;
}

// ---------------- edge canonicalize (+ int64 detection) ----------------
__global__ void k_edges(const void* __restrict__ raw, int* __restrict__ uo, int* __restrict__ vo) {
    const int* r32 = (const int*)raw;
    const long long* r64 = (const long long*)raw;
    int acc = 0;
    #pragma unroll
    for (int i = 1; i < 128; i += 2) acc |= r32[i];
    bool is64 = (acc == 0);
    int e = blockIdx.x * 256 + threadIdx.x;
    if (e < EN) {
        int u, v;
        if (is64) { u = (int)r64[2*e]; v = (int)r64[2*e+1]; }
        else      { u = r32[2*e];      v = r32[2*e+1]; }
        uo[e] = u; vo[e] = v;
    }
}

// ---------------- pack Wcat[l][g][k] and wsumT[k][g] ----------------
__global__ void k_pack(const float* __restrict__ w1, const float* __restrict__ w2,
                       const float* __restrict__ w3, const float* __restrict__ wih,
                       float* __restrict__ wcat, float* __restrict__ wsumT) {
    int t = blockIdx.x * 256 + threadIdx.x;
    if (t < 3*128*384) {
        int l = t / (128*384); int rem = t % (128*384);
        int g = rem / 384;     int k = rem % 384;
        const float* w = (k < 128) ? w1 : (k < 256 ? w2 : w3);
        int kk = k & 127;
        wcat[t] = w[((long)l*128 + g)*128 + kk];
    }
    if (t < 128*384) {      // wsumT[k][g] = wih[g][k] + wih[g][128+k]
        int k = t / 384, g = t % 384;
        wsumT[t] = wih[g*256 + k] + wih[g*256 + 128 + k];
    }
}

// ---------------- winner map: map[u*512+v] = max edge id ----------------
__global__ void k_map(const int* __restrict__ uA, const int* __restrict__ vA, int* __restrict__ map) {
    int e = blockIdx.x * 256 + threadIdx.x;
    if (e < EN) atomicMax(&map[uA[e]*VN + vA[e]], e);
}

// ---------------- embed: x[a,b,h] = sum_f adj[a,b,f]*emb[h,f] ----------------
__global__ __launch_bounds__(256) void k_embed(const float* __restrict__ adj,
                                               const float* __restrict__ emb,
                                               float* __restrict__ x) {
    __shared__ float semb[HN][FN];
    __shared__ float sadj[2][FN];
    int tid = threadIdx.x;
    for (int i = tid; i < HN*FN; i += 256) semb[i/FN][i%FN] = emb[i];
    if (tid < 16) sadj[tid>>3][tid&7] = adj[(long)blockIdx.x*16 + tid];
    __syncthreads();
    int p = tid >> 7;
    int h = tid & 127;
    float acc = 0.f;
    #pragma unroll
    for (int f = 0; f < FN; f++) acc += sadj[p][f]*semb[h][f];
    long row = (long)blockIdx.x*2 + p;
    x[row*HN + h] = acc;
}

// ---------------- col_sum[b,h] = sum_a x[a,b,h]; nnz[b] = count over (a,h) ----------------
__global__ __launch_bounds__(512) void k_colsum(const float* __restrict__ x,
                                                float* __restrict__ colsum, int* __restrict__ nnz) {
    int b = blockIdx.x;
    int tid = threadIdx.x;
    int h = tid & 127, q = tid >> 7;
    float s = 0.f; int c = 0;
    for (int a = q*128; a < q*128 + 128; a++) {
        float v = x[((long)a*VN + b)*HN + h];
        s += v; c += (v != 0.f) ? 1 : 0;
    }
    __shared__ float ss[4][128];
    __shared__ int sc[8];
    ss[q][h] = s;
    #pragma unroll
    for (int off = 32; off; off >>= 1) c += __shfl_down(c, off);
    if ((tid & 63) == 0) sc[tid>>6] = c;
    __syncthreads();
    if (tid < 128) colsum[b*HN + tid] = ss[0][tid]+ss[1][tid]+ss[2][tid]+ss[3][tid];
    if (tid == 0) { int t = 0; for (int i = 0; i < 8; i++) t += sc[i]; nnz[b] = t; }
}

// ---------------- per-edge GEMM inputs: in3 = [x_uv, e_in, e_out] ----------------
__global__ __launch_bounds__(256) void k_edgein(const float* __restrict__ x,
    const int* __restrict__ uA, const int* __restrict__ vA,
    const float* __restrict__ colsum, const int* __restrict__ nnz, float* __restrict__ in3) {
    int w = threadIdx.x >> 6;
    int lane = threadIdx.x & 63;
    int e = blockIdx.x*4 + w;
    int u = uA[e], v = vA[e];
    const float* xuv = x + ((long)u*VN + v)*HN;
    const float* xvu = x + ((long)v*VN + u)*HN;
    float xu0 = xuv[lane], xu1 = xuv[lane+64];
    float xv0 = xvu[lane], xv1 = xvu[lane+64];
    int cnt_vu = __popcll(__ballot(xv0 != 0.f)) + __popcll(__ballot(xv1 != 0.f));
    int cnt_uv = __popcll(__ballot(xu0 != 0.f)) + __popcll(__ballot(xu1 != 0.f));
    float nin  = (float)(nnz[u] - cnt_vu) * (1.f/128.f); if (nin  == 0.f) nin  = 1.f;
    float nout = (float)(nnz[v] - cnt_uv) * (1.f/128.f); if (nout == 0.f) nout = 1.f;
    float* o = in3 + (long)e*G3;
    o[lane]        = xu0;  o[lane+64]      = xu1;
    o[128+lane]    = (colsum[u*HN+lane]    - xv0)/nin;
    o[128+lane+64] = (colsum[u*HN+lane+64] - xv1)/nin;
    o[256+lane]    = (colsum[v*HN+lane]    - xu0)/nout;
    o[256+lane+64] = (colsum[v*HN+lane+64] - xu1)/nout;
}

// ---------------- msg GEMM: msg[e][g] = relu(sum_k in3[e][k]*Wcat[g][k]) ----------------
__global__ __launch_bounds__(256) void k_msggemm(const float* __restrict__ in3,
    const float* __restrict__ wcat, float* __restrict__ msg) {
    const int tid = threadIdx.x;
    const int tn = tid & 31;
    const int tm = tid >> 5;
    const long m0 = (long)blockIdx.x * 64;
    __shared__ float As[64][32];
    __shared__ float Bs[128][32];
    float acc[8][4];
    #pragma unroll
    for (int i = 0; i < 8; i++) { acc[i][0]=acc[i][1]=acc[i][2]=acc[i][3]=0.f; }
    for (int kc = 0; kc < 384; kc += 32) {
        #pragma unroll
        for (int i = 0; i < 2; i++) {
            int idx = tid*2 + i;
            int r = idx >> 3, kv = idx & 7;
            *(float4*)&As[r][kv*4] = *(const float4*)&in3[(m0 + r)*G3 + kc + kv*4];
        }
        #pragma unroll
        for (int i = 0; i < 4; i++) {
            int idx = tid*4 + i;
            int gg = idx >> 3, kv = idx & 7;
            float4 t = *(const float4*)&wcat[(long)gg*G3 + kc + kv*4];
            int kvs = kv ^ ((gg>>2)&7);
            *(float4*)&Bs[gg][kvs*4] = t;
        }
        __syncthreads();
        #pragma unroll
        for (int k4 = 0; k4 < 8; k4++) {
            float4 av[8], bv[4];
            #pragma unroll
            for (int i = 0; i < 8; i++) av[i] = *(const float4*)&As[tm*8+i][k4*4];
            #pragma unroll
            for (int j = 0; j < 4; j++) {
                int n = tn*4 + j;
                int kvs = k4 ^ ((n>>2)&7);
                bv[j] = *(const float4*)&Bs[n][kvs*4];
            }
            #pragma unroll
            for (int i = 0; i < 8; i++)
                #pragma unroll
                for (int j = 0; j < 4; j++)
                    acc[i][j] += av[i].x*bv[j].x + av[i].y*bv[j].y + av[i].z*bv[j].z + av[i].w*bv[j].w;
        }
        __syncthreads();
    }
    #pragma unroll
    for (int i = 0; i < 8; i++) {
        long r = m0 + tm*8 + i;
        float4 o;
        o.x = fmaxf(acc[i][0], 0.f); o.y = fmaxf(acc[i][1], 0.f);
        o.z = fmaxf(acc[i][2], 0.f); o.w = fmaxf(acc[i][3], 0.f);
        *(float4*)&msg[r*HN + tn*4] = o;
    }
}

// ---------------- corr[e][g] = (msg[e] - x_uv[e]) @ wl[g]  (wl = wih[:, 0:128]) ----------------
__global__ __launch_bounds__(384) void k_corr(const float* __restrict__ in3,
    const float* __restrict__ msg, const float* __restrict__ wih, float* __restrict__ corr) {
    int g = threadIdx.x;
    int eb = blockIdx.x * 16;
    float4 w4[32];
    #pragma unroll
    for (int i = 0; i < 32; i++) w4[i] = *(const float4*)&wih[(long)g*256 + i*4];
    __shared__ float D[16][HN];
    for (int idx = g; idx < 16*HN; idx += 384) {
        int e = idx >> 7, k = idx & 127;
        D[e][k] = msg[(long)(eb+e)*HN + k] - in3[(long)(eb+e)*G3 + k];
    }
    __syncthreads();
    #pragma unroll 4
    for (int e = 0; e < 16; e++) {
        float acc = 0.f;
        #pragma unroll
        for (int k4 = 0; k4 < 32; k4++) {
            float4 d = *(const float4*)&D[e][k4*4];
            acc += d.x*w4[k4].x + d.y*w4[k4].y + d.z*w4[k4].z + d.w*w4[k4].w;
        }
        corr[(long)(eb+e)*G3 + g] = acc;
    }
}

// ---------------- fused xi + GRU scan (v2) ----------------
// Block a (512 blocks, 384 threads). Per 16-step panel:
//   stage x rows -> LDS; cooperative tile GEMM xiP = xP @ wsumT (wsumT k-tiles
//   staged coalesced into LDS; wsT[k][g] reads are bank-conflict-free, xP[t][k]
//   broadcast); add corr via map; then 16 sequential gate steps with whh row
//   in VGPRs. NO launch_bounds min-waves (round-3 spill lesson). Writes h over x.
__global__ __launch_bounds__(384) void k_scanf(
    float* __restrict__ x, const float* __restrict__ wsumT,
    const float* __restrict__ bih, const float* __restrict__ whh,
    const float* __restrict__ bhh, const float* __restrict__ corr,
    const int* __restrict__ map) {
    const int g = threadIdx.x;
    const int a = blockIdx.x;
    float4 w4[32];
    #pragma unroll
    for (int i = 0; i < 32; i++) w4[i] = *(const float4*)&whh[(long)g*HN + i*4];
    const float bh = bhh[g];
    const float bi = bih[g];

    __shared__ float xP[TP][HN];     // 8 KB
    __shared__ float wsT[TP][G3];    // 24 KB
    __shared__ float xiP[TP][G3];    // 24 KB
    __shared__ float hS[HN];
    __shared__ float ghS[G3];
    __shared__ int   eS[TP];

    if (g < HN) hS[g] = 0.f;

    float* xbase = x + (long)a*VN*HN;
    const long rowbase = (long)a*VN;

    for (int p0 = 0; p0 < VN; p0 += TP) {
        // ---- stage x panel (prev panel fully consumed behind last gate barrier) ----
        for (int idx = g; idx < TP*HN/4; idx += 384)
            ((float4*)xP)[idx] = *(const float4*)&xbase[(long)p0*HN + idx*4];
        if (g < TP) eS[g] = map[rowbase + p0 + g];
        __syncthreads();

        // ---- xi panel GEMM: acc[t] = bi + sum_k xP[t][k]*wsumT[k][g] ----
        float acc[TP];
        #pragma unroll
        for (int t = 0; t < TP; t++) acc[t] = bi;
        for (int kc = 0; kc < HN; kc += TP) {
            for (int idx = g; idx < TP*G3/4; idx += 384)
                ((float4*)wsT)[idx] = *(const float4*)&wsumT[(long)kc*G3 + idx*4];
            __syncthreads();
            #pragma unroll
            for (int k = 0; k < TP; k++) {
                float wv = wsT[k][g];
                #pragma unroll
                for (int t = 0; t < TP; t++)
                    acc[t] += xP[t][kc + k] * wv;
            }
            __syncthreads();
        }
        #pragma unroll
        for (int t = 0; t < TP; t++) {
            int e = eS[t];
            float c = (e >= 0) ? corr[(long)e*G3 + g] : 0.f;
            xiP[t][g] = acc[t] + c;
        }
        __syncthreads();

        // ---- sequential gate steps ----
        for (int t = 0; t < TP; t++) {
            float4 s4 = {0.f, 0.f, 0.f, 0.f};
            #pragma unroll
            for (int k4 = 0; k4 < 32; k4++) {
                float4 hv = *(const float4*)&hS[k4*4];
                s4.x += w4[k4].x*hv.x; s4.y += w4[k4].y*hv.y;
                s4.z += w4[k4].z*hv.z; s4.w += w4[k4].w*hv.w;
            }
            ghS[g] = (s4.x + s4.y) + (s4.z + s4.w) + bh;
            __syncthreads();
            if (g < HN) {
                float hr = ghS[g], hz = ghS[HN+g], hn = ghS[2*HN+g];
                float xr = xiP[t][g], xz = xiP[t][HN+g], xn = xiP[t][2*HN+g];
                float r = 1.f/(1.f + expf(-(xr + hr)));
                float z = 1.f/(1.f + expf(-(xz + hz)));
                float n = tanhf(xn + r*hn);
                float hnew = (1.f - z)*n + z*hS[g];
                hS[g] = hnew;
                xbase[((long)p0 + t)*HN + g] = hnew;
            }
            __syncthreads();
        }
    }
}

extern "C" void kernel_launch(void* const* d_in, const int* in_sizes, int n_in,
                              void* d_out, int out_size, void* d_ws, size_t ws_size,
                              hipStream_t stream) {
    const float* adj   = (const float*)d_in[0];
    const void*  edges = d_in[1];
    const float* emb   = (const float*)d_in[2];
    const float* w1    = (const float*)d_in[3];
    const float* w2    = (const float*)d_in[4];
    const float* w3    = (const float*)d_in[5];
    const float* wih   = (const float*)d_in[6];
    const float* whh   = (const float*)d_in[7];
    const float* bih   = (const float*)d_in[8];
    const float* bhh   = (const float*)d_in[9];

    float* x = (float*)d_out;          // x lives in d_out; scan updates it in place

    char* p = (char*)d_ws;
    auto alloc = [&](size_t bytes) { char* r = p; p += (bytes + 255) & ~255UL; return r; };
    float* in3    = (float*)alloc((size_t)EN*G3*4);        // 50.3 MB
    float* msg    = (float*)alloc((size_t)EN*HN*4);        // 16.8 MB
    float* corr   = (float*)alloc((size_t)EN*G3*4);        // 50.3 MB
    float* colsum = (float*)alloc((size_t)VN*HN*4);
    int*   nnz    = (int*)  alloc((size_t)VN*4);
    int*   map    = (int*)  alloc((size_t)NROWS*4);
    int*   uA     = (int*)  alloc((size_t)EN*4);
    int*   vA     = (int*)  alloc((size_t)EN*4);
    float* wcat   = (float*)alloc((size_t)LN*HN*G3*4);
    float* wsumT  = (float*)alloc((size_t)HN*G3*4);

    k_edges<<<EN/256, 256, 0, stream>>>(edges, uA, vA);
    k_pack<<<(3*128*384 + 255)/256, 256, 0, stream>>>(w1, w2, w3, wih, wcat, wsumT);
    k_fill<<<NROWS/256, 256, 0, stream>>>(map, -1, NROWS);
    k_map<<<EN/256, 256, 0, stream>>>(uA, vA, map);
    k_embed<<<NROWS/2, 256, 0, stream>>>(adj, emb, x);

    for (int l = 0; l < LN; l++) {
        k_colsum<<<VN, 512, 0, stream>>>(x, colsum, nnz);
        k_edgein<<<EN/4, 256, 0, stream>>>(x, uA, vA, colsum, nnz, in3);
        k_msggemm<<<EN/64, 256, 0, stream>>>(in3, wcat + (long)l*HN*G3, msg);
        k_corr<<<EN/16, 384, 0, stream>>>(in3, msg, wih, corr);
        k_scanf<<<VN, 384, 0, stream>>>(x, wsumT, bih, whh, bhh, corr, map);
    }
}

// Round 5
// 6381.321 us; speedup vs baseline: 6.4973x; 1.6884x over previous
//
#include <hip/hip_runtime.h>

#define VN 512
#define EN 32768
#define FN 8
#define HN 128
#define G3 384
#define LN 3
#define TP 16
#define NROWS (VN*VN)   // 262144
#define XIPLD 388       // xiP row pad (floats) for LDS bank spread

typedef short bf16x8 __attribute__((ext_vector_type(8)));
typedef float f32x4  __attribute__((ext_vector_type(4)));

__device__ __forceinline__ unsigned short f2bf(float f) {
    unsigned int u = __float_as_uint(f);
    unsigned int r = (u + 0x7FFFu + ((u >> 16) & 1u)) >> 16;
    return (unsigned short)r;
}

// ---------------- generic int fill ----------------
__global__ void k_fill(int* __restrict__ p, int val, int n) {
    int i = blockIdx.x * 256 + threadIdx.x;
    if (i < n) p[i] = val;
}

// ---------------- edge canonicalize (+ int64 detection) ----------------
__global__ void k_edges(const void* __restrict__ raw, int* __restrict__ uo, int* __restrict__ vo) {
    const int* r32 = (const int*)raw;
    const long long* r64 = (const long long*)raw;
    int acc = 0;
    #pragma unroll
    for (int i = 1; i < 128; i += 2) acc |= r32[i];
    bool is64 = (acc == 0);
    int e = blockIdx.x * 256 + threadIdx.x;
    if (e < EN) {
        int u, v;
        if (is64) { u = (int)r64[2*e]; v = (int)r64[2*e+1]; }
        else      { u = r32[2*e];      v = r32[2*e+1]; }
        uo[e] = u; vo[e] = v;
    }
}

// ---------------- pack Wcat[l][g][k]; wsum B-fragments (bf16 hi/lo, MFMA lane layout) ----------------
// wsB layout: [ntile 0..23][ktile 0..3][lane 0..63][elem 0..7]
//   k = kt*32 + (lane>>4)*8 + e ; gcol = nt*16 + (lane&15)
__global__ void k_pack(const float* __restrict__ w1, const float* __restrict__ w2,
                       const float* __restrict__ w3, const float* __restrict__ wih,
                       unsigned short* __restrict__ wsBh, unsigned short* __restrict__ wsBl,
                       float* __restrict__ wcat) {
    int t = blockIdx.x * 256 + threadIdx.x;
    if (t < 3*128*384) {
        int l = t / (128*384); int rem = t % (128*384);
        int g = rem / 384;     int k = rem % 384;
        const float* w = (k < 128) ? w1 : (k < 256 ? w2 : w3);
        int kk = k & 127;
        wcat[t] = w[((long)l*128 + g)*128 + kk];
    }
    if (t < 24*4*64*8) {   // 49152
        int e = t & 7, lane = (t >> 3) & 63, kt = (t >> 9) & 3, nt = t >> 11;
        int k  = kt*32 + (lane >> 4)*8 + e;
        int gc = nt*16 + (lane & 15);
        float val = wih[gc*256 + k] + wih[gc*256 + 128 + k];
        unsigned short hi = f2bf(val);
        float fh = __uint_as_float((unsigned int)hi << 16);
        unsigned short lo = f2bf(val - fh);
        wsBh[t] = hi; wsBl[t] = lo;
    }
}

// ---------------- winner map: map[u*512+v] = max edge id ----------------
__global__ void k_map(const int* __restrict__ uA, const int* __restrict__ vA, int* __restrict__ map) {
    int e = blockIdx.x * 256 + threadIdx.x;
    if (e < EN) atomicMax(&map[uA[e]*VN + vA[e]], e);
}

// ---------------- embed: x[a,b,h] = sum_f adj[a,b,f]*emb[h,f] ----------------
__global__ __launch_bounds__(256) void k_embed(const float* __restrict__ adj,
                                               const float* __restrict__ emb,
                                               float* __restrict__ x) {
    __shared__ float semb[HN][FN];
    __shared__ float sadj[2][FN];
    int tid = threadIdx.x;
    for (int i = tid; i < HN*FN; i += 256) semb[i/FN][i%FN] = emb[i];
    if (tid < 16) sadj[tid>>3][tid&7] = adj[(long)blockIdx.x*16 + tid];
    __syncthreads();
    int p = tid >> 7;
    int h = tid & 127;
    float acc = 0.f;
    #pragma unroll
    for (int f = 0; f < FN; f++) acc += sadj[p][f]*semb[h][f];
    long row = (long)blockIdx.x*2 + p;
    x[row*HN + h] = acc;
}

// ---------------- col_sum[b,h] = sum_a x[a,b,h]; nnz[b] = count over (a,h) ----------------
__global__ __launch_bounds__(512) void k_colsum(const float* __restrict__ x,
                                                float* __restrict__ colsum, int* __restrict__ nnz) {
    int b = blockIdx.x;
    int tid = threadIdx.x;
    int h = tid & 127, q = tid >> 7;
    float s = 0.f; int c = 0;
    for (int a = q*128; a < q*128 + 128; a++) {
        float v = x[((long)a*VN + b)*HN + h];
        s += v; c += (v != 0.f) ? 1 : 0;
    }
    __shared__ float ss[4][128];
    __shared__ int sc[8];
    ss[q][h] = s;
    #pragma unroll
    for (int off = 32; off; off >>= 1) c += __shfl_down(c, off);
    if ((tid & 63) == 0) sc[tid>>6] = c;
    __syncthreads();
    if (tid < 128) colsum[b*HN + tid] = ss[0][tid]+ss[1][tid]+ss[2][tid]+ss[3][tid];
    if (tid == 0) { int t = 0; for (int i = 0; i < 8; i++) t += sc[i]; nnz[b] = t; }
}

// ---------------- per-edge GEMM inputs: in3 = [x_uv, e_in, e_out] ----------------
__global__ __launch_bounds__(256) void k_edgein(const float* __restrict__ x,
    const int* __restrict__ uA, const int* __restrict__ vA,
    const float* __restrict__ colsum, const int* __restrict__ nnz, float* __restrict__ in3) {
    int w = threadIdx.x >> 6;
    int lane = threadIdx.x & 63;
    int e = blockIdx.x*4 + w;
    int u = uA[e], v = vA[e];
    const float* xuv = x + ((long)u*VN + v)*HN;
    const float* xvu = x + ((long)v*VN + u)*HN;
    float xu0 = xuv[lane], xu1 = xuv[lane+64];
    float xv0 = xvu[lane], xv1 = xvu[lane+64];
    int cnt_vu = __popcll(__ballot(xv0 != 0.f)) + __popcll(__ballot(xv1 != 0.f));
    int cnt_uv = __popcll(__ballot(xu0 != 0.f)) + __popcll(__ballot(xu1 != 0.f));
    float nin  = (float)(nnz[u] - cnt_vu) * (1.f/128.f); if (nin  == 0.f) nin  = 1.f;
    float nout = (float)(nnz[v] - cnt_uv) * (1.f/128.f); if (nout == 0.f) nout = 1.f;
    float* o = in3 + (long)e*G3;
    o[lane]        = xu0;  o[lane+64]      = xu1;
    o[128+lane]    = (colsum[u*HN+lane]    - xv0)/nin;
    o[128+lane+64] = (colsum[u*HN+lane+64] - xv1)/nin;
    o[256+lane]    = (colsum[v*HN+lane]    - xu0)/nout;
    o[256+lane+64] = (colsum[v*HN+lane+64] - xu1)/nout;
}

// ---------------- msg GEMM: msg[e][g] = relu(sum_k in3[e][k]*Wcat[g][k]) ----------------
__global__ __launch_bounds__(256) void k_msggemm(const float* __restrict__ in3,
    const float* __restrict__ wcat, float* __restrict__ msg) {
    const int tid = threadIdx.x;
    const int tn = tid & 31;
    const int tm = tid >> 5;
    const long m0 = (long)blockIdx.x * 64;
    __shared__ float As[64][32];
    __shared__ float Bs[128][32];
    float acc[8][4];
    #pragma unroll
    for (int i = 0; i < 8; i++) { acc[i][0]=acc[i][1]=acc[i][2]=acc[i][3]=0.f; }
    for (int kc = 0; kc < 384; kc += 32) {
        #pragma unroll
        for (int i = 0; i < 2; i++) {
            int idx = tid*2 + i;
            int r = idx >> 3, kv = idx & 7;
            *(float4*)&As[r][kv*4] = *(const float4*)&in3[(m0 + r)*G3 + kc + kv*4];
        }
        #pragma unroll
        for (int i = 0; i < 4; i++) {
            int idx = tid*4 + i;
            int gg = idx >> 3, kv = idx & 7;
            float4 t = *(const float4*)&wcat[(long)gg*G3 + kc + kv*4];
            int kvs = kv ^ ((gg>>2)&7);
            *(float4*)&Bs[gg][kvs*4] = t;
        }
        __syncthreads();
        #pragma unroll
        for (int k4 = 0; k4 < 8; k4++) {
            float4 av[8], bv[4];
            #pragma unroll
            for (int i = 0; i < 8; i++) av[i] = *(const float4*)&As[tm*8+i][k4*4];
            #pragma unroll
            for (int j = 0; j < 4; j++) {
                int n = tn*4 + j;
                int kvs = k4 ^ ((n>>2)&7);
                bv[j] = *(const float4*)&Bs[n][kvs*4];
            }
            #pragma unroll
            for (int i = 0; i < 8; i++)
                #pragma unroll
                for (int j = 0; j < 4; j++)
                    acc[i][j] += av[i].x*bv[j].x + av[i].y*bv[j].y + av[i].z*bv[j].z + av[i].w*bv[j].w;
        }
        __syncthreads();
    }
    #pragma unroll
    for (int i = 0; i < 8; i++) {
        long r = m0 + tm*8 + i;
        float4 o;
        o.x = fmaxf(acc[i][0], 0.f); o.y = fmaxf(acc[i][1], 0.f);
        o.z = fmaxf(acc[i][2], 0.f); o.w = fmaxf(acc[i][3], 0.f);
        *(float4*)&msg[r*HN + tn*4] = o;
    }
}

// ---------------- corr[e][g] = (msg[e] - x_uv[e]) @ wl[g]  (wl = wih[:, 0:128]) ----------------
__global__ __launch_bounds__(384) void k_corr(const float* __restrict__ in3,
    const float* __restrict__ msg, const float* __restrict__ wih, float* __restrict__ corr) {
    int g = threadIdx.x;
    int eb = blockIdx.x * 16;
    float4 w4[32];
    #pragma unroll
    for (int i = 0; i < 32; i++) w4[i] = *(const float4*)&wih[(long)g*256 + i*4];
    __shared__ float D[16][HN];
    for (int idx = g; idx < 16*HN; idx += 384) {
        int e = idx >> 7, k = idx & 127;
        D[e][k] = msg[(long)(eb+e)*HN + k] - in3[(long)(eb+e)*G3 + k];
    }
    __syncthreads();
    #pragma unroll 4
    for (int e = 0; e < 16; e++) {
        float acc = 0.f;
        #pragma unroll
        for (int k4 = 0; k4 < 32; k4++) {
            float4 d = *(const float4*)&D[e][k4*4];
            acc += d.x*w4[k4].x + d.y*w4[k4].y + d.z*w4[k4].z + d.w*w4[k4].w;
        }
        corr[(long)(eb+e)*G3 + g] = acc;
    }
}

// ---------------- fused xi(MFMA) + GRU scan (v3) ----------------
// 256 blocks x 384 threads; block owns a-rows {a0, a0+256}. Per 16-step panel:
//   stage x panel as bf16 hi/lo into padded LDS; xi = split-bf16 MFMA (A from LDS,
//   B-fragments precomputed in wsBh/wsBl, streamed from L2); add bias+corr;
//   16 sequential fp32 gate steps with whh row in VGPRs (2 rows/thread -> 2x ILP).
__global__ __launch_bounds__(384, 2) void k_scanf(
    float* __restrict__ x,
    const unsigned short* __restrict__ wsBh, const unsigned short* __restrict__ wsBl,
    const float* __restrict__ bih, const float* __restrict__ whh,
    const float* __restrict__ bhh, const float* __restrict__ corr,
    const int* __restrict__ map) {
    const int g = threadIdx.x;
    const int a0 = blockIdx.x;
    const int wv = g >> 6;
    const int lane = g & 63;
    const int r16 = lane & 15;
    const int kgrp = lane >> 4;

    float4 w4[32];
    #pragma unroll
    for (int i = 0; i < 32; i++) w4[i] = *(const float4*)&whh[(long)g*HN + i*4];
    const float bh = bhh[g];
    const float bi = bih[g];

    __shared__ unsigned short xh[2][TP][136];   // 8704 B
    __shared__ unsigned short xl[2][TP][136];   // 8704 B
    __shared__ float xiP[2][TP][XIPLD];         // 49664 B
    __shared__ float hS[2][HN];
    __shared__ float ghS[2][G3];
    __shared__ int   eS[2][TP];

    if (g < 256) hS[g >> 7][g & 127] = 0.f;

    for (int p0 = 0; p0 < VN; p0 += TP) {
        // ---- stage x panel as bf16 hi/lo (prev panel consumed behind last gate barrier) ----
        for (int idx = g; idx < 2*TP*32; idx += 384) {
            int rs = idx >> 9; int j = idx & 511; int t = j >> 5; int c4 = j & 31;
            float4 v = *(const float4*)&x[((long)(a0 + rs*256)*VN + p0 + t)*HN + c4*4];
            ushort4 h4, l4;
            h4.x = f2bf(v.x); l4.x = f2bf(v.x - __uint_as_float((unsigned int)h4.x << 16));
            h4.y = f2bf(v.y); l4.y = f2bf(v.y - __uint_as_float((unsigned int)h4.y << 16));
            h4.z = f2bf(v.z); l4.z = f2bf(v.z - __uint_as_float((unsigned int)h4.z << 16));
            h4.w = f2bf(v.w); l4.w = f2bf(v.w - __uint_as_float((unsigned int)h4.w << 16));
            *(ushort4*)&xh[rs][t][c4*4] = h4;
            *(ushort4*)&xl[rs][t][c4*4] = l4;
        }
        if (g < 32) eS[g >> 4][g & 15] = map[(long)(a0 + (g >> 4)*256)*VN + p0 + (g & 15)];
        __syncthreads();

        // ---- xi panel via MFMA: wave wv owns n-tiles wv*4..wv*4+3 ----
        {
            f32x4 acc[2][4];
            #pragma unroll
            for (int rs = 0; rs < 2; rs++)
                #pragma unroll
                for (int nt = 0; nt < 4; nt++) acc[rs][nt] = (f32x4){0.f,0.f,0.f,0.f};
            #pragma unroll
            for (int kt = 0; kt < 4; kt++) {
                bf16x8 ah0 = *(const bf16x8*)&xh[0][r16][kt*32 + kgrp*8];
                bf16x8 al0 = *(const bf16x8*)&xl[0][r16][kt*32 + kgrp*8];
                bf16x8 ah1 = *(const bf16x8*)&xh[1][r16][kt*32 + kgrp*8];
                bf16x8 al1 = *(const bf16x8*)&xl[1][r16][kt*32 + kgrp*8];
                #pragma unroll
                for (int nt = 0; nt < 4; nt++) {
                    long bidx = (((long)(wv*4 + nt)*4 + kt)*64 + lane)*8;
                    bf16x8 b_h = *(const bf16x8*)&wsBh[bidx];
                    bf16x8 b_l = *(const bf16x8*)&wsBl[bidx];
                    acc[0][nt] = __builtin_amdgcn_mfma_f32_16x16x32_bf16(ah0, b_h, acc[0][nt], 0, 0, 0);
                    acc[0][nt] = __builtin_amdgcn_mfma_f32_16x16x32_bf16(ah0, b_l, acc[0][nt], 0, 0, 0);
                    acc[0][nt] = __builtin_amdgcn_mfma_f32_16x16x32_bf16(al0, b_h, acc[0][nt], 0, 0, 0);
                    acc[1][nt] = __builtin_amdgcn_mfma_f32_16x16x32_bf16(ah1, b_h, acc[1][nt], 0, 0, 0);
                    acc[1][nt] = __builtin_amdgcn_mfma_f32_16x16x32_bf16(ah1, b_l, acc[1][nt], 0, 0, 0);
                    acc[1][nt] = __builtin_amdgcn_mfma_f32_16x16x32_bf16(al1, b_h, acc[1][nt], 0, 0, 0);
                }
            }
            // C layout (m89-verified): col = lane&15, row = (lane>>4)*4 + r
            #pragma unroll
            for (int rs = 0; rs < 2; rs++)
                #pragma unroll
                for (int nt = 0; nt < 4; nt++)
                    #pragma unroll
                    for (int r = 0; r < 4; r++)
                        xiP[rs][kgrp*4 + r][(wv*4 + nt)*16 + r16] = acc[rs][nt][r];
        }
        __syncthreads();

        // ---- bias + sparse corr ----
        #pragma unroll
        for (int rs = 0; rs < 2; rs++)
            #pragma unroll
            for (int t = 0; t < TP; t++) {
                float vv = xiP[rs][t][g] + bi;
                int e = eS[rs][t];
                if (e >= 0) vv += corr[(long)e*G3 + g];
                xiP[rs][t][g] = vv;
            }
        __syncthreads();

        // ---- sequential gate steps (2 rows per thread) ----
        for (int t = 0; t < TP; t++) {
            float4 s0 = {0.f,0.f,0.f,0.f}, s1 = {0.f,0.f,0.f,0.f};
            #pragma unroll
            for (int k4 = 0; k4 < 32; k4++) {
                float4 h0 = *(const float4*)&hS[0][k4*4];
                float4 h1 = *(const float4*)&hS[1][k4*4];
                s0.x += w4[k4].x*h0.x; s0.y += w4[k4].y*h0.y;
                s0.z += w4[k4].z*h0.z; s0.w += w4[k4].w*h0.w;
                s1.x += w4[k4].x*h1.x; s1.y += w4[k4].y*h1.y;
                s1.z += w4[k4].z*h1.z; s1.w += w4[k4].w*h1.w;
            }
            ghS[0][g] = (s0.x + s0.y) + (s0.z + s0.w) + bh;
            ghS[1][g] = (s1.x + s1.y) + (s1.z + s1.w) + bh;
            __syncthreads();
            if (g < 256) {
                int rs = g >> 7, gg = g & 127;
                float hr = ghS[rs][gg], hz = ghS[rs][HN+gg], hn = ghS[rs][2*HN+gg];
                float xr = xiP[rs][t][gg], xz = xiP[rs][t][HN+gg], xn = xiP[rs][t][2*HN+gg];
                float r = 1.f/(1.f + expf(-(xr + hr)));
                float z = 1.f/(1.f + expf(-(xz + hz)));
                float n = tanhf(xn + r*hn);
                float hnew = (1.f - z)*n + z*hS[rs][gg];
                hS[rs][gg] = hnew;
                x[((long)(a0 + rs*256)*VN + p0 + t)*HN + gg] = hnew;
            }
            __syncthreads();
        }
    }
}

extern "C" void kernel_launch(void* const* d_in, const int* in_sizes, int n_in,
                              void* d_out, int out_size, void* d_ws, size_t ws_size,
                              hipStream_t stream) {
    const float* adj   = (const float*)d_in[0];
    const void*  edges = d_in[1];
    const float* emb   = (const float*)d_in[2];
    const float* w1    = (const float*)d_in[3];
    const float* w2    = (const float*)d_in[4];
    const float* w3    = (const float*)d_in[5];
    const float* wih   = (const float*)d_in[6];
    const float* whh   = (const float*)d_in[7];
    const float* bih   = (const float*)d_in[8];
    const float* bhh   = (const float*)d_in[9];

    float* x = (float*)d_out;          // x lives in d_out; scan updates it in place

    char* p = (char*)d_ws;
    auto alloc = [&](size_t bytes) { char* r = p; p += (bytes + 255) & ~255UL; return r; };
    float* in3    = (float*)alloc((size_t)EN*G3*4);        // 50.3 MB
    float* msg    = (float*)alloc((size_t)EN*HN*4);        // 16.8 MB
    float* corr   = (float*)alloc((size_t)EN*G3*4);        // 50.3 MB
    float* colsum = (float*)alloc((size_t)VN*HN*4);
    int*   nnz    = (int*)  alloc((size_t)VN*4);
    int*   map    = (int*)  alloc((size_t)NROWS*4);
    int*   uA     = (int*)  alloc((size_t)EN*4);
    int*   vA     = (int*)  alloc((size_t)EN*4);
    float* wcat   = (float*)alloc((size_t)LN*HN*G3*4);
    unsigned short* wsBh = (unsigned short*)alloc((size_t)24*4*64*8*2);  // 98.3 KB
    unsigned short* wsBl = (unsigned short*)alloc((size_t)24*4*64*8*2);

    k_edges<<<EN/256, 256, 0, stream>>>(edges, uA, vA);
    k_pack<<<(3*128*384 + 255)/256, 256, 0, stream>>>(w1, w2, w3, wih, wsBh, wsBl, wcat);
    k_fill<<<NROWS/256, 256, 0, stream>>>(map, -1, NROWS);
    k_map<<<EN/256, 256, 0, stream>>>(uA, vA, map);
    k_embed<<<NROWS/2, 256, 0, stream>>>(adj, emb, x);

    for (int l = 0; l < LN; l++) {
        k_colsum<<<VN, 512, 0, stream>>>(x, colsum, nnz);
        k_edgein<<<EN/4, 256, 0, stream>>>(x, uA, vA, colsum, nnz, in3);
        k_msggemm<<<EN/64, 256, 0, stream>>>(in3, wcat + (long)l*HN*G3, msg);
        k_corr<<<EN/16, 384, 0, stream>>>(in3, msg, wih, corr);
        k_scanf<<<VN/2, 384, 0, stream>>>(x, wsBh, wsBl, bih, whh, bhh, corr, map);
    }
}

// Round 6
// 5482.730 us; speedup vs baseline: 7.5622x; 1.1639x over previous
//
#include <hip/hip_runtime.h>

#define VN 512
#define EN 32768
#define FN 8
#define HN 128
#define G3 384
#define LN 3
#define TP 16
#define NROWS (VN*VN)   // 262144
#define XIPLD 392       // xiP row pad (floats): 392%32=8 -> store groups hit disjoint bank ranges

typedef short bf16x8 __attribute__((ext_vector_type(8)));
typedef float f32x4  __attribute__((ext_vector_type(4)));

__device__ __forceinline__ unsigned short f2bf(float f) {
    unsigned int u = __float_as_uint(f);
    unsigned int r = (u + 0x7FFFu + ((u >> 16) & 1u)) >> 16;
    return (unsigned short)r;
}

// ---------------- generic int fill ----------------
__global__ void k_fill(int* __restrict__ p, int val, int n) {
    int i = blockIdx.x * 256 + threadIdx.x;
    if (i < n) p[i] = val;
}

// ---------------- edge canonicalize (+ int64 detection) ----------------
__global__ void k_edges(const void* __restrict__ raw, int* __restrict__ uo, int* __restrict__ vo) {
    const int* r32 = (const int*)raw;
    const long long* r64 = (const long long*)raw;
    int acc = 0;
    #pragma unroll
    for (int i = 1; i < 128; i += 2) acc |= r32[i];
    bool is64 = (acc == 0);
    int e = blockIdx.x * 256 + threadIdx.x;
    if (e < EN) {
        int u, v;
        if (is64) { u = (int)r64[2*e]; v = (int)r64[2*e+1]; }
        else      { u = r32[2*e];      v = r32[2*e+1]; }
        uo[e] = u; vo[e] = v;
    }
}

// ---------------- pack Wcat; wsum + whh B-fragments (bf16 hi/lo, MFMA lane layout) ----------------
// B layout: [ntile][ktile][lane][elem]: k = kt*32 + (lane>>4)*8 + e ; gcol = nt*16 + (lane&15)
__global__ void k_pack(const float* __restrict__ w1, const float* __restrict__ w2,
                       const float* __restrict__ w3, const float* __restrict__ wih,
                       const float* __restrict__ whh,
                       unsigned short* __restrict__ wsBh, unsigned short* __restrict__ wsBl,
                       unsigned short* __restrict__ whBh, unsigned short* __restrict__ whBl,
                       float* __restrict__ wcat) {
    int t = blockIdx.x * 256 + threadIdx.x;
    if (t < 3*128*384) {
        int l = t / (128*384); int rem = t % (128*384);
        int g = rem / 384;     int k = rem % 384;
        const float* w = (k < 128) ? w1 : (k < 256 ? w2 : w3);
        int kk = k & 127;
        wcat[t] = w[((long)l*128 + g)*128 + kk];
    }
    if (t < 24*4*64*8) {   // 49152
        int e = t & 7, lane = (t >> 3) & 63, kt = (t >> 9) & 3, nt = t >> 11;
        int k  = kt*32 + (lane >> 4)*8 + e;
        int gc = nt*16 + (lane & 15);
        // wsum fragment
        float val = wih[gc*256 + k] + wih[gc*256 + 128 + k];
        unsigned short hi = f2bf(val);
        float fh = __uint_as_float((unsigned int)hi << 16);
        unsigned short lo = f2bf(val - fh);
        wsBh[t] = hi; wsBl[t] = lo;
        // whh fragment
        float wv = whh[gc*HN + k];
        unsigned short whi = f2bf(wv);
        float wfh = __uint_as_float((unsigned int)whi << 16);
        unsigned short wlo = f2bf(wv - wfh);
        whBh[t] = whi; whBl[t] = wlo;
    }
}

// ---------------- winner map: map[u*512+v] = max edge id ----------------
__global__ void k_map(const int* __restrict__ uA, const int* __restrict__ vA, int* __restrict__ map) {
    int e = blockIdx.x * 256 + threadIdx.x;
    if (e < EN) atomicMax(&map[uA[e]*VN + vA[e]], e);
}

// ---------------- embed: x[a,b,h] = sum_f adj[a,b,f]*emb[h,f] ----------------
__global__ __launch_bounds__(256) void k_embed(const float* __restrict__ adj,
                                               const float* __restrict__ emb,
                                               float* __restrict__ x) {
    __shared__ float semb[HN][FN];
    __shared__ float sadj[2][FN];
    int tid = threadIdx.x;
    for (int i = tid; i < HN*FN; i += 256) semb[i/FN][i%FN] = emb[i];
    if (tid < 16) sadj[tid>>3][tid&7] = adj[(long)blockIdx.x*16 + tid];
    __syncthreads();
    int p = tid >> 7;
    int h = tid & 127;
    float acc = 0.f;
    #pragma unroll
    for (int f = 0; f < FN; f++) acc += sadj[p][f]*semb[h][f];
    long row = (long)blockIdx.x*2 + p;
    x[row*HN + h] = acc;
}

// ---------------- col_sum[b,h] = sum_a x[a,b,h]; nnz[b] = count over (a,h) ----------------
__global__ __launch_bounds__(512) void k_colsum(const float* __restrict__ x,
                                                float* __restrict__ colsum, int* __restrict__ nnz) {
    int b = blockIdx.x;
    int tid = threadIdx.x;
    int h = tid & 127, q = tid >> 7;
    float s = 0.f; int c = 0;
    for (int a = q*128; a < q*128 + 128; a++) {
        float v = x[((long)a*VN + b)*HN + h];
        s += v; c += (v != 0.f) ? 1 : 0;
    }
    __shared__ float ss[4][128];
    __shared__ int sc[8];
    ss[q][h] = s;
    #pragma unroll
    for (int off = 32; off; off >>= 1) c += __shfl_down(c, off);
    if ((tid & 63) == 0) sc[tid>>6] = c;
    __syncthreads();
    if (tid < 128) colsum[b*HN + tid] = ss[0][tid]+ss[1][tid]+ss[2][tid]+ss[3][tid];
    if (tid == 0) { int t = 0; for (int i = 0; i < 8; i++) t += sc[i]; nnz[b] = t; }
}

// ---------------- per-edge GEMM inputs: in3 = [x_uv, e_in, e_out] ----------------
__global__ __launch_bounds__(256) void k_edgein(const float* __restrict__ x,
    const int* __restrict__ uA, const int* __restrict__ vA,
    const float* __restrict__ colsum, const int* __restrict__ nnz, float* __restrict__ in3) {
    int w = threadIdx.x >> 6;
    int lane = threadIdx.x & 63;
    int e = blockIdx.x*4 + w;
    int u = uA[e], v = vA[e];
    const float* xuv = x + ((long)u*VN + v)*HN;
    const float* xvu = x + ((long)v*VN + u)*HN;
    float xu0 = xuv[lane], xu1 = xuv[lane+64];
    float xv0 = xvu[lane], xv1 = xvu[lane+64];
    int cnt_vu = __popcll(__ballot(xv0 != 0.f)) + __popcll(__ballot(xv1 != 0.f));
    int cnt_uv = __popcll(__ballot(xu0 != 0.f)) + __popcll(__ballot(xu1 != 0.f));
    float nin  = (float)(nnz[u] - cnt_vu) * (1.f/128.f); if (nin  == 0.f) nin  = 1.f;
    float nout = (float)(nnz[v] - cnt_uv) * (1.f/128.f); if (nout == 0.f) nout = 1.f;
    float* o = in3 + (long)e*G3;
    o[lane]        = xu0;  o[lane+64]      = xu1;
    o[128+lane]    = (colsum[u*HN+lane]    - xv0)/nin;
    o[128+lane+64] = (colsum[u*HN+lane+64] - xv1)/nin;
    o[256+lane]    = (colsum[v*HN+lane]    - xu0)/nout;
    o[256+lane+64] = (colsum[v*HN+lane+64] - xu1)/nout;
}

// ---------------- msg GEMM: msg[e][g] = relu(sum_k in3[e][k]*Wcat[g][k]) ----------------
__global__ __launch_bounds__(256) void k_msggemm(const float* __restrict__ in3,
    const float* __restrict__ wcat, float* __restrict__ msg) {
    const int tid = threadIdx.x;
    const int tn = tid & 31;
    const int tm = tid >> 5;
    const long m0 = (long)blockIdx.x * 64;
    __shared__ float As[64][32];
    __shared__ float Bs[128][32];
    float acc[8][4];
    #pragma unroll
    for (int i = 0; i < 8; i++) { acc[i][0]=acc[i][1]=acc[i][2]=acc[i][3]=0.f; }
    for (int kc = 0; kc < 384; kc += 32) {
        #pragma unroll
        for (int i = 0; i < 2; i++) {
            int idx = tid*2 + i;
            int r = idx >> 3, kv = idx & 7;
            *(float4*)&As[r][kv*4] = *(const float4*)&in3[(m0 + r)*G3 + kc + kv*4];
        }
        #pragma unroll
        for (int i = 0; i < 4; i++) {
            int idx = tid*4 + i;
            int gg = idx >> 3, kv = idx & 7;
            float4 t = *(const float4*)&wcat[(long)gg*G3 + kc + kv*4];
            int kvs = kv ^ ((gg>>2)&7);
            *(float4*)&Bs[gg][kvs*4] = t;
        }
        __syncthreads();
        #pragma unroll
        for (int k4 = 0; k4 < 8; k4++) {
            float4 av[8], bv[4];
            #pragma unroll
            for (int i = 0; i < 8; i++) av[i] = *(const float4*)&As[tm*8+i][k4*4];
            #pragma unroll
            for (int j = 0; j < 4; j++) {
                int n = tn*4 + j;
                int kvs = k4 ^ ((n>>2)&7);
                bv[j] = *(const float4*)&Bs[n][kvs*4];
            }
            #pragma unroll
            for (int i = 0; i < 8; i++)
                #pragma unroll
                for (int j = 0; j < 4; j++)
                    acc[i][j] += av[i].x*bv[j].x + av[i].y*bv[j].y + av[i].z*bv[j].z + av[i].w*bv[j].w;
        }
        __syncthreads();
    }
    #pragma unroll
    for (int i = 0; i < 8; i++) {
        long r = m0 + tm*8 + i;
        float4 o;
        o.x = fmaxf(acc[i][0], 0.f); o.y = fmaxf(acc[i][1], 0.f);
        o.z = fmaxf(acc[i][2], 0.f); o.w = fmaxf(acc[i][3], 0.f);
        *(float4*)&msg[r*HN + tn*4] = o;
    }
}

// ---------------- corr[e][g] = (msg[e] - x_uv[e]) @ wl[g]  (wl = wih[:, 0:128]) ----------------
__global__ __launch_bounds__(384) void k_corr(const float* __restrict__ in3,
    const float* __restrict__ msg, const float* __restrict__ wih, float* __restrict__ corr) {
    int g = threadIdx.x;
    int eb = blockIdx.x * 16;
    float4 w4[32];
    #pragma unroll
    for (int i = 0; i < 32; i++) w4[i] = *(const float4*)&wih[(long)g*256 + i*4];
    __shared__ float D[16][HN];
    for (int idx = g; idx < 16*HN; idx += 384) {
        int e = idx >> 7, k = idx & 127;
        D[e][k] = msg[(long)(eb+e)*HN + k] - in3[(long)(eb+e)*G3 + k];
    }
    __syncthreads();
    #pragma unroll 4
    for (int e = 0; e < 16; e++) {
        float acc = 0.f;
        #pragma unroll
        for (int k4 = 0; k4 < 32; k4++) {
            float4 d = *(const float4*)&D[e][k4*4];
            acc += d.x*w4[k4].x + d.y*w4[k4].y + d.z*w4[k4].z + d.w*w4[k4].w;
        }
        corr[(long)(eb+e)*G3 + g] = acc;
    }
}

// ---------------- fused xi(MFMA) + GRU scan (v4: MFMA recurrent dot) ----------------
// 256 blocks x 384 threads; block owns a-rows {a0, a0+256}.
// whh B-fragments resident in VGPRs for the whole kernel; h kept as bf16 hi/lo
// in swizzled LDS (written by gate threads), h_prev fp32 in gate-thread register.
__global__ __launch_bounds__(384, 2) void k_scanf(
    float* __restrict__ x,
    const unsigned short* __restrict__ wsBh, const unsigned short* __restrict__ wsBl,
    const unsigned short* __restrict__ whBh, const unsigned short* __restrict__ whBl,
    const float* __restrict__ bih, const float* __restrict__ bhh,
    const float* __restrict__ corr, const int* __restrict__ map) {
    const int g = threadIdx.x;
    const int a0 = blockIdx.x;
    const int wv = g >> 6;
    const int lane = g & 63;
    const int r16 = lane & 15;
    const int kgrp = lane >> 4;
    const int rsg = g >> 7;        // gate mapping (valid g<256)
    const int gg = g & 127;

    __shared__ unsigned short xh[2][TP][136];   // 8704 B
    __shared__ unsigned short xl[2][TP][136];   // 8704 B
    __shared__ float xiP[2][TP][XIPLD];         // 50176 B
    __shared__ unsigned short hSh[16][HN];      // 4096 B (rows 0,1 live; 2-15 garbage ok)
    __shared__ unsigned short hSl[16][HN];      // 4096 B
    __shared__ float ghS[2][G3];                // 3072 B
    __shared__ int   eS[2][TP];

    const float bi = bih[g];
    const float br = bhh[gg], bz = bhh[HN + gg], bn = bhh[2*HN + gg];
    float hprev = 0.f;

    // permanent whh B fragments (128 VGPRs)
    bf16x8 wBh[16], wBl[16];
    #pragma unroll
    for (int nt = 0; nt < 4; nt++)
        #pragma unroll
        for (int kt = 0; kt < 4; kt++) {
            long bidx = (((long)(wv*4 + nt)*4 + kt)*64 + lane)*8;
            wBh[nt*4 + kt] = *(const bf16x8*)&whBh[bidx];
            wBl[nt*4 + kt] = *(const bf16x8*)&whBl[bidx];
        }

    if (g < HN) { hSh[0][g] = 0; hSh[1][g] = 0; hSl[0][g] = 0; hSl[1][g] = 0; }
    __syncthreads();

    for (int p0 = 0; p0 < VN; p0 += TP) {
        // ---- stage x panel as bf16 hi/lo ----
        for (int idx = g; idx < 2*TP*32; idx += 384) {
            int rs = idx >> 9; int j = idx & 511; int t = j >> 5; int c4 = j & 31;
            float4 v = *(const float4*)&x[((long)(a0 + rs*256)*VN + p0 + t)*HN + c4*4];
            ushort4 h4, l4;
            h4.x = f2bf(v.x); l4.x = f2bf(v.x - __uint_as_float((unsigned int)h4.x << 16));
            h4.y = f2bf(v.y); l4.y = f2bf(v.y - __uint_as_float((unsigned int)h4.y << 16));
            h4.z = f2bf(v.z); l4.z = f2bf(v.z - __uint_as_float((unsigned int)h4.z << 16));
            h4.w = f2bf(v.w); l4.w = f2bf(v.w - __uint_as_float((unsigned int)h4.w << 16));
            *(ushort4*)&xh[rs][t][c4*4] = h4;
            *(ushort4*)&xl[rs][t][c4*4] = l4;
        }
        if (g < 32) eS[g >> 4][g & 15] = map[(long)(a0 + (g >> 4)*256)*VN + p0 + (g & 15)];
        __syncthreads();

        // ---- xi panel via MFMA (wsB streamed from L2) ----
        {
            f32x4 acc[2][4];
            #pragma unroll
            for (int rs = 0; rs < 2; rs++)
                #pragma unroll
                for (int nt = 0; nt < 4; nt++) acc[rs][nt] = (f32x4){0.f,0.f,0.f,0.f};
            #pragma unroll
            for (int kt = 0; kt < 4; kt++) {
                bf16x8 ah0 = *(const bf16x8*)&xh[0][r16][kt*32 + kgrp*8];
                bf16x8 al0 = *(const bf16x8*)&xl[0][r16][kt*32 + kgrp*8];
                bf16x8 ah1 = *(const bf16x8*)&xh[1][r16][kt*32 + kgrp*8];
                bf16x8 al1 = *(const bf16x8*)&xl[1][r16][kt*32 + kgrp*8];
                #pragma unroll
                for (int nt = 0; nt < 4; nt++) {
                    long bidx = (((long)(wv*4 + nt)*4 + kt)*64 + lane)*8;
                    bf16x8 b_h = *(const bf16x8*)&wsBh[bidx];
                    bf16x8 b_l = *(const bf16x8*)&wsBl[bidx];
                    acc[0][nt] = __builtin_amdgcn_mfma_f32_16x16x32_bf16(ah0, b_h, acc[0][nt], 0, 0, 0);
                    acc[0][nt] = __builtin_amdgcn_mfma_f32_16x16x32_bf16(ah0, b_l, acc[0][nt], 0, 0, 0);
                    acc[0][nt] = __builtin_amdgcn_mfma_f32_16x16x32_bf16(al0, b_h, acc[0][nt], 0, 0, 0);
                    acc[1][nt] = __builtin_amdgcn_mfma_f32_16x16x32_bf16(ah1, b_h, acc[1][nt], 0, 0, 0);
                    acc[1][nt] = __builtin_amdgcn_mfma_f32_16x16x32_bf16(ah1, b_l, acc[1][nt], 0, 0, 0);
                    acc[1][nt] = __builtin_amdgcn_mfma_f32_16x16x32_bf16(al1, b_h, acc[1][nt], 0, 0, 0);
                }
            }
            // C layout: col = lane&15, row = (lane>>4)*4 + r
            #pragma unroll
            for (int rs = 0; rs < 2; rs++)
                #pragma unroll
                for (int nt = 0; nt < 4; nt++)
                    #pragma unroll
                    for (int r = 0; r < 4; r++)
                        xiP[rs][kgrp*4 + r][(wv*4 + nt)*16 + r16] = acc[rs][nt][r];
        }
        __syncthreads();

        // ---- bias + sparse corr ----
        #pragma unroll
        for (int rs = 0; rs < 2; rs++)
            #pragma unroll
            for (int t = 0; t < TP; t++) {
                float vv = xiP[rs][t][g] + bi;
                int e = eS[rs][t];
                if (e >= 0) vv += corr[(long)e*G3 + g];
                xiP[rs][t][g] = vv;
            }
        __syncthreads();

        // ---- 16 sequential gate steps; gh via MFMA (whh frags in VGPRs) ----
        for (int t = 0; t < TP; t++) {
            f32x4 gacc[4];
            #pragma unroll
            for (int nt = 0; nt < 4; nt++) gacc[nt] = (f32x4){0.f,0.f,0.f,0.f};
            #pragma unroll
            for (int kt = 0; kt < 4; kt++) {
                int k0 = (kt*32 + kgrp*8) ^ ((r16 & 7) << 3);   // XOR bank swizzle
                bf16x8 ah = *(const bf16x8*)&hSh[r16][k0];
                bf16x8 al = *(const bf16x8*)&hSl[r16][k0];
                #pragma unroll
                for (int nt = 0; nt < 4; nt++) {
                    gacc[nt] = __builtin_amdgcn_mfma_f32_16x16x32_bf16(ah, wBh[nt*4 + kt], gacc[nt], 0, 0, 0);
                    gacc[nt] = __builtin_amdgcn_mfma_f32_16x16x32_bf16(ah, wBl[nt*4 + kt], gacc[nt], 0, 0, 0);
                    gacc[nt] = __builtin_amdgcn_mfma_f32_16x16x32_bf16(al, wBh[nt*4 + kt], gacc[nt], 0, 0, 0);
                }
            }
            // rows 0,1 of C live in lanes 0-15 (kgrp==0), regs 0,1
            if (lane < 16) {
                #pragma unroll
                for (int nt = 0; nt < 4; nt++) {
                    ghS[0][(wv*4 + nt)*16 + lane] = gacc[nt][0];
                    ghS[1][(wv*4 + nt)*16 + lane] = gacc[nt][1];
                }
            }
            __syncthreads();
            if (g < 256) {
                float hr = ghS[rsg][gg] + br;
                float hz = ghS[rsg][HN + gg] + bz;
                float hn = ghS[rsg][2*HN + gg] + bn;
                float xr = xiP[rsg][t][gg], xz = xiP[rsg][t][HN + gg], xn = xiP[rsg][t][2*HN + gg];
                float r = 1.f/(1.f + expf(-(xr + hr)));
                float z = 1.f/(1.f + expf(-(xz + hz)));
                float n = tanhf(xn + r*hn);
                float hnew = (1.f - z)*n + z*hprev;
                hprev = hnew;
                x[((long)(a0 + rsg*256)*VN + p0 + t)*HN + gg] = hnew;
                unsigned short hi = f2bf(hnew);
                unsigned short lo = f2bf(hnew - __uint_as_float((unsigned int)hi << 16));
                int kw = gg ^ (rsg << 3);                        // matches read swizzle
                hSh[rsg][kw] = hi;
                hSl[rsg][kw] = lo;
            }
            __syncthreads();
        }
    }
}

extern "C" void kernel_launch(void* const* d_in, const int* in_sizes, int n_in,
                              void* d_out, int out_size, void* d_ws, size_t ws_size,
                              hipStream_t stream) {
    const float* adj   = (const float*)d_in[0];
    const void*  edges = d_in[1];
    const float* emb   = (const float*)d_in[2];
    const float* w1    = (const float*)d_in[3];
    const float* w2    = (const float*)d_in[4];
    const float* w3    = (const float*)d_in[5];
    const float* wih   = (const float*)d_in[6];
    const float* whh   = (const float*)d_in[7];
    const float* bih   = (const float*)d_in[8];
    const float* bhh   = (const float*)d_in[9];

    float* x = (float*)d_out;          // x lives in d_out; scan updates it in place

    char* p = (char*)d_ws;
    auto alloc = [&](size_t bytes) { char* r = p; p += (bytes + 255) & ~255UL; return r; };
    float* in3    = (float*)alloc((size_t)EN*G3*4);        // 50.3 MB
    float* msg    = (float*)alloc((size_t)EN*HN*4);        // 16.8 MB
    float* corr   = (float*)alloc((size_t)EN*G3*4);        // 50.3 MB
    float* colsum = (float*)alloc((size_t)VN*HN*4);
    int*   nnz    = (int*)  alloc((size_t)VN*4);
    int*   map    = (int*)  alloc((size_t)NROWS*4);
    int*   uA     = (int*)  alloc((size_t)EN*4);
    int*   vA     = (int*)  alloc((size_t)EN*4);
    float* wcat   = (float*)alloc((size_t)LN*HN*G3*4);
    unsigned short* wsBh = (unsigned short*)alloc((size_t)24*4*64*8*2);  // 98.3 KB
    unsigned short* wsBl = (unsigned short*)alloc((size_t)24*4*64*8*2);
    unsigned short* whBh = (unsigned short*)alloc((size_t)24*4*64*8*2);
    unsigned short* whBl = (unsigned short*)alloc((size_t)24*4*64*8*2);

    k_edges<<<EN/256, 256, 0, stream>>>(edges, uA, vA);
    k_pack<<<(3*128*384 + 255)/256, 256, 0, stream>>>(w1, w2, w3, wih, whh, wsBh, wsBl, whBh, whBl, wcat);
    k_fill<<<NROWS/256, 256, 0, stream>>>(map, -1, NROWS);
    k_map<<<EN/256, 256, 0, stream>>>(uA, vA, map);
    k_embed<<<NROWS/2, 256, 0, stream>>>(adj, emb, x);

    for (int l = 0; l < LN; l++) {
        k_colsum<<<VN, 512, 0, stream>>>(x, colsum, nnz);
        k_edgein<<<EN/4, 256, 0, stream>>>(x, uA, vA, colsum, nnz, in3);
        k_msggemm<<<EN/64, 256, 0, stream>>>(in3, wcat + (long)l*HN*G3, msg);
        k_corr<<<EN/16, 384, 0, stream>>>(in3, msg, wih, corr);
        k_scanf<<<VN/2, 384, 0, stream>>>(x, wsBh, wsBl, whBh, whBl, bih, bhh, corr, map);
    }
}

// Round 7
// 5049.076 us; speedup vs baseline: 8.2117x; 1.0859x over previous
//
#include <hip/hip_runtime.h>

#define VN 512
#define EN 32768
#define FN 8
#define HN 128
#define G3 384
#define LN 3
#define TP 16
#define NROWS (VN*VN)   // 262144
#define XIPAD 388       // 4*388 % 32 == 16 -> xiP stores are 2-way (free)

typedef short bf16x8 __attribute__((ext_vector_type(8)));
typedef float f32x4  __attribute__((ext_vector_type(4)));

__device__ __forceinline__ unsigned short f2bf(float f) {
    unsigned int u = __float_as_uint(f);
    unsigned int r = (u + 0x7FFFu + ((u >> 16) & 1u)) >> 16;
    return (unsigned short)r;
}

// ---------------- generic int fill ----------------
__global__ void k_fill(int* __restrict__ p, int val, int n) {
    int i = blockIdx.x * 256 + threadIdx.x;
    if (i < n) p[i] = val;
}

// ---------------- edge canonicalize (+ int64 detection) ----------------
__global__ void k_edges(const void* __restrict__ raw, int* __restrict__ uo, int* __restrict__ vo) {
    const int* r32 = (const int*)raw;
    const long long* r64 = (const long long*)raw;
    int acc = 0;
    #pragma unroll
    for (int i = 1; i < 128; i += 2) acc |= r32[i];
    bool is64 = (acc == 0);
    int e = blockIdx.x * 256 + threadIdx.x;
    if (e < EN) {
        int u, v;
        if (is64) { u = (int)r64[2*e]; v = (int)r64[2*e+1]; }
        else      { u = r32[2*e];      v = r32[2*e+1]; }
        uo[e] = u; vo[e] = v;
    }
}

// ---------------- pack Wcat; wsum + whh B-fragments (bf16 hi/lo, MFMA lane layout) ----------------
// B layout: [ntile][ktile][lane][elem]: k = kt*32 + (lane>>4)*8 + e ; gcol = nt*16 + (lane&15)
__global__ void k_pack(const float* __restrict__ w1, const float* __restrict__ w2,
                       const float* __restrict__ w3, const float* __restrict__ wih,
                       const float* __restrict__ whh,
                       unsigned short* __restrict__ wsBh, unsigned short* __restrict__ wsBl,
                       unsigned short* __restrict__ whBh, unsigned short* __restrict__ whBl,
                       float* __restrict__ wcat) {
    int t = blockIdx.x * 256 + threadIdx.x;
    if (t < 3*128*384) {
        int l = t / (128*384); int rem = t % (128*384);
        int g = rem / 384;     int k = rem % 384;
        const float* w = (k < 128) ? w1 : (k < 256 ? w2 : w3);
        int kk = k & 127;
        wcat[t] = w[((long)l*128 + g)*128 + kk];
    }
    if (t < 24*4*64*8) {   // 49152
        int e = t & 7, lane = (t >> 3) & 63, kt = (t >> 9) & 3, nt = t >> 11;
        int k  = kt*32 + (lane >> 4)*8 + e;
        int gc = nt*16 + (lane & 15);
        float val = wih[gc*256 + k] + wih[gc*256 + 128 + k];
        unsigned short hi = f2bf(val);
        float fh = __uint_as_float((unsigned int)hi << 16);
        unsigned short lo = f2bf(val - fh);
        wsBh[t] = hi; wsBl[t] = lo;
        float wv = whh[gc*HN + k];
        unsigned short whi = f2bf(wv);
        float wfh = __uint_as_float((unsigned int)whi << 16);
        unsigned short wlo = f2bf(wv - wfh);
        whBh[t] = whi; whBl[t] = wlo;
    }
}

// ---------------- winner map: map[u*512+v] = max edge id ----------------
__global__ void k_map(const int* __restrict__ uA, const int* __restrict__ vA, int* __restrict__ map) {
    int e = blockIdx.x * 256 + threadIdx.x;
    if (e < EN) atomicMax(&map[uA[e]*VN + vA[e]], e);
}

// ---------------- embed: x[a,b,h] = sum_f adj[a,b,f]*emb[h,f] ----------------
__global__ __launch_bounds__(256) void k_embed(const float* __restrict__ adj,
                                               const float* __restrict__ emb,
                                               float* __restrict__ x) {
    __shared__ float semb[HN][FN];
    __shared__ float sadj[2][FN];
    int tid = threadIdx.x;
    for (int i = tid; i < HN*FN; i += 256) semb[i/FN][i%FN] = emb[i];
    if (tid < 16) sadj[tid>>3][tid&7] = adj[(long)blockIdx.x*16 + tid];
    __syncthreads();
    int p = tid >> 7;
    int h = tid & 127;
    float acc = 0.f;
    #pragma unroll
    for (int f = 0; f < FN; f++) acc += sadj[p][f]*semb[h][f];
    long row = (long)blockIdx.x*2 + p;
    x[row*HN + h] = acc;
}

// ---------------- col_sum[b,h] = sum_a x[a,b,h]; nnz[b] = count over (a,h) ----------------
__global__ __launch_bounds__(512) void k_colsum(const float* __restrict__ x,
                                                float* __restrict__ colsum, int* __restrict__ nnz) {
    int b = blockIdx.x;
    int tid = threadIdx.x;
    int h = tid & 127, q = tid >> 7;
    float s = 0.f; int c = 0;
    for (int a = q*128; a < q*128 + 128; a++) {
        float v = x[((long)a*VN + b)*HN + h];
        s += v; c += (v != 0.f) ? 1 : 0;
    }
    __shared__ float ss[4][128];
    __shared__ int sc[8];
    ss[q][h] = s;
    #pragma unroll
    for (int off = 32; off; off >>= 1) c += __shfl_down(c, off);
    if ((tid & 63) == 0) sc[tid>>6] = c;
    __syncthreads();
    if (tid < 128) colsum[b*HN + tid] = ss[0][tid]+ss[1][tid]+ss[2][tid]+ss[3][tid];
    if (tid == 0) { int t = 0; for (int i = 0; i < 8; i++) t += sc[i]; nnz[b] = t; }
}

// ---------------- per-edge GEMM inputs: in3 = [x_uv, e_in, e_out] ----------------
__global__ __launch_bounds__(256) void k_edgein(const float* __restrict__ x,
    const int* __restrict__ uA, const int* __restrict__ vA,
    const float* __restrict__ colsum, const int* __restrict__ nnz, float* __restrict__ in3) {
    int w = threadIdx.x >> 6;
    int lane = threadIdx.x & 63;
    int e = blockIdx.x*4 + w;
    int u = uA[e], v = vA[e];
    const float* xuv = x + ((long)u*VN + v)*HN;
    const float* xvu = x + ((long)v*VN + u)*HN;
    float xu0 = xuv[lane], xu1 = xuv[lane+64];
    float xv0 = xvu[lane], xv1 = xvu[lane+64];
    int cnt_vu = __popcll(__ballot(xv0 != 0.f)) + __popcll(__ballot(xv1 != 0.f));
    int cnt_uv = __popcll(__ballot(xu0 != 0.f)) + __popcll(__ballot(xu1 != 0.f));
    float nin  = (float)(nnz[u] - cnt_vu) * (1.f/128.f); if (nin  == 0.f) nin  = 1.f;
    float nout = (float)(nnz[v] - cnt_uv) * (1.f/128.f); if (nout == 0.f) nout = 1.f;
    float* o = in3 + (long)e*G3;
    o[lane]        = xu0;  o[lane+64]      = xu1;
    o[128+lane]    = (colsum[u*HN+lane]    - xv0)/nin;
    o[128+lane+64] = (colsum[u*HN+lane+64] - xv1)/nin;
    o[256+lane]    = (colsum[v*HN+lane]    - xu0)/nout;
    o[256+lane+64] = (colsum[v*HN+lane+64] - xu1)/nout;
}

// ---------------- msg GEMM: msg[e][g] = relu(sum_k in3[e][k]*Wcat[g][k]) ----------------
__global__ __launch_bounds__(256) void k_msggemm(const float* __restrict__ in3,
    const float* __restrict__ wcat, float* __restrict__ msg) {
    const int tid = threadIdx.x;
    const int tn = tid & 31;
    const int tm = tid >> 5;
    const long m0 = (long)blockIdx.x * 64;
    __shared__ float As[64][32];
    __shared__ float Bs[128][32];
    float acc[8][4];
    #pragma unroll
    for (int i = 0; i < 8; i++) { acc[i][0]=acc[i][1]=acc[i][2]=acc[i][3]=0.f; }
    for (int kc = 0; kc < 384; kc += 32) {
        #pragma unroll
        for (int i = 0; i < 2; i++) {
            int idx = tid*2 + i;
            int r = idx >> 3, kv = idx & 7;
            *(float4*)&As[r][kv*4] = *(const float4*)&in3[(m0 + r)*G3 + kc + kv*4];
        }
        #pragma unroll
        for (int i = 0; i < 4; i++) {
            int idx = tid*4 + i;
            int gg = idx >> 3, kv = idx & 7;
            float4 t = *(const float4*)&wcat[(long)gg*G3 + kc + kv*4];
            int kvs = kv ^ ((gg>>2)&7);
            *(float4*)&Bs[gg][kvs*4] = t;
        }
        __syncthreads();
        #pragma unroll
        for (int k4 = 0; k4 < 8; k4++) {
            float4 av[8], bv[4];
            #pragma unroll
            for (int i = 0; i < 8; i++) av[i] = *(const float4*)&As[tm*8+i][k4*4];
            #pragma unroll
            for (int j = 0; j < 4; j++) {
                int n = tn*4 + j;
                int kvs = k4 ^ ((n>>2)&7);
                bv[j] = *(const float4*)&Bs[n][kvs*4];
            }
            #pragma unroll
            for (int i = 0; i < 8; i++)
                #pragma unroll
                for (int j = 0; j < 4; j++)
                    acc[i][j] += av[i].x*bv[j].x + av[i].y*bv[j].y + av[i].z*bv[j].z + av[i].w*bv[j].w;
        }
        __syncthreads();
    }
    #pragma unroll
    for (int i = 0; i < 8; i++) {
        long r = m0 + tm*8 + i;
        float4 o;
        o.x = fmaxf(acc[i][0], 0.f); o.y = fmaxf(acc[i][1], 0.f);
        o.z = fmaxf(acc[i][2], 0.f); o.w = fmaxf(acc[i][3], 0.f);
        *(float4*)&msg[r*HN + tn*4] = o;
    }
}

// ---------------- corr[e][g] = (msg[e] - x_uv[e]) @ wl[g]  (wl = wih[:, 0:128]) ----------------
__global__ __launch_bounds__(384) void k_corr(const float* __restrict__ in3,
    const float* __restrict__ msg, const float* __restrict__ wih, float* __restrict__ corr) {
    int g = threadIdx.x;
    int eb = blockIdx.x * 16;
    float4 w4[32];
    #pragma unroll
    for (int i = 0; i < 32; i++) w4[i] = *(const float4*)&wih[(long)g*256 + i*4];
    __shared__ float D[16][HN];
    for (int idx = g; idx < 16*HN; idx += 384) {
        int e = idx >> 7, k = idx & 127;
        D[e][k] = msg[(long)(eb+e)*HN + k] - in3[(long)(eb+e)*G3 + k];
    }
    __syncthreads();
    #pragma unroll 4
    for (int e = 0; e < 16; e++) {
        float acc = 0.f;
        #pragma unroll
        for (int k4 = 0; k4 < 32; k4++) {
            float4 d = *(const float4*)&D[e][k4*4];
            acc += d.x*w4[k4].x + d.y*w4[k4].y + d.z*w4[k4].z + d.w*w4[k4].w;
        }
        corr[(long)(eb+e)*G3 + g] = acc;
    }
}

// ---------------- fused xi(MFMA) + GRU scan (v5: per-wave gate ownership) ----------------
// 256 blocks x 512 threads (8 waves); block owns chains {a0, a0+256}.
// Wave wv owns output cols [wv*16, wv*16+16) of ALL THREE gates (nt = wv, 8+wv, 16+wv).
// gh MFMA result rows 0/1 (= the 2 chains) land in lanes 0-15 of the owning wave ->
// gate math fully in-register; h goes through parity-double-buffered bf16 LDS;
// ONE barrier per step; no global ops inside steps (hOut written back per panel).
__global__ __launch_bounds__(512) void k_scanf(
    float* __restrict__ x,
    const unsigned short* __restrict__ wsBh, const unsigned short* __restrict__ wsBl,
    const unsigned short* __restrict__ whBh, const unsigned short* __restrict__ whBl,
    const float* __restrict__ bih, const float* __restrict__ bhh,
    const float* __restrict__ corr, const int* __restrict__ map) {
    const int g = threadIdx.x;          // 0..511
    const int a0 = blockIdx.x;
    const int wv = g >> 6;              // 0..7
    const int lane = g & 63;
    const int r16 = lane & 15;
    const int kgrp = lane >> 4;

    __shared__ unsigned short xh[2][TP][136];   // 8704 B
    __shared__ unsigned short xl[2][TP][136];   // 8704 B
    __shared__ float xiP[2][TP][XIPAD];         // 49664 B
    __shared__ unsigned short hSh[2][2][HN];    // [parity][chain][col] 1024 B
    __shared__ unsigned short hSl[2][2][HN];    // 1024 B
    __shared__ float hOut[2][TP][HN];           // 16384 B
    __shared__ int   eS[2][TP];

    // resident whh B-frags: [gate 0..2][kt 0..3] hi/lo = 96 VGPRs
    bf16x8 wBh[12], wBl[12];
    #pragma unroll
    for (int gi = 0; gi < 3; gi++)
        #pragma unroll
        for (int kt = 0; kt < 4; kt++) {
            long bidx = (((long)(gi*8 + wv)*4 + kt)*64 + lane)*8;
            wBh[gi*4+kt] = *(const bf16x8*)&whBh[bidx];
            wBl[gi*4+kt] = *(const bf16x8*)&whBl[bidx];
        }

    const int c = wv*16 + r16;                  // this lane's gate column
    const float br = bhh[c],  bz = bhh[HN + c],  bn = bhh[2*HN + c];
    const float biR = bih[c], biZ = bih[HN + c], biN = bih[2*HN + c];
    float hprev0 = 0.f, hprev1 = 0.f;

    if (g < 2*HN) {                             // zero parity-0 h buffers
        ((unsigned short*)hSh)[g] = 0;
        ((unsigned short*)hSl)[g] = 0;
    }
    int cur = 0;
    __syncthreads();

    for (int p0 = 0; p0 < VN; p0 += TP) {
        // ---- phase A: write back prev panel's h; stage current x panel (bf16 hi/lo); eS ----
        if (p0 > 0) {
            int pp = p0 - TP;
            for (int idx = g; idx < 2*TP*32; idx += 512) {
                int rs = idx >> 9, j = idx & 511, t = j >> 5, c4 = j & 31;
                *(float4*)&x[((long)(a0 + rs*256)*VN + pp + t)*HN + c4*4] =
                    *(const float4*)&hOut[rs][t][c4*4];
            }
        }
        for (int idx = g; idx < 2*TP*32; idx += 512) {
            int rs = idx >> 9, j = idx & 511, t = j >> 5, c4 = j & 31;
            float4 v = *(const float4*)&x[((long)(a0 + rs*256)*VN + p0 + t)*HN + c4*4];
            ushort4 h4, l4;
            h4.x = f2bf(v.x); l4.x = f2bf(v.x - __uint_as_float((unsigned int)h4.x << 16));
            h4.y = f2bf(v.y); l4.y = f2bf(v.y - __uint_as_float((unsigned int)h4.y << 16));
            h4.z = f2bf(v.z); l4.z = f2bf(v.z - __uint_as_float((unsigned int)h4.z << 16));
            h4.w = f2bf(v.w); l4.w = f2bf(v.w - __uint_as_float((unsigned int)h4.w << 16));
            *(ushort4*)&xh[rs][t][c4*4] = h4;
            *(ushort4*)&xl[rs][t][c4*4] = l4;
        }
        if (g < 32) eS[g >> 4][g & 15] = map[(long)(a0 + (g >> 4)*256)*VN + p0 + (g & 15)];
        __syncthreads();

        // ---- xi panel via MFMA (B streamed from L2); bias added at store ----
        {
            f32x4 acc[2][3];
            #pragma unroll
            for (int rs = 0; rs < 2; rs++)
                #pragma unroll
                for (int gi = 0; gi < 3; gi++) acc[rs][gi] = (f32x4){0.f,0.f,0.f,0.f};
            #pragma unroll
            for (int kt = 0; kt < 4; kt++) {
                bf16x8 ah0 = *(const bf16x8*)&xh[0][r16][kt*32 + kgrp*8];
                bf16x8 al0 = *(const bf16x8*)&xl[0][r16][kt*32 + kgrp*8];
                bf16x8 ah1 = *(const bf16x8*)&xh[1][r16][kt*32 + kgrp*8];
                bf16x8 al1 = *(const bf16x8*)&xl[1][r16][kt*32 + kgrp*8];
                #pragma unroll
                for (int gi = 0; gi < 3; gi++) {
                    long bidx = (((long)(gi*8 + wv)*4 + kt)*64 + lane)*8;
                    bf16x8 b_h = *(const bf16x8*)&wsBh[bidx];
                    bf16x8 b_l = *(const bf16x8*)&wsBl[bidx];
                    acc[0][gi] = __builtin_amdgcn_mfma_f32_16x16x32_bf16(ah0, b_h, acc[0][gi], 0, 0, 0);
                    acc[0][gi] = __builtin_amdgcn_mfma_f32_16x16x32_bf16(ah0, b_l, acc[0][gi], 0, 0, 0);
                    acc[0][gi] = __builtin_amdgcn_mfma_f32_16x16x32_bf16(al0, b_h, acc[0][gi], 0, 0, 0);
                    acc[1][gi] = __builtin_amdgcn_mfma_f32_16x16x32_bf16(ah1, b_h, acc[1][gi], 0, 0, 0);
                    acc[1][gi] = __builtin_amdgcn_mfma_f32_16x16x32_bf16(ah1, b_l, acc[1][gi], 0, 0, 0);
                    acc[1][gi] = __builtin_amdgcn_mfma_f32_16x16x32_bf16(al1, b_h, acc[1][gi], 0, 0, 0);
                }
            }
            // C layout: col = lane&15, row = kgrp*4 + r (= panel t)
            #pragma unroll
            for (int rs = 0; rs < 2; rs++) {
                #pragma unroll
                for (int gi = 0; gi < 3; gi++) {
                    float bias = (gi == 0) ? biR : (gi == 1) ? biZ : biN;
                    #pragma unroll
                    for (int r = 0; r < 4; r++)
                        xiP[rs][kgrp*4 + r][gi*128 + c] = acc[rs][gi][r] + bias;
                }
            }
        }
        __syncthreads();

        // ---- sparse corr add ----
        if (g < G3) {
            #pragma unroll
            for (int rs = 0; rs < 2; rs++)
                for (int t = 0; t < TP; t++) {
                    int e = eS[rs][t];
                    if (e >= 0) xiP[rs][t][g] += corr[(long)e*G3 + g];
                }
        }
        __syncthreads();

        // ---- 16 sequential gate steps: gh MFMA -> in-register gates -> hS parity write ----
        for (int t = 0; t < TP; t++) {
            f32x4 gR = (f32x4){0.f,0.f,0.f,0.f};
            f32x4 gZ = (f32x4){0.f,0.f,0.f,0.f};
            f32x4 gN = (f32x4){0.f,0.f,0.f,0.f};
            const int arow = r16 & 1;           // A rows 0/1 = chains; rows 2-15 duplicates
            #pragma unroll
            for (int kt = 0; kt < 4; kt++) {
                bf16x8 ah = *(const bf16x8*)&hSh[cur][arow][kt*32 + kgrp*8];
                bf16x8 al = *(const bf16x8*)&hSl[cur][arow][kt*32 + kgrp*8];
                gR = __builtin_amdgcn_mfma_f32_16x16x32_bf16(ah, wBh[kt],   gR, 0, 0, 0);
                gR = __builtin_amdgcn_mfma_f32_16x16x32_bf16(ah, wBl[kt],   gR, 0, 0, 0);
                gR = __builtin_amdgcn_mfma_f32_16x16x32_bf16(al, wBh[kt],   gR, 0, 0, 0);
                gZ = __builtin_amdgcn_mfma_f32_16x16x32_bf16(ah, wBh[4+kt], gZ, 0, 0, 0);
                gZ = __builtin_amdgcn_mfma_f32_16x16x32_bf16(ah, wBl[4+kt], gZ, 0, 0, 0);
                gZ = __builtin_amdgcn_mfma_f32_16x16x32_bf16(al, wBh[4+kt], gZ, 0, 0, 0);
                gN = __builtin_amdgcn_mfma_f32_16x16x32_bf16(ah, wBh[8+kt], gN, 0, 0, 0);
                gN = __builtin_amdgcn_mfma_f32_16x16x32_bf16(ah, wBl[8+kt], gN, 0, 0, 0);
                gN = __builtin_amdgcn_mfma_f32_16x16x32_bf16(al, wBh[8+kt], gN, 0, 0, 0);
            }
            if (lane < 16) {                    // rows 0/1 of C live here in regs 0/1
                float xr0 = xiP[0][t][c], xz0 = xiP[0][t][HN+c], xn0 = xiP[0][t][2*HN+c];
                float xr1 = xiP[1][t][c], xz1 = xiP[1][t][HN+c], xn1 = xiP[1][t][2*HN+c];
                float r0 = 1.f/(1.f + expf(-(xr0 + gR[0] + br)));
                float z0 = 1.f/(1.f + expf(-(xz0 + gZ[0] + bz)));
                float n0 = tanhf(xn0 + r0*(gN[0] + bn));
                float h0 = (1.f - z0)*n0 + z0*hprev0;
                float r1 = 1.f/(1.f + expf(-(xr1 + gR[1] + br)));
                float z1 = 1.f/(1.f + expf(-(xz1 + gZ[1] + bz)));
                float n1 = tanhf(xn1 + r1*(gN[1] + bn));
                float h1 = (1.f - z1)*n1 + z1*hprev1;
                hprev0 = h0; hprev1 = h1;
                hOut[0][t][c] = h0; hOut[1][t][c] = h1;
                int nxt = cur ^ 1;
                unsigned short hi0 = f2bf(h0);
                hSh[nxt][0][c] = hi0;
                hSl[nxt][0][c] = f2bf(h0 - __uint_as_float((unsigned int)hi0 << 16));
                unsigned short hi1 = f2bf(h1);
                hSh[nxt][1][c] = hi1;
                hSl[nxt][1][c] = f2bf(h1 - __uint_as_float((unsigned int)hi1 << 16));
            }
            cur ^= 1;
            __syncthreads();
        }
    }
    // ---- final write-back of last panel ----
    {
        int pp = VN - TP;
        for (int idx = g; idx < 2*TP*32; idx += 512) {
            int rs = idx >> 9, j = idx & 511, t = j >> 5, c4 = j & 31;
            *(float4*)&x[((long)(a0 + rs*256)*VN + pp + t)*HN + c4*4] =
                *(const float4*)&hOut[rs][t][c4*4];
        }
    }
}

extern "C" void kernel_launch(void* const* d_in, const int* in_sizes, int n_in,
                              void* d_out, int out_size, void* d_ws, size_t ws_size,
                              hipStream_t stream) {
    const float* adj   = (const float*)d_in[0];
    const void*  edges = d_in[1];
    const float* emb   = (const float*)d_in[2];
    const float* w1    = (const float*)d_in[3];
    const float* w2    = (const float*)d_in[4];
    const float* w3    = (const float*)d_in[5];
    const float* wih   = (const float*)d_in[6];
    const float* whh   = (const float*)d_in[7];
    const float* bih   = (const float*)d_in[8];
    const float* bhh   = (const float*)d_in[9];

    float* x = (float*)d_out;          // x lives in d_out; scan updates it in place

    char* p = (char*)d_ws;
    auto alloc = [&](size_t bytes) { char* r = p; p += (bytes + 255) & ~255UL; return r; };
    float* in3    = (float*)alloc((size_t)EN*G3*4);        // 50.3 MB
    float* msg    = (float*)alloc((size_t)EN*HN*4);        // 16.8 MB
    float* corr   = (float*)alloc((size_t)EN*G3*4);        // 50.3 MB
    float* colsum = (float*)alloc((size_t)VN*HN*4);
    int*   nnz    = (int*)  alloc((size_t)VN*4);
    int*   map    = (int*)  alloc((size_t)NROWS*4);
    int*   uA     = (int*)  alloc((size_t)EN*4);
    int*   vA     = (int*)  alloc((size_t)EN*4);
    float* wcat   = (float*)alloc((size_t)LN*HN*G3*4);
    unsigned short* wsBh = (unsigned short*)alloc((size_t)24*4*64*8*2);  // 98.3 KB
    unsigned short* wsBl = (unsigned short*)alloc((size_t)24*4*64*8*2);
    unsigned short* whBh = (unsigned short*)alloc((size_t)24*4*64*8*2);
    unsigned short* whBl = (unsigned short*)alloc((size_t)24*4*64*8*2);

    k_edges<<<EN/256, 256, 0, stream>>>(edges, uA, vA);
    k_pack<<<(3*128*384 + 255)/256, 256, 0, stream>>>(w1, w2, w3, wih, whh, wsBh, wsBl, whBh, whBl, wcat);
    k_fill<<<NROWS/256, 256, 0, stream>>>(map, -1, NROWS);
    k_map<<<EN/256, 256, 0, stream>>>(uA, vA, map);
    k_embed<<<NROWS/2, 256, 0, stream>>>(adj, emb, x);

    for (int l = 0; l < LN; l++) {
        k_colsum<<<VN, 512, 0, stream>>>(x, colsum, nnz);
        k_edgein<<<EN/4, 256, 0, stream>>>(x, uA, vA, colsum, nnz, in3);
        k_msggemm<<<EN/64, 256, 0, stream>>>(in3, wcat + (long)l*HN*G3, msg);
        k_corr<<<EN/16, 384, 0, stream>>>(in3, msg, wih, corr);
        k_scanf<<<VN/2, 512, 0, stream>>>(x, wsBh, wsBl, whBh, whBl, bih, bhh, corr, map);
    }
}

// Round 8
// 3429.244 us; speedup vs baseline: 12.0906x; 1.4724x over previous
//
#include <hip/hip_runtime.h>

#define VN 512
#define EN 32768
#define FN 8
#define HN 128
#define G3 384
#define LN 3
#define TP 16
#define NROWS (VN*VN)   // 262144
#define XIPAD 388       // 4*388 % 32 == 16 -> xiP stores are 2-way (free)

typedef short bf16x8 __attribute__((ext_vector_type(8)));
typedef float f32x4  __attribute__((ext_vector_type(4)));

__device__ __forceinline__ unsigned short f2bf(float f) {
    unsigned int u = __float_as_uint(f);
    unsigned int r = (u + 0x7FFFu + ((u >> 16) & 1u)) >> 16;
    return (unsigned short)r;
}

// ---------------- generic int fill ----------------
__global__ void k_fill(int* __restrict__ p, int val, int n) {
    int i = blockIdx.x * 256 + threadIdx.x;
    if (i < n) p[i] = val;
}

// ---------------- edge canonicalize (+ int64 detection) ----------------
__global__ void k_edges(const void* __restrict__ raw, int* __restrict__ uo, int* __restrict__ vo) {
    const int* r32 = (const int*)raw;
    const long long* r64 = (const long long*)raw;
    int acc = 0;
    #pragma unroll
    for (int i = 1; i < 128; i += 2) acc |= r32[i];
    bool is64 = (acc == 0);
    int e = blockIdx.x * 256 + threadIdx.x;
    if (e < EN) {
        int u, v;
        if (is64) { u = (int)r64[2*e]; v = (int)r64[2*e+1]; }
        else      { u = r32[2*e];      v = r32[2*e+1]; }
        uo[e] = u; vo[e] = v;
    }
}

// ---------------- pack ALL weight B-fragments (bf16 hi/lo, MFMA lane layout) ----------------
// frag layout: [..ntile..][ktile][lane][elem]: k = kt*32 + (lane>>4)*8 + e ; col = nt*16 + (lane&15)
__global__ void k_pack(const float* __restrict__ w1, const float* __restrict__ w2,
                       const float* __restrict__ w3, const float* __restrict__ wih,
                       const float* __restrict__ whh,
                       unsigned short* __restrict__ wsBh, unsigned short* __restrict__ wsBl,
                       unsigned short* __restrict__ whBh, unsigned short* __restrict__ whBl,
                       unsigned short* __restrict__ wlBh, unsigned short* __restrict__ wlBl,
                       unsigned short* __restrict__ wcBh, unsigned short* __restrict__ wcBl) {
    int t = blockIdx.x * 256 + threadIdx.x;
    if (t < 3*8*12*64*8) {        // 442368: wcat frags [l][nt0..7][kt0..11]
        int e = t & 7, lane = (t >> 3) & 63;
        int frag = t >> 9;
        int kt = frag % 12;
        int rem = frag / 12;
        int nt = rem & 7;
        int l  = rem >> 3;
        int k  = kt*32 + (lane >> 4)*8 + e;       // 0..383
        int gc = nt*16 + (lane & 15);             // 0..127
        const float* w = (k < 128) ? w1 : (k < 256 ? w2 : w3);
        float val = w[((long)l*128 + gc)*128 + (k & 127)];
        unsigned short hi = f2bf(val);
        wcBh[t] = hi;
        wcBl[t] = f2bf(val - __uint_as_float((unsigned int)hi << 16));
    }
    if (t < 24*4*64*8) {          // 49152: wsum / whh / wl frags [nt0..23][kt0..3]
        int e = t & 7, lane = (t >> 3) & 63, kt = (t >> 9) & 3, nt = t >> 11;
        int k  = kt*32 + (lane >> 4)*8 + e;       // 0..127
        int gc = nt*16 + (lane & 15);             // 0..383
        float vs = wih[gc*256 + k] + wih[gc*256 + 128 + k];
        unsigned short hi = f2bf(vs);
        wsBh[t] = hi; wsBl[t] = f2bf(vs - __uint_as_float((unsigned int)hi << 16));
        float vh = whh[gc*HN + k];
        hi = f2bf(vh);
        whBh[t] = hi; whBl[t] = f2bf(vh - __uint_as_float((unsigned int)hi << 16));
        float vl = wih[gc*256 + k];
        hi = f2bf(vl);
        wlBh[t] = hi; wlBl[t] = f2bf(vl - __uint_as_float((unsigned int)hi << 16));
    }
}

// ---------------- winner map: map[u*512+v] = max edge id ----------------
__global__ void k_map(const int* __restrict__ uA, const int* __restrict__ vA, int* __restrict__ map) {
    int e = blockIdx.x * 256 + threadIdx.x;
    if (e < EN) atomicMax(&map[uA[e]*VN + vA[e]], e);
}

// ---------------- embed: x[a,b,h] = sum_f adj[a,b,f]*emb[h,f] ----------------
__global__ __launch_bounds__(256) void k_embed(const float* __restrict__ adj,
                                               const float* __restrict__ emb,
                                               float* __restrict__ x) {
    __shared__ float semb[HN][FN];
    __shared__ float sadj[2][FN];
    int tid = threadIdx.x;
    for (int i = tid; i < HN*FN; i += 256) semb[i/FN][i%FN] = emb[i];
    if (tid < 16) sadj[tid>>3][tid&7] = adj[(long)blockIdx.x*16 + tid];
    __syncthreads();
    int p = tid >> 7;
    int h = tid & 127;
    float acc = 0.f;
    #pragma unroll
    for (int f = 0; f < FN; f++) acc += sadj[p][f]*semb[h][f];
    long row = (long)blockIdx.x*2 + p;
    x[row*HN + h] = acc;
}

// ---------------- col_sum[b,h] = sum_a x[a,b,h]; nnz[b] = count over (a,h) ----------------
__global__ __launch_bounds__(512) void k_colsum(const float* __restrict__ x,
                                                float* __restrict__ colsum, int* __restrict__ nnz) {
    int b = blockIdx.x;
    int tid = threadIdx.x;
    int h = tid & 127, q = tid >> 7;
    float s = 0.f; int c = 0;
    for (int a = q*128; a < q*128 + 128; a++) {
        float v = x[((long)a*VN + b)*HN + h];
        s += v; c += (v != 0.f) ? 1 : 0;
    }
    __shared__ float ss[4][128];
    __shared__ int sc[8];
    ss[q][h] = s;
    #pragma unroll
    for (int off = 32; off; off >>= 1) c += __shfl_down(c, off);
    if ((tid & 63) == 0) sc[tid>>6] = c;
    __syncthreads();
    if (tid < 128) colsum[b*HN + tid] = ss[0][tid]+ss[1][tid]+ss[2][tid]+ss[3][tid];
    if (tid == 0) { int t = 0; for (int i = 0; i < 8; i++) t += sc[i]; nnz[b] = t; }
}

// ---------------- per-edge GEMM inputs: in3 = [x_uv, e_in, e_out] ----------------
__global__ __launch_bounds__(256) void k_edgein(const float* __restrict__ x,
    const int* __restrict__ uA, const int* __restrict__ vA,
    const float* __restrict__ colsum, const int* __restrict__ nnz, float* __restrict__ in3) {
    int w = threadIdx.x >> 6;
    int lane = threadIdx.x & 63;
    int e = blockIdx.x*4 + w;
    int u = uA[e], v = vA[e];
    const float* xuv = x + ((long)u*VN + v)*HN;
    const float* xvu = x + ((long)v*VN + u)*HN;
    float xu0 = xuv[lane], xu1 = xuv[lane+64];
    float xv0 = xvu[lane], xv1 = xvu[lane+64];
    int cnt_vu = __popcll(__ballot(xv0 != 0.f)) + __popcll(__ballot(xv1 != 0.f));
    int cnt_uv = __popcll(__ballot(xu0 != 0.f)) + __popcll(__ballot(xu1 != 0.f));
    float nin  = (float)(nnz[u] - cnt_vu) * (1.f/128.f); if (nin  == 0.f) nin  = 1.f;
    float nout = (float)(nnz[v] - cnt_uv) * (1.f/128.f); if (nout == 0.f) nout = 1.f;
    float* o = in3 + (long)e*G3;
    o[lane]        = xu0;  o[lane+64]      = xu1;
    o[128+lane]    = (colsum[u*HN+lane]    - xv0)/nin;
    o[128+lane+64] = (colsum[u*HN+lane+64] - xv1)/nin;
    o[256+lane]    = (colsum[v*HN+lane]    - xu0)/nout;
    o[256+lane+64] = (colsum[v*HN+lane+64] - xu1)/nout;
}

// ---------------- fused msg+corr (MFMA): per block 16 edges ----------------
// phase 1: msg = relu(in3[16x384] @ Wcat^T)   (wave wv owns output cols wv*16..+15)
// D = msg - x_uv (bf16 hi/lo in LDS)
// phase 2: corr = D @ Wl^T                    (wave wv owns nt = 3wv..3wv+2)
__global__ __launch_bounds__(512) void k_msgcorr(
    const float* __restrict__ in3,
    const unsigned short* __restrict__ wcBh, const unsigned short* __restrict__ wcBl,
    const unsigned short* __restrict__ wlBh, const unsigned short* __restrict__ wlBl,
    float* __restrict__ corr) {
    const int g = threadIdx.x;
    const int wv = g >> 6;
    const int lane = g & 63;
    const int r16 = lane & 15;
    const int kgrp = lane >> 4;
    const long m0 = (long)blockIdx.x * 16;

    __shared__ unsigned short Dh[16][136];
    __shared__ unsigned short Dl[16][136];

    // ---- phase 1 ----
    f32x4 pacc[2];
    pacc[0] = (f32x4){0.f,0.f,0.f,0.f};
    pacc[1] = (f32x4){0.f,0.f,0.f,0.f};
    #pragma unroll
    for (int kt = 0; kt < 12; kt++) {
        const float* xs = &in3[(m0 + r16)*G3 + kt*32 + kgrp*8];
        float4 v0 = *(const float4*)xs;
        float4 v1 = *(const float4*)(xs + 4);
        float vv[8] = {v0.x,v0.y,v0.z,v0.w,v1.x,v1.y,v1.z,v1.w};
        bf16x8 ah, al;
        #pragma unroll
        for (int j = 0; j < 8; j++) {
            unsigned short hi = f2bf(vv[j]);
            ah[j] = (short)hi;
            al[j] = (short)f2bf(vv[j] - __uint_as_float((unsigned int)hi << 16));
        }
        long bidx = (((long)wv*12 + kt)*64 + lane)*8;
        bf16x8 bh = *(const bf16x8*)&wcBh[bidx];
        bf16x8 bl = *(const bf16x8*)&wcBl[bidx];
        const int p = kt & 1;
        pacc[p] = __builtin_amdgcn_mfma_f32_16x16x32_bf16(ah, bh, pacc[p], 0, 0, 0);
        pacc[p] = __builtin_amdgcn_mfma_f32_16x16x32_bf16(ah, bl, pacc[p], 0, 0, 0);
        pacc[p] = __builtin_amdgcn_mfma_f32_16x16x32_bf16(al, bh, pacc[p], 0, 0, 0);
    }
    const int c = wv*16 + r16;                  // msg col 0..127
    #pragma unroll
    for (int r = 0; r < 4; r++) {
        int m = kgrp*4 + r;
        float mv = fmaxf(pacc[0][r] + pacc[1][r], 0.f) - in3[(m0 + m)*G3 + c];
        unsigned short hi = f2bf(mv);
        Dh[m][c] = hi;
        Dl[m][c] = f2bf(mv - __uint_as_float((unsigned int)hi << 16));
    }
    __syncthreads();

    // ---- phase 2 ----
    f32x4 cacc[3];
    cacc[0] = cacc[1] = cacc[2] = (f32x4){0.f,0.f,0.f,0.f};
    #pragma unroll
    for (int kt = 0; kt < 4; kt++) {
        bf16x8 ah = *(const bf16x8*)&Dh[r16][kt*32 + kgrp*8];
        bf16x8 al = *(const bf16x8*)&Dl[r16][kt*32 + kgrp*8];
        #pragma unroll
        for (int j = 0; j < 3; j++) {
            long bidx = (((long)(wv*3 + j)*4 + kt)*64 + lane)*8;
            bf16x8 bh = *(const bf16x8*)&wlBh[bidx];
            bf16x8 bl = *(const bf16x8*)&wlBl[bidx];
            cacc[j] = __builtin_amdgcn_mfma_f32_16x16x32_bf16(ah, bh, cacc[j], 0, 0, 0);
            cacc[j] = __builtin_amdgcn_mfma_f32_16x16x32_bf16(ah, bl, cacc[j], 0, 0, 0);
            cacc[j] = __builtin_amdgcn_mfma_f32_16x16x32_bf16(al, bh, cacc[j], 0, 0, 0);
        }
    }
    #pragma unroll
    for (int j = 0; j < 3; j++) {
        int n = (wv*3 + j)*16 + r16;
        #pragma unroll
        for (int r = 0; r < 4; r++)
            corr[(m0 + kgrp*4 + r)*G3 + n] = cacc[j][r];
    }
}

// ---------------- fused xi(MFMA) + GRU scan (v6) ----------------
// 256 blocks x 512 threads (8 waves); block owns chains {a0, a0+256}.
// xi A-frags converted from global x in registers (no LDS staging, no 8-way-conflict reads);
// gh via resident whh B-frags, 6 split accumulator chains; one barrier per step.
__global__ __launch_bounds__(512) void k_scanf(
    float* __restrict__ x,
    const unsigned short* __restrict__ wsBh, const unsigned short* __restrict__ wsBl,
    const unsigned short* __restrict__ whBh, const unsigned short* __restrict__ whBl,
    const float* __restrict__ bih, const float* __restrict__ bhh,
    const float* __restrict__ corr, const int* __restrict__ map) {
    const int g = threadIdx.x;          // 0..511
    const int a0 = blockIdx.x;
    const int wv = g >> 6;              // 0..7
    const int lane = g & 63;
    const int r16 = lane & 15;
    const int kgrp = lane >> 4;

    __shared__ float xiP[2][TP][XIPAD];         // 49664 B
    __shared__ unsigned short hSh[2][2][HN];    // [parity][chain][col]
    __shared__ unsigned short hSl[2][2][HN];
    __shared__ float hOut[2][TP][HN];           // 16384 B
    __shared__ int   eS[2][TP];

    // resident whh B-frags: [gate 0..2][kt 0..3] hi/lo = 96 VGPRs
    bf16x8 wBh[12], wBl[12];
    #pragma unroll
    for (int gi = 0; gi < 3; gi++)
        #pragma unroll
        for (int kt = 0; kt < 4; kt++) {
            long bidx = (((long)(gi*8 + wv)*4 + kt)*64 + lane)*8;
            wBh[gi*4+kt] = *(const bf16x8*)&whBh[bidx];
            wBl[gi*4+kt] = *(const bf16x8*)&whBl[bidx];
        }

    const int c = wv*16 + r16;                  // this lane's gate column
    const float br = bhh[c],  bz = bhh[HN + c],  bn = bhh[2*HN + c];
    const float biR = bih[c], biZ = bih[HN + c], biN = bih[2*HN + c];
    float hprev0 = 0.f, hprev1 = 0.f;

    if (g < 2*HN) {
        ((unsigned short*)hSh)[g] = 0;
        ((unsigned short*)hSl)[g] = 0;
    }
    int cur = 0;
    __syncthreads();

    for (int p0 = 0; p0 < VN; p0 += TP) {
        // ---- write back prev panel's h (rows disjoint from current panel) ----
        if (p0 > 0) {
            int pp = p0 - TP;
            for (int idx = g; idx < 2*TP*32; idx += 512) {
                int rs = idx >> 9, j = idx & 511, t = j >> 5, c4 = j & 31;
                *(float4*)&x[((long)(a0 + rs*256)*VN + pp + t)*HN + c4*4] =
                    *(const float4*)&hOut[rs][t][c4*4];
            }
        }
        if (g < 32) eS[g >> 4][g & 15] = map[(long)(a0 + (g >> 4)*256)*VN + p0 + (g & 15)];

        // ---- xi panel via MFMA: A-frags from global x, converted in registers ----
        {
            f32x4 acc[2][3];
            #pragma unroll
            for (int rs = 0; rs < 2; rs++)
                #pragma unroll
                for (int gi = 0; gi < 3; gi++) acc[rs][gi] = (f32x4){0.f,0.f,0.f,0.f};
            #pragma unroll
            for (int kt = 0; kt < 4; kt++) {
                bf16x8 ah[2], al[2];
                #pragma unroll
                for (int rs = 0; rs < 2; rs++) {
                    const float* xs = &x[((long)(a0 + rs*256)*VN + p0 + r16)*HN + kt*32 + kgrp*8];
                    float4 v0 = *(const float4*)xs;
                    float4 v1 = *(const float4*)(xs + 4);
                    float vv[8] = {v0.x,v0.y,v0.z,v0.w,v1.x,v1.y,v1.z,v1.w};
                    #pragma unroll
                    for (int j = 0; j < 8; j++) {
                        unsigned short hi = f2bf(vv[j]);
                        ah[rs][j] = (short)hi;
                        al[rs][j] = (short)f2bf(vv[j] - __uint_as_float((unsigned int)hi << 16));
                    }
                }
                #pragma unroll
                for (int gi = 0; gi < 3; gi++) {
                    long bidx = (((long)(gi*8 + wv)*4 + kt)*64 + lane)*8;
                    bf16x8 b_h = *(const bf16x8*)&wsBh[bidx];
                    bf16x8 b_l = *(const bf16x8*)&wsBl[bidx];
                    acc[0][gi] = __builtin_amdgcn_mfma_f32_16x16x32_bf16(ah[0], b_h, acc[0][gi], 0, 0, 0);
                    acc[0][gi] = __builtin_amdgcn_mfma_f32_16x16x32_bf16(ah[0], b_l, acc[0][gi], 0, 0, 0);
                    acc[0][gi] = __builtin_amdgcn_mfma_f32_16x16x32_bf16(al[0], b_h, acc[0][gi], 0, 0, 0);
                    acc[1][gi] = __builtin_amdgcn_mfma_f32_16x16x32_bf16(ah[1], b_h, acc[1][gi], 0, 0, 0);
                    acc[1][gi] = __builtin_amdgcn_mfma_f32_16x16x32_bf16(ah[1], b_l, acc[1][gi], 0, 0, 0);
                    acc[1][gi] = __builtin_amdgcn_mfma_f32_16x16x32_bf16(al[1], b_h, acc[1][gi], 0, 0, 0);
                }
            }
            // C layout: col = lane&15, row = kgrp*4 + r (= panel t)
            #pragma unroll
            for (int rs = 0; rs < 2; rs++) {
                #pragma unroll
                for (int gi = 0; gi < 3; gi++) {
                    float bias = (gi == 0) ? biR : (gi == 1) ? biZ : biN;
                    #pragma unroll
                    for (int r = 0; r < 4; r++)
                        xiP[rs][kgrp*4 + r][gi*128 + c] = acc[rs][gi][r] + bias;
                }
            }
        }
        __syncthreads();

        // ---- sparse corr add ----
        if (g < G3) {
            #pragma unroll
            for (int rs = 0; rs < 2; rs++)
                for (int t = 0; t < TP; t++) {
                    int e = eS[rs][t];
                    if (e >= 0) xiP[rs][t][g] += corr[(long)e*G3 + g];
                }
        }
        __syncthreads();

        // ---- 16 sequential gate steps ----
        const int arow = r16 & 1;
        for (int t = 0; t < TP; t++) {
            bf16x8 hA[4], lA[4];
            #pragma unroll
            for (int kt = 0; kt < 4; kt++) {
                hA[kt] = *(const bf16x8*)&hSh[cur][arow][kt*32 + kgrp*8];
                lA[kt] = *(const bf16x8*)&hSl[cur][arow][kt*32 + kgrp*8];
            }
            f32x4 gR[2], gZ[2], gN[2];
            gR[0]=gR[1]=gZ[0]=gZ[1]=gN[0]=gN[1]=(f32x4){0.f,0.f,0.f,0.f};
            #pragma unroll
            for (int kt = 0; kt < 4; kt++) {
                const int p = kt & 1;
                gR[p] = __builtin_amdgcn_mfma_f32_16x16x32_bf16(hA[kt], wBh[kt],   gR[p], 0, 0, 0);
                gR[p] = __builtin_amdgcn_mfma_f32_16x16x32_bf16(hA[kt], wBl[kt],   gR[p], 0, 0, 0);
                gR[p] = __builtin_amdgcn_mfma_f32_16x16x32_bf16(lA[kt], wBh[kt],   gR[p], 0, 0, 0);
                gZ[p] = __builtin_amdgcn_mfma_f32_16x16x32_bf16(hA[kt], wBh[4+kt], gZ[p], 0, 0, 0);
                gZ[p] = __builtin_amdgcn_mfma_f32_16x16x32_bf16(hA[kt], wBl[4+kt], gZ[p], 0, 0, 0);
                gZ[p] = __builtin_amdgcn_mfma_f32_16x16x32_bf16(lA[kt], wBh[4+kt], gZ[p], 0, 0, 0);
                gN[p] = __builtin_amdgcn_mfma_f32_16x16x32_bf16(hA[kt], wBh[8+kt], gN[p], 0, 0, 0);
                gN[p] = __builtin_amdgcn_mfma_f32_16x16x32_bf16(hA[kt], wBl[8+kt], gN[p], 0, 0, 0);
                gN[p] = __builtin_amdgcn_mfma_f32_16x16x32_bf16(lA[kt], wBh[8+kt], gN[p], 0, 0, 0);
            }
            if (lane < 16) {
                float gr0 = gR[0][0] + gR[1][0], gr1 = gR[0][1] + gR[1][1];
                float gz0 = gZ[0][0] + gZ[1][0], gz1 = gZ[0][1] + gZ[1][1];
                float gn0 = gN[0][0] + gN[1][0], gn1 = gN[0][1] + gN[1][1];
                float xr0 = xiP[0][t][c], xz0 = xiP[0][t][HN+c], xn0 = xiP[0][t][2*HN+c];
                float xr1 = xiP[1][t][c], xz1 = xiP[1][t][HN+c], xn1 = xiP[1][t][2*HN+c];
                float r0 = 1.f/(1.f + expf(-(xr0 + gr0 + br)));
                float z0 = 1.f/(1.f + expf(-(xz0 + gz0 + bz)));
                float n0 = tanhf(xn0 + r0*(gn0 + bn));
                float h0 = (1.f - z0)*n0 + z0*hprev0;
                float r1 = 1.f/(1.f + expf(-(xr1 + gr1 + br)));
                float z1 = 1.f/(1.f + expf(-(xz1 + gz1 + bz)));
                float n1 = tanhf(xn1 + r1*(gn1 + bn));
                float h1 = (1.f - z1)*n1 + z1*hprev1;
                hprev0 = h0; hprev1 = h1;
                hOut[0][t][c] = h0; hOut[1][t][c] = h1;
                int nxt = cur ^ 1;
                unsigned short hi0 = f2bf(h0);
                hSh[nxt][0][c] = hi0;
                hSl[nxt][0][c] = f2bf(h0 - __uint_as_float((unsigned int)hi0 << 16));
                unsigned short hi1 = f2bf(h1);
                hSh[nxt][1][c] = hi1;
                hSl[nxt][1][c] = f2bf(h1 - __uint_as_float((unsigned int)hi1 << 16));
            }
            cur ^= 1;
            __syncthreads();
        }
    }
    // ---- final write-back of last panel ----
    {
        int pp = VN - TP;
        for (int idx = g; idx < 2*TP*32; idx += 512) {
            int rs = idx >> 9, j = idx & 511, t = j >> 5, c4 = j & 31;
            *(float4*)&x[((long)(a0 + rs*256)*VN + pp + t)*HN + c4*4] =
                *(const float4*)&hOut[rs][t][c4*4];
        }
    }
}

extern "C" void kernel_launch(void* const* d_in, const int* in_sizes, int n_in,
                              void* d_out, int out_size, void* d_ws, size_t ws_size,
                              hipStream_t stream) {
    const float* adj   = (const float*)d_in[0];
    const void*  edges = d_in[1];
    const float* emb   = (const float*)d_in[2];
    const float* w1    = (const float*)d_in[3];
    const float* w2    = (const float*)d_in[4];
    const float* w3    = (const float*)d_in[5];
    const float* wih   = (const float*)d_in[6];
    const float* whh   = (const float*)d_in[7];
    const float* bih   = (const float*)d_in[8];
    const float* bhh   = (const float*)d_in[9];

    float* x = (float*)d_out;          // x lives in d_out; scan updates it in place

    char* p = (char*)d_ws;
    auto alloc = [&](size_t bytes) { char* r = p; p += (bytes + 255) & ~255UL; return r; };
    float* in3    = (float*)alloc((size_t)EN*G3*4);        // 50.3 MB
    float* corr   = (float*)alloc((size_t)EN*G3*4);        // 50.3 MB
    float* colsum = (float*)alloc((size_t)VN*HN*4);
    int*   nnz    = (int*)  alloc((size_t)VN*4);
    int*   map    = (int*)  alloc((size_t)NROWS*4);
    int*   uA     = (int*)  alloc((size_t)EN*4);
    int*   vA     = (int*)  alloc((size_t)EN*4);
    unsigned short* wsBh = (unsigned short*)alloc((size_t)24*4*64*8*2);
    unsigned short* wsBl = (unsigned short*)alloc((size_t)24*4*64*8*2);
    unsigned short* whBh = (unsigned short*)alloc((size_t)24*4*64*8*2);
    unsigned short* whBl = (unsigned short*)alloc((size_t)24*4*64*8*2);
    unsigned short* wlBh = (unsigned short*)alloc((size_t)24*4*64*8*2);
    unsigned short* wlBl = (unsigned short*)alloc((size_t)24*4*64*8*2);
    unsigned short* wcBh = (unsigned short*)alloc((size_t)3*8*12*64*8*2);  // 884.7 KB
    unsigned short* wcBl = (unsigned short*)alloc((size_t)3*8*12*64*8*2);

    k_edges<<<EN/256, 256, 0, stream>>>(edges, uA, vA);
    k_pack<<<(3*8*12*64*8 + 255)/256, 256, 0, stream>>>(w1, w2, w3, wih, whh,
        wsBh, wsBl, whBh, whBl, wlBh, wlBl, wcBh, wcBl);
    k_fill<<<NROWS/256, 256, 0, stream>>>(map, -1, NROWS);
    k_map<<<EN/256, 256, 0, stream>>>(uA, vA, map);
    k_embed<<<NROWS/2, 256, 0, stream>>>(adj, emb, x);

    for (int l = 0; l < LN; l++) {
        k_colsum<<<VN, 512, 0, stream>>>(x, colsum, nnz);
        k_edgein<<<EN/4, 256, 0, stream>>>(x, uA, vA, colsum, nnz, in3);
        k_msgcorr<<<EN/16, 512, 0, stream>>>(in3, wcBh + (long)l*8*12*64*8, wcBl + (long)l*8*12*64*8,
                                             wlBh, wlBl, corr);
        k_scanf<<<VN/2, 512, 0, stream>>>(x, wsBh, wsBl, whBh, whBl, bih, bhh, corr, map);
    }
}

// Round 9
// 3189.811 us; speedup vs baseline: 12.9981x; 1.0751x over previous
//
#include <hip/hip_runtime.h>

#define VN 512
#define EN 32768
#define FN 8
#define HN 128
#define G3 384
#define LN 3
#define TP 16
#define NROWS (VN*VN)   // 262144
#define XIPAD 388       // 4*388 % 32 == 16 -> 2-way LDS aliasing (free)

typedef short bf16x8 __attribute__((ext_vector_type(8)));
typedef float f32x4  __attribute__((ext_vector_type(4)));
typedef unsigned int u32x4 __attribute__((ext_vector_type(4)));
union b8u4 { u32x4 u; bf16x8 b; };

__device__ __forceinline__ unsigned short f2bf(float f) {
    unsigned int u = __float_as_uint(f);
    unsigned int r = (u + 0x7FFFu + ((u >> 16) & 1u)) >> 16;
    return (unsigned short)r;
}
__device__ __forceinline__ unsigned cvtpk(float a, float b) {
    unsigned r;
    asm("v_cvt_pk_bf16_f32 %0, %1, %2" : "=v"(r) : "v"(a), "v"(b));
    return r;   // lo16 = bf16(a), hi16 = bf16(b)
}
__device__ __forceinline__ float fexp2(float x) {
    float r; asm("v_exp_f32 %0, %1" : "=v"(r) : "v"(x)); return r;
}
__device__ __forceinline__ float frcp(float x) {
    float r; asm("v_rcp_f32 %0, %1" : "=v"(r) : "v"(x)); return r;
}
__device__ __forceinline__ float fsigmoid(float x) {
    return frcp(1.f + fexp2(x * -1.44269504089f));
}
__device__ __forceinline__ float ftanh(float x) {
    return 1.f - 2.f * frcp(1.f + fexp2(x * 2.88539008178f));
}

// ---------------- generic int fill ----------------
__global__ void k_fill(int* __restrict__ p, int val, int n) {
    int i = blockIdx.x * 256 + threadIdx.x;
    if (i < n) p[i] = val;
}

// ---------------- edge canonicalize (+ int64 detection) ----------------
__global__ void k_edges(const void* __restrict__ raw, int* __restrict__ uo, int* __restrict__ vo) {
    const int* r32 = (const int*)raw;
    const long long* r64 = (const long long*)raw;
    int acc = 0;
    #pragma unroll
    for (int i = 1; i < 128; i += 2) acc |= r32[i];
    bool is64 = (acc == 0);
    int e = blockIdx.x * 256 + threadIdx.x;
    if (e < EN) {
        int u, v;
        if (is64) { u = (int)r64[2*e]; v = (int)r64[2*e+1]; }
        else      { u = r32[2*e];      v = r32[2*e+1]; }
        uo[e] = u; vo[e] = v;
    }
}

// ---------------- pack ALL weight B-fragments (bf16 hi/lo, MFMA lane layout) ----------------
__global__ void k_pack(const float* __restrict__ w1, const float* __restrict__ w2,
                       const float* __restrict__ w3, const float* __restrict__ wih,
                       const float* __restrict__ whh,
                       unsigned short* __restrict__ wsBh, unsigned short* __restrict__ wsBl,
                       unsigned short* __restrict__ whBh, unsigned short* __restrict__ whBl,
                       unsigned short* __restrict__ wlBh, unsigned short* __restrict__ wlBl,
                       unsigned short* __restrict__ wcBh, unsigned short* __restrict__ wcBl) {
    int t = blockIdx.x * 256 + threadIdx.x;
    if (t < 3*8*12*64*8) {        // wcat frags [l][nt0..7][kt0..11]
        int e = t & 7, lane = (t >> 3) & 63;
        int frag = t >> 9;
        int kt = frag % 12;
        int rem = frag / 12;
        int nt = rem & 7;
        int l  = rem >> 3;
        int k  = kt*32 + (lane >> 4)*8 + e;
        int gc = nt*16 + (lane & 15);
        const float* w = (k < 128) ? w1 : (k < 256 ? w2 : w3);
        float val = w[((long)l*128 + gc)*128 + (k & 127)];
        unsigned short hi = f2bf(val);
        wcBh[t] = hi;
        wcBl[t] = f2bf(val - __uint_as_float((unsigned int)hi << 16));
    }
    if (t < 24*4*64*8) {          // wsum / whh / wl frags [nt0..23][kt0..3]
        int e = t & 7, lane = (t >> 3) & 63, kt = (t >> 9) & 3, nt = t >> 11;
        int k  = kt*32 + (lane >> 4)*8 + e;
        int gc = nt*16 + (lane & 15);
        float vs = wih[gc*256 + k] + wih[gc*256 + 128 + k];
        unsigned short hi = f2bf(vs);
        wsBh[t] = hi; wsBl[t] = f2bf(vs - __uint_as_float((unsigned int)hi << 16));
        float vh = whh[gc*HN + k];
        hi = f2bf(vh);
        whBh[t] = hi; whBl[t] = f2bf(vh - __uint_as_float((unsigned int)hi << 16));
        float vl = wih[gc*256 + k];
        hi = f2bf(vl);
        wlBh[t] = hi; wlBl[t] = f2bf(vl - __uint_as_float((unsigned int)hi << 16));
    }
}

// ---------------- winner map ----------------
__global__ void k_map(const int* __restrict__ uA, const int* __restrict__ vA, int* __restrict__ map) {
    int e = blockIdx.x * 256 + threadIdx.x;
    if (e < EN) atomicMax(&map[uA[e]*VN + vA[e]], e);
}

// ---------------- embed ----------------
__global__ __launch_bounds__(256) void k_embed(const float* __restrict__ adj,
                                               const float* __restrict__ emb,
                                               float* __restrict__ x) {
    __shared__ float semb[HN][FN];
    __shared__ float sadj[2][FN];
    int tid = threadIdx.x;
    for (int i = tid; i < HN*FN; i += 256) semb[i/FN][i%FN] = emb[i];
    if (tid < 16) sadj[tid>>3][tid&7] = adj[(long)blockIdx.x*16 + tid];
    __syncthreads();
    int p = tid >> 7;
    int h = tid & 127;
    float acc = 0.f;
    #pragma unroll
    for (int f = 0; f < FN; f++) acc += sadj[p][f]*semb[h][f];
    long row = (long)blockIdx.x*2 + p;
    x[row*HN + h] = acc;
}

// ---------------- colsum + nnz ----------------
__global__ __launch_bounds__(512) void k_colsum(const float* __restrict__ x,
                                                float* __restrict__ colsum, int* __restrict__ nnz) {
    int b = blockIdx.x;
    int tid = threadIdx.x;
    int h = tid & 127, q = tid >> 7;
    float s = 0.f; int c = 0;
    for (int a = q*128; a < q*128 + 128; a++) {
        float v = x[((long)a*VN + b)*HN + h];
        s += v; c += (v != 0.f) ? 1 : 0;
    }
    __shared__ float ss[4][128];
    __shared__ int sc[8];
    ss[q][h] = s;
    #pragma unroll
    for (int off = 32; off; off >>= 1) c += __shfl_down(c, off);
    if ((tid & 63) == 0) sc[tid>>6] = c;
    __syncthreads();
    if (tid < 128) colsum[b*HN + tid] = ss[0][tid]+ss[1][tid]+ss[2][tid]+ss[3][tid];
    if (tid == 0) { int t = 0; for (int i = 0; i < 8; i++) t += sc[i]; nnz[b] = t; }
}

// ---------------- edge inputs ----------------
__global__ __launch_bounds__(256) void k_edgein(const float* __restrict__ x,
    const int* __restrict__ uA, const int* __restrict__ vA,
    const float* __restrict__ colsum, const int* __restrict__ nnz, float* __restrict__ in3) {
    int w = threadIdx.x >> 6;
    int lane = threadIdx.x & 63;
    int e = blockIdx.x*4 + w;
    int u = uA[e], v = vA[e];
    const float* xuv = x + ((long)u*VN + v)*HN;
    const float* xvu = x + ((long)v*VN + u)*HN;
    float xu0 = xuv[lane], xu1 = xuv[lane+64];
    float xv0 = xvu[lane], xv1 = xvu[lane+64];
    int cnt_vu = __popcll(__ballot(xv0 != 0.f)) + __popcll(__ballot(xv1 != 0.f));
    int cnt_uv = __popcll(__ballot(xu0 != 0.f)) + __popcll(__ballot(xu1 != 0.f));
    float nin  = (float)(nnz[u] - cnt_vu) * (1.f/128.f); if (nin  == 0.f) nin  = 1.f;
    float nout = (float)(nnz[v] - cnt_uv) * (1.f/128.f); if (nout == 0.f) nout = 1.f;
    float* o = in3 + (long)e*G3;
    o[lane]        = xu0;  o[lane+64]      = xu1;
    o[128+lane]    = (colsum[u*HN+lane]    - xv0)/nin;
    o[128+lane+64] = (colsum[u*HN+lane+64] - xv1)/nin;
    o[256+lane]    = (colsum[v*HN+lane]    - xu0)/nout;
    o[256+lane+64] = (colsum[v*HN+lane+64] - xu1)/nout;
}

// ---------------- fused msg+corr (MFMA) ----------------
__global__ __launch_bounds__(512) void k_msgcorr(
    const float* __restrict__ in3,
    const unsigned short* __restrict__ wcBh, const unsigned short* __restrict__ wcBl,
    const unsigned short* __restrict__ wlBh, const unsigned short* __restrict__ wlBl,
    float* __restrict__ corr) {
    const int g = threadIdx.x;
    const int wv = g >> 6;
    const int lane = g & 63;
    const int r16 = lane & 15;
    const int kgrp = lane >> 4;
    const long m0 = (long)blockIdx.x * 16;

    __shared__ unsigned short Dh[16][136];
    __shared__ unsigned short Dl[16][136];

    f32x4 pacc[2];
    pacc[0] = (f32x4){0.f,0.f,0.f,0.f};
    pacc[1] = (f32x4){0.f,0.f,0.f,0.f};
    #pragma unroll
    for (int kt = 0; kt < 12; kt++) {
        const float* xs = &in3[(m0 + r16)*G3 + kt*32 + kgrp*8];
        float4 v0 = *(const float4*)xs;
        float4 v1 = *(const float4*)(xs + 4);
        unsigned h0 = cvtpk(v0.x, v0.y), h1 = cvtpk(v0.z, v0.w);
        unsigned h2 = cvtpk(v1.x, v1.y), h3 = cvtpk(v1.z, v1.w);
        float q0 = v0.x - __uint_as_float(h0 << 16);
        float q1 = v0.y - __uint_as_float(h0 & 0xffff0000u);
        float q2 = v0.z - __uint_as_float(h1 << 16);
        float q3 = v0.w - __uint_as_float(h1 & 0xffff0000u);
        float q4 = v1.x - __uint_as_float(h2 << 16);
        float q5 = v1.y - __uint_as_float(h2 & 0xffff0000u);
        float q6 = v1.z - __uint_as_float(h3 << 16);
        float q7 = v1.w - __uint_as_float(h3 & 0xffff0000u);
        b8u4 H, L;
        H.u = (u32x4){h0, h1, h2, h3};
        L.u = (u32x4){cvtpk(q0,q1), cvtpk(q2,q3), cvtpk(q4,q5), cvtpk(q6,q7)};
        long bidx = (((long)wv*12 + kt)*64 + lane)*8;
        bf16x8 bh = *(const bf16x8*)&wcBh[bidx];
        bf16x8 bl = *(const bf16x8*)&wcBl[bidx];
        const int p = kt & 1;
        pacc[p] = __builtin_amdgcn_mfma_f32_16x16x32_bf16(H.b, bh, pacc[p], 0, 0, 0);
        pacc[p] = __builtin_amdgcn_mfma_f32_16x16x32_bf16(H.b, bl, pacc[p], 0, 0, 0);
        pacc[p] = __builtin_amdgcn_mfma_f32_16x16x32_bf16(L.b, bh, pacc[p], 0, 0, 0);
    }
    const int c = wv*16 + r16;
    #pragma unroll
    for (int r = 0; r < 4; r++) {
        int m = kgrp*4 + r;
        float mv = fmaxf(pacc[0][r] + pacc[1][r], 0.f) - in3[(m0 + m)*G3 + c];
        unsigned short hi = f2bf(mv);
        Dh[m][c] = hi;
        Dl[m][c] = f2bf(mv - __uint_as_float((unsigned int)hi << 16));
    }
    __syncthreads();

    f32x4 cacc[3];
    cacc[0] = cacc[1] = cacc[2] = (f32x4){0.f,0.f,0.f,0.f};
    #pragma unroll
    for (int kt = 0; kt < 4; kt++) {
        bf16x8 ah = *(const bf16x8*)&Dh[r16][kt*32 + kgrp*8];
        bf16x8 al = *(const bf16x8*)&Dl[r16][kt*32 + kgrp*8];
        #pragma unroll
        for (int j = 0; j < 3; j++) {
            long bidx = (((long)(wv*3 + j)*4 + kt)*64 + lane)*8;
            bf16x8 bh = *(const bf16x8*)&wlBh[bidx];
            bf16x8 bl = *(const bf16x8*)&wlBl[bidx];
            cacc[j] = __builtin_amdgcn_mfma_f32_16x16x32_bf16(ah, bh, cacc[j], 0, 0, 0);
            cacc[j] = __builtin_amdgcn_mfma_f32_16x16x32_bf16(ah, bl, cacc[j], 0, 0, 0);
            cacc[j] = __builtin_amdgcn_mfma_f32_16x16x32_bf16(al, bh, cacc[j], 0, 0, 0);
        }
    }
    #pragma unroll
    for (int j = 0; j < 3; j++) {
        int n = (wv*3 + j)*16 + r16;
        #pragma unroll
        for (int r = 0; r < 4; r++)
            corr[(m0 + kgrp*4 + r)*G3 + n] = cacc[j][r];
    }
}

// ================= fused xi(MFMA, pipelined) + GRU scan (v7) =================
// 256 blocks x 512 threads (8 waves); block owns chains {a0, a0+256}.
// Panel p+1's xi items (3 MFMA + loads + cvt each) statically interleaved into
// panel p's 16 gate steps; gate math on 32 lanes via ds_bpermute row move;
// fast sigmoid/tanh via v_exp/v_rcp; cvt_pk_bf16 conversions.

#define MF(A,B,C) __builtin_amdgcn_mfma_f32_16x16x32_bf16((A),(B),(C),0,0,0)
#define Z4 ((f32x4){0.f,0.f,0.f,0.f})

#define XI_ITEM(RS, GI, KT) do { \
    const float* xs_ = &x[((long)(a0 + RS*256)*VN + xrow + r16)*HN + KT*32 + kgrp*8]; \
    float4 v0_ = *(const float4*)xs_; \
    float4 v1_ = *(const float4*)(xs_ + 4); \
    unsigned h0_ = cvtpk(v0_.x, v0_.y), h1_ = cvtpk(v0_.z, v0_.w); \
    unsigned h2_ = cvtpk(v1_.x, v1_.y), h3_ = cvtpk(v1_.z, v1_.w); \
    float q0_ = v0_.x - __uint_as_float(h0_ << 16); \
    float q1_ = v0_.y - __uint_as_float(h0_ & 0xffff0000u); \
    float q2_ = v0_.z - __uint_as_float(h1_ << 16); \
    float q3_ = v0_.w - __uint_as_float(h1_ & 0xffff0000u); \
    float q4_ = v1_.x - __uint_as_float(h2_ << 16); \
    float q5_ = v1_.y - __uint_as_float(h2_ & 0xffff0000u); \
    float q6_ = v1_.z - __uint_as_float(h3_ << 16); \
    float q7_ = v1_.w - __uint_as_float(h3_ & 0xffff0000u); \
    b8u4 H_, L_; \
    H_.u = (u32x4){h0_, h1_, h2_, h3_}; \
    L_.u = (u32x4){cvtpk(q0_,q1_), cvtpk(q2_,q3_), cvtpk(q4_,q5_), cvtpk(q6_,q7_)}; \
    long bix_ = (((long)(GI*8 + wv)*4 + KT)*64 + lane)*8; \
    bf16x8 bh_ = *(const bf16x8*)&wsBh[bix_]; \
    bf16x8 bl_ = *(const bf16x8*)&wsBl[bix_]; \
    xacc##RS##GI = MF(H_.b, bh_, xacc##RS##GI); \
    xacc##RS##GI = MF(H_.b, bl_, xacc##RS##GI); \
    xacc##RS##GI = MF(L_.b, bh_, xacc##RS##GI); \
} while(0)

#define XI_STORE(PAR) do { \
    _Pragma("unroll") \
    for (int r_ = 0; r_ < 4; ++r_) { \
        xiP[PAR][0][kgrp*4 + r_][c]        = xacc00[r_] + biR; \
        xiP[PAR][0][kgrp*4 + r_][HN + c]   = xacc01[r_] + biZ; \
        xiP[PAR][0][kgrp*4 + r_][2*HN + c] = xacc02[r_] + biN; \
        xiP[PAR][1][kgrp*4 + r_][c]        = xacc10[r_] + biR; \
        xiP[PAR][1][kgrp*4 + r_][HN + c]   = xacc11[r_] + biZ; \
        xiP[PAR][1][kgrp*4 + r_][2*HN + c] = xacc12[r_] + biN; \
    } \
    xacc00 = Z4; xacc01 = Z4; xacc02 = Z4; \
    xacc10 = Z4; xacc11 = Z4; xacc12 = Z4; \
} while(0)

#define CORR_ADD(PAR) do { if (g < G3) { \
    for (int rs_ = 0; rs_ < 2; ++rs_) \
        for (int t_ = 0; t_ < TP; ++t_) { \
            int e_ = eS[rs_][t_]; \
            if (e_ >= 0) xiP[PAR][rs_][t_][g] += corr[(long)e_*G3 + g]; \
        } } } while(0)

#define STEP(T, ...) do { \
    const int arow_ = r16 & 1; \
    bf16x8 hA0_ = *(const bf16x8*)&hSh[cur][arow_][0*32 + kgrp*8]; \
    bf16x8 lA0_ = *(const bf16x8*)&hSl[cur][arow_][0*32 + kgrp*8]; \
    bf16x8 hA1_ = *(const bf16x8*)&hSh[cur][arow_][1*32 + kgrp*8]; \
    bf16x8 lA1_ = *(const bf16x8*)&hSl[cur][arow_][1*32 + kgrp*8]; \
    bf16x8 hA2_ = *(const bf16x8*)&hSh[cur][arow_][2*32 + kgrp*8]; \
    bf16x8 lA2_ = *(const bf16x8*)&hSl[cur][arow_][2*32 + kgrp*8]; \
    bf16x8 hA3_ = *(const bf16x8*)&hSh[cur][arow_][3*32 + kgrp*8]; \
    bf16x8 lA3_ = *(const bf16x8*)&hSl[cur][arow_][3*32 + kgrp*8]; \
    f32x4 gr0_ = Z4, gr1_ = Z4, gz0_ = Z4, gz1_ = Z4, gn0_ = Z4, gn1_ = Z4; \
    gr0_ = MF(hA0_, wBh[0], gr0_);  gr0_ = MF(hA0_, wBl[0], gr0_);  gr0_ = MF(lA0_, wBh[0], gr0_); \
    gr1_ = MF(hA1_, wBh[1], gr1_);  gr1_ = MF(hA1_, wBl[1], gr1_);  gr1_ = MF(lA1_, wBh[1], gr1_); \
    gr0_ = MF(hA2_, wBh[2], gr0_);  gr0_ = MF(hA2_, wBl[2], gr0_);  gr0_ = MF(lA2_, wBh[2], gr0_); \
    gr1_ = MF(hA3_, wBh[3], gr1_);  gr1_ = MF(hA3_, wBl[3], gr1_);  gr1_ = MF(lA3_, wBh[3], gr1_); \
    gz0_ = MF(hA0_, wBh[4], gz0_);  gz0_ = MF(hA0_, wBl[4], gz0_);  gz0_ = MF(lA0_, wBh[4], gz0_); \
    gz1_ = MF(hA1_, wBh[5], gz1_);  gz1_ = MF(hA1_, wBl[5], gz1_);  gz1_ = MF(lA1_, wBh[5], gz1_); \
    gz0_ = MF(hA2_, wBh[6], gz0_);  gz0_ = MF(hA2_, wBl[6], gz0_);  gz0_ = MF(lA2_, wBh[6], gz0_); \
    gz1_ = MF(hA3_, wBh[7], gz1_);  gz1_ = MF(hA3_, wBl[7], gz1_);  gz1_ = MF(lA3_, wBh[7], gz1_); \
    gn0_ = MF(hA0_, wBh[8], gn0_);  gn0_ = MF(hA0_, wBl[8], gn0_);  gn0_ = MF(lA0_, wBh[8], gn0_); \
    gn1_ = MF(hA1_, wBh[9], gn1_);  gn1_ = MF(hA1_, wBl[9], gn1_);  gn1_ = MF(lA1_, wBh[9], gn1_); \
    gn0_ = MF(hA2_, wBh[10], gn0_); gn0_ = MF(hA2_, wBl[10], gn0_); gn0_ = MF(lA2_, wBh[10], gn0_); \
    gn1_ = MF(hA3_, wBh[11], gn1_); gn1_ = MF(hA3_, wBl[11], gn1_); gn1_ = MF(lA3_, wBh[11], gn1_); \
    __VA_ARGS__ \
    float sR_ = gr0_[0] + gr1_[0], tR_ = gr0_[1] + gr1_[1]; \
    float sZ_ = gz0_[0] + gz1_[0], tZ_ = gz0_[1] + gz1_[1]; \
    float sN_ = gn0_[0] + gn1_[0], tN_ = gn0_[1] + gn1_[1]; \
    int ba_ = (lane & 15) << 2; \
    float mR_ = __int_as_float(__builtin_amdgcn_ds_bpermute(ba_, __float_as_int(tR_))); \
    float mZ_ = __int_as_float(__builtin_amdgcn_ds_bpermute(ba_, __float_as_int(tZ_))); \
    float mN_ = __int_as_float(__builtin_amdgcn_ds_bpermute(ba_, __float_as_int(tN_))); \
    float vR_ = (lane < 16) ? sR_ : mR_; \
    float vZ_ = (lane < 16) ? sZ_ : mZ_; \
    float vN_ = (lane < 16) ? sN_ : mN_; \
    if (lane < 32) { \
        int rs_ = lane >> 4; \
        float xr_ = xiP[cp][rs_][T][c]; \
        float xz_ = xiP[cp][rs_][T][HN + c]; \
        float xn_ = xiP[cp][rs_][T][2*HN + c]; \
        float r_ = fsigmoid(xr_ + vR_ + br); \
        float z_ = fsigmoid(xz_ + vZ_ + bz); \
        float n_ = ftanh(xn_ + r_*(vN_ + bn)); \
        float h_ = (1.f - z_)*n_ + z_*hprev; \
        hprev = h_; \
        hOut[rs_][T][c] = h_; \
        unsigned uh_ = cvtpk(h_, 0.f); \
        float fh_ = __uint_as_float(uh_ << 16); \
        unsigned ul_ = cvtpk(h_ - fh_, 0.f); \
        hSh[cur ^ 1][rs_][c] = (unsigned short)uh_; \
        hSl[cur ^ 1][rs_][c] = (unsigned short)ul_; \
    } \
    cur ^= 1; \
    __syncthreads(); \
} while(0)

__global__ __launch_bounds__(512) void k_scanf(
    float* __restrict__ x,
    const unsigned short* __restrict__ wsBh, const unsigned short* __restrict__ wsBl,
    const unsigned short* __restrict__ whBh, const unsigned short* __restrict__ whBl,
    const float* __restrict__ bih, const float* __restrict__ bhh,
    const float* __restrict__ corr, const int* __restrict__ map) {
    const int g = threadIdx.x;
    const int a0 = blockIdx.x;
    const int wv = g >> 6;
    const int lane = g & 63;
    const int r16 = lane & 15;
    const int kgrp = lane >> 4;

    __shared__ float xiP[2][2][TP][XIPAD];      // 99.3 KB (parity double-buffer)
    __shared__ unsigned short hSh[2][2][HN];    // [parity][chain][col]
    __shared__ unsigned short hSl[2][2][HN];
    __shared__ float hOut[2][TP][HN];           // 16 KB
    __shared__ int eS[2][TP];

    // resident whh B-frags: [gate 0..2][kt 0..3] hi/lo
    bf16x8 wBh[12], wBl[12];
    #pragma unroll
    for (int gi = 0; gi < 3; gi++)
        #pragma unroll
        for (int kt = 0; kt < 4; kt++) {
            long bidx = (((long)(gi*8 + wv)*4 + kt)*64 + lane)*8;
            wBh[gi*4+kt] = *(const bf16x8*)&whBh[bidx];
            wBl[gi*4+kt] = *(const bf16x8*)&whBl[bidx];
        }

    const int c = wv*16 + r16;
    const float br = bhh[c],  bz = bhh[HN + c],  bn = bhh[2*HN + c];
    const float biR = bih[c], biZ = bih[HN + c], biN = bih[2*HN + c];
    float hprev = 0.f;                  // lanes<32: chain (lane>>4)

    f32x4 xacc00 = Z4, xacc01 = Z4, xacc02 = Z4;
    f32x4 xacc10 = Z4, xacc11 = Z4, xacc12 = Z4;

    if (g < 2*HN) {
        ((unsigned short*)hSh)[g] = 0;
        ((unsigned short*)hSl)[g] = 0;
    }
    int cur = 0;
    int xrow = 0;

    // ---- prologue: xi(panel 0) + corr(0) ----
    if (g < 32) eS[g >> 4][g & 15] = map[(long)(a0 + (g >> 4)*256)*VN + (g & 15)];
    XI_ITEM(0,0,0); XI_ITEM(0,0,1); XI_ITEM(0,0,2); XI_ITEM(0,0,3);
    XI_ITEM(0,1,0); XI_ITEM(0,1,1); XI_ITEM(0,1,2); XI_ITEM(0,1,3);
    XI_ITEM(0,2,0); XI_ITEM(0,2,1); XI_ITEM(0,2,2); XI_ITEM(0,2,3);
    XI_ITEM(1,0,0); XI_ITEM(1,0,1); XI_ITEM(1,0,2); XI_ITEM(1,0,3);
    XI_ITEM(1,1,0); XI_ITEM(1,1,1); XI_ITEM(1,1,2); XI_ITEM(1,1,3);
    XI_ITEM(1,2,0); XI_ITEM(1,2,1); XI_ITEM(1,2,2); XI_ITEM(1,2,3);
    XI_STORE(0);
    __syncthreads();
    CORR_ADD(0);

    for (int p0 = 0; p0 < VN; p0 += TP) {
        const int cp = (p0 >> 4) & 1;
        const int np = cp ^ 1;
        const bool hasnext = (p0 + TP) < VN;

        // write back prev panel's h (same barrier region as CORR_ADD; disjoint memory)
        if (p0 > 0) {
            int pp = p0 - TP;
            for (int idx = g; idx < 2*TP*32; idx += 512) {
                int rs = idx >> 9, j = idx & 511, t = j >> 5, c4 = j & 31;
                *(float4*)&x[((long)(a0 + rs*256)*VN + pp + t)*HN + c4*4] =
                    *(const float4*)&hOut[rs][t][c4*4];
            }
        }
        __syncthreads();

        xrow = p0 + TP;
        STEP(0,  if (hasnext) { if (g < 32) eS[g >> 4][g & 15] =
                     map[(long)(a0 + (g >> 4)*256)*VN + xrow + (g & 15)];
                     XI_ITEM(0,0,0); } );
        STEP(1,  if (hasnext) { XI_ITEM(0,0,1); XI_ITEM(0,0,2); } );
        STEP(2,  if (hasnext) { XI_ITEM(0,0,3); } );
        STEP(3,  if (hasnext) { XI_ITEM(0,1,0); XI_ITEM(0,1,1); } );
        STEP(4,  if (hasnext) { XI_ITEM(0,1,2); } );
        STEP(5,  if (hasnext) { XI_ITEM(0,1,3); XI_ITEM(0,2,0); } );
        STEP(6,  if (hasnext) { XI_ITEM(0,2,1); } );
        STEP(7,  if (hasnext) { XI_ITEM(0,2,2); XI_ITEM(0,2,3); } );
        STEP(8,  if (hasnext) { XI_ITEM(1,0,0); } );
        STEP(9,  if (hasnext) { XI_ITEM(1,0,1); XI_ITEM(1,0,2); } );
        STEP(10, if (hasnext) { XI_ITEM(1,0,3); } );
        STEP(11, if (hasnext) { XI_ITEM(1,1,0); XI_ITEM(1,1,1); } );
        STEP(12, if (hasnext) { XI_ITEM(1,1,2); } );
        STEP(13, if (hasnext) { XI_ITEM(1,1,3); XI_ITEM(1,2,0); } );
        STEP(14, if (hasnext) { XI_ITEM(1,2,1); } );
        STEP(15, if (hasnext) { XI_ITEM(1,2,2); XI_ITEM(1,2,3); XI_STORE(np); } );

        if (hasnext) CORR_ADD(np);
    }
    // ---- final write-back ----
    {
        int pp = VN - TP;
        for (int idx = g; idx < 2*TP*32; idx += 512) {
            int rs = idx >> 9, j = idx & 511, t = j >> 5, c4 = j & 31;
            *(float4*)&x[((long)(a0 + rs*256)*VN + pp + t)*HN + c4*4] =
                *(const float4*)&hOut[rs][t][c4*4];
        }
    }
}

extern "C" void kernel_launch(void* const* d_in, const int* in_sizes, int n_in,
                              void* d_out, int out_size, void* d_ws, size_t ws_size,
                              hipStream_t stream) {
    const float* adj   = (const float*)d_in[0];
    const void*  edges = d_in[1];
    const float* emb   = (const float*)d_in[2];
    const float* w1    = (const float*)d_in[3];
    const float* w2    = (const float*)d_in[4];
    const float* w3    = (const float*)d_in[5];
    const float* wih   = (const float*)d_in[6];
    const float* whh   = (const float*)d_in[7];
    const float* bih   = (const float*)d_in[8];
    const float* bhh   = (const float*)d_in[9];

    float* x = (float*)d_out;          // x lives in d_out; scan updates it in place

    char* p = (char*)d_ws;
    auto alloc = [&](size_t bytes) { char* r = p; p += (bytes + 255) & ~255UL; return r; };
    float* in3    = (float*)alloc((size_t)EN*G3*4);
    float* corr   = (float*)alloc((size_t)EN*G3*4);
    float* colsum = (float*)alloc((size_t)VN*HN*4);
    int*   nnz    = (int*)  alloc((size_t)VN*4);
    int*   map    = (int*)  alloc((size_t)NROWS*4);
    int*   uA     = (int*)  alloc((size_t)EN*4);
    int*   vA     = (int*)  alloc((size_t)EN*4);
    unsigned short* wsBh = (unsigned short*)alloc((size_t)24*4*64*8*2);
    unsigned short* wsBl = (unsigned short*)alloc((size_t)24*4*64*8*2);
    unsigned short* whBh = (unsigned short*)alloc((size_t)24*4*64*8*2);
    unsigned short* whBl = (unsigned short*)alloc((size_t)24*4*64*8*2);
    unsigned short* wlBh = (unsigned short*)alloc((size_t)24*4*64*8*2);
    unsigned short* wlBl = (unsigned short*)alloc((size_t)24*4*64*8*2);
    unsigned short* wcBh = (unsigned short*)alloc((size_t)3*8*12*64*8*2);
    unsigned short* wcBl = (unsigned short*)alloc((size_t)3*8*12*64*8*2);

    k_edges<<<EN/256, 256, 0, stream>>>(edges, uA, vA);
    k_pack<<<(3*8*12*64*8 + 255)/256, 256, 0, stream>>>(w1, w2, w3, wih, whh,
        wsBh, wsBl, whBh, whBl, wlBh, wlBl, wcBh, wcBl);
    k_fill<<<NROWS/256, 256, 0, stream>>>(map, -1, NROWS);
    k_map<<<EN/256, 256, 0, stream>>>(uA, vA, map);
    k_embed<<<NROWS/2, 256, 0, stream>>>(adj, emb, x);

    for (int l = 0; l < LN; l++) {
        k_colsum<<<VN, 512, 0, stream>>>(x, colsum, nnz);
        k_edgein<<<EN/4, 256, 0, stream>>>(x, uA, vA, colsum, nnz, in3);
        k_msgcorr<<<EN/16, 512, 0, stream>>>(in3, wcBh + (long)l*8*12*64*8, wcBl + (long)l*8*12*64*8,
                                             wlBh, wlBl, corr);
        k_scanf<<<VN/2, 512, 0, stream>>>(x, wsBh, wsBl, whBh, whBl, bih, bhh, corr, map);
    }
}

// Round 10
// 2372.190 us; speedup vs baseline: 17.4782x; 1.3447x over previous
//
#include <hip/hip_runtime.h>

#define VN 512
#define EN 32768
#define FN 8
#define HN 128
#define G3 384
#define LN 3
#define TP 16
#define NROWS (VN*VN)   // 262144
#define XIPAD 388       // 4*388 % 32 == 16 -> 2-way LDS aliasing (free)

typedef short bf16x8 __attribute__((ext_vector_type(8)));
typedef float f32x4  __attribute__((ext_vector_type(4)));
typedef unsigned int u32x4 __attribute__((ext_vector_type(4)));
union b8u4 { u32x4 u; bf16x8 b; };

__device__ __forceinline__ unsigned short f2bf(float f) {
    unsigned int u = __float_as_uint(f);
    unsigned int r = (u + 0x7FFFu + ((u >> 16) & 1u)) >> 16;
    return (unsigned short)r;
}
__device__ __forceinline__ unsigned cvtpk(float a, float b) {
    unsigned r;
    asm("v_cvt_pk_bf16_f32 %0, %1, %2" : "=v"(r) : "v"(a), "v"(b));
    return r;   // lo16 = bf16(a), hi16 = bf16(b)
}
__device__ __forceinline__ float fexp2(float x) {
    float r; asm("v_exp_f32 %0, %1" : "=v"(r) : "v"(x)); return r;
}
__device__ __forceinline__ float frcp(float x) {
    float r; asm("v_rcp_f32 %0, %1" : "=v"(r) : "v"(x)); return r;
}
__device__ __forceinline__ float fsigmoid(float x) {
    return frcp(1.f + fexp2(x * -1.44269504089f));
}
__device__ __forceinline__ float ftanh(float x) {
    return 1.f - 2.f * frcp(1.f + fexp2(x * 2.88539008178f));
}

// ---------------- generic int fill ----------------
__global__ void k_fill(int* __restrict__ p, int val, int n) {
    int i = blockIdx.x * 256 + threadIdx.x;
    if (i < n) p[i] = val;
}

// ---------------- edge canonicalize (+ int64 detection) ----------------
__global__ void k_edges(const void* __restrict__ raw, int* __restrict__ uo, int* __restrict__ vo) {
    const int* r32 = (const int*)raw;
    const long long* r64 = (const long long*)raw;
    int acc = 0;
    #pragma unroll
    for (int i = 1; i < 128; i += 2) acc |= r32[i];
    bool is64 = (acc == 0);
    int e = blockIdx.x * 256 + threadIdx.x;
    if (e < EN) {
        int u, v;
        if (is64) { u = (int)r64[2*e]; v = (int)r64[2*e+1]; }
        else      { u = r32[2*e];      v = r32[2*e+1]; }
        uo[e] = u; vo[e] = v;
    }
}

// ---------------- pack ALL weight B-fragments (bf16 hi/lo, MFMA lane layout) ----------------
__global__ void k_pack(const float* __restrict__ w1, const float* __restrict__ w2,
                       const float* __restrict__ w3, const float* __restrict__ wih,
                       const float* __restrict__ whh,
                       unsigned short* __restrict__ wsBh, unsigned short* __restrict__ wsBl,
                       unsigned short* __restrict__ whBh, unsigned short* __restrict__ whBl,
                       unsigned short* __restrict__ wlBh, unsigned short* __restrict__ wlBl,
                       unsigned short* __restrict__ wcBh, unsigned short* __restrict__ wcBl) {
    int t = blockIdx.x * 256 + threadIdx.x;
    if (t < 3*8*12*64*8) {        // wcat frags [l][nt0..7][kt0..11]
        int e = t & 7, lane = (t >> 3) & 63;
        int frag = t >> 9;
        int kt = frag % 12;
        int rem = frag / 12;
        int nt = rem & 7;
        int l  = rem >> 3;
        int k  = kt*32 + (lane >> 4)*8 + e;
        int gc = nt*16 + (lane & 15);
        const float* w = (k < 128) ? w1 : (k < 256 ? w2 : w3);
        float val = w[((long)l*128 + gc)*128 + (k & 127)];
        unsigned short hi = f2bf(val);
        wcBh[t] = hi;
        wcBl[t] = f2bf(val - __uint_as_float((unsigned int)hi << 16));
    }
    if (t < 24*4*64*8) {          // wsum / whh / wl frags [nt0..23][kt0..3]
        int e = t & 7, lane = (t >> 3) & 63, kt = (t >> 9) & 3, nt = t >> 11;
        int k  = kt*32 + (lane >> 4)*8 + e;
        int gc = nt*16 + (lane & 15);
        float vs = wih[gc*256 + k] + wih[gc*256 + 128 + k];
        unsigned short hi = f2bf(vs);
        wsBh[t] = hi; wsBl[t] = f2bf(vs - __uint_as_float((unsigned int)hi << 16));
        float vh = whh[gc*HN + k];
        hi = f2bf(vh);
        whBh[t] = hi; whBl[t] = f2bf(vh - __uint_as_float((unsigned int)hi << 16));
        float vl = wih[gc*256 + k];
        hi = f2bf(vl);
        wlBh[t] = hi; wlBl[t] = f2bf(vl - __uint_as_float((unsigned int)hi << 16));
    }
}

// ---------------- winner map ----------------
__global__ void k_map(const int* __restrict__ uA, const int* __restrict__ vA, int* __restrict__ map) {
    int e = blockIdx.x * 256 + threadIdx.x;
    if (e < EN) atomicMax(&map[uA[e]*VN + vA[e]], e);
}

// ---------------- embed ----------------
__global__ __launch_bounds__(256) void k_embed(const float* __restrict__ adj,
                                               const float* __restrict__ emb,
                                               float* __restrict__ x) {
    __shared__ float semb[HN][FN];
    __shared__ float sadj[2][FN];
    int tid = threadIdx.x;
    for (int i = tid; i < HN*FN; i += 256) semb[i/FN][i%FN] = emb[i];
    if (tid < 16) sadj[tid>>3][tid&7] = adj[(long)blockIdx.x*16 + tid];
    __syncthreads();
    int p = tid >> 7;
    int h = tid & 127;
    float acc = 0.f;
    #pragma unroll
    for (int f = 0; f < FN; f++) acc += sadj[p][f]*semb[h][f];
    long row = (long)blockIdx.x*2 + p;
    x[row*HN + h] = acc;
}

// ---------------- colsum + nnz ----------------
__global__ __launch_bounds__(512) void k_colsum(const float* __restrict__ x,
                                                float* __restrict__ colsum, int* __restrict__ nnz) {
    int b = blockIdx.x;
    int tid = threadIdx.x;
    int h = tid & 127, q = tid >> 7;
    float s = 0.f; int c = 0;
    for (int a = q*128; a < q*128 + 128; a++) {
        float v = x[((long)a*VN + b)*HN + h];
        s += v; c += (v != 0.f) ? 1 : 0;
    }
    __shared__ float ss[4][128];
    __shared__ int sc[8];
    ss[q][h] = s;
    #pragma unroll
    for (int off = 32; off; off >>= 1) c += __shfl_down(c, off);
    if ((tid & 63) == 0) sc[tid>>6] = c;
    __syncthreads();
    if (tid < 128) colsum[b*HN + tid] = ss[0][tid]+ss[1][tid]+ss[2][tid]+ss[3][tid];
    if (tid == 0) { int t = 0; for (int i = 0; i < 8; i++) t += sc[i]; nnz[b] = t; }
}

// ---------------- edge inputs ----------------
__global__ __launch_bounds__(256) void k_edgein(const float* __restrict__ x,
    const int* __restrict__ uA, const int* __restrict__ vA,
    const float* __restrict__ colsum, const int* __restrict__ nnz, float* __restrict__ in3) {
    int w = threadIdx.x >> 6;
    int lane = threadIdx.x & 63;
    int e = blockIdx.x*4 + w;
    int u = uA[e], v = vA[e];
    const float* xuv = x + ((long)u*VN + v)*HN;
    const float* xvu = x + ((long)v*VN + u)*HN;
    float xu0 = xuv[lane], xu1 = xuv[lane+64];
    float xv0 = xvu[lane], xv1 = xvu[lane+64];
    int cnt_vu = __popcll(__ballot(xv0 != 0.f)) + __popcll(__ballot(xv1 != 0.f));
    int cnt_uv = __popcll(__ballot(xu0 != 0.f)) + __popcll(__ballot(xu1 != 0.f));
    float nin  = (float)(nnz[u] - cnt_vu) * (1.f/128.f); if (nin  == 0.f) nin  = 1.f;
    float nout = (float)(nnz[v] - cnt_uv) * (1.f/128.f); if (nout == 0.f) nout = 1.f;
    float* o = in3 + (long)e*G3;
    o[lane]        = xu0;  o[lane+64]      = xu1;
    o[128+lane]    = (colsum[u*HN+lane]    - xv0)/nin;
    o[128+lane+64] = (colsum[u*HN+lane+64] - xv1)/nin;
    o[256+lane]    = (colsum[v*HN+lane]    - xu0)/nout;
    o[256+lane+64] = (colsum[v*HN+lane+64] - xu1)/nout;
}

// ---------------- fused msg+corr (MFMA) ----------------
__global__ __launch_bounds__(512) void k_msgcorr(
    const float* __restrict__ in3,
    const unsigned short* __restrict__ wcBh, const unsigned short* __restrict__ wcBl,
    const unsigned short* __restrict__ wlBh, const unsigned short* __restrict__ wlBl,
    float* __restrict__ corr) {
    const int g = threadIdx.x;
    const int wv = g >> 6;
    const int lane = g & 63;
    const int r16 = lane & 15;
    const int kgrp = lane >> 4;
    const long m0 = (long)blockIdx.x * 16;

    __shared__ unsigned short Dh[16][136];
    __shared__ unsigned short Dl[16][136];

    f32x4 pacc[2];
    pacc[0] = (f32x4){0.f,0.f,0.f,0.f};
    pacc[1] = (f32x4){0.f,0.f,0.f,0.f};
    #pragma unroll
    for (int kt = 0; kt < 12; kt++) {
        const float* xs = &in3[(m0 + r16)*G3 + kt*32 + kgrp*8];
        float4 v0 = *(const float4*)xs;
        float4 v1 = *(const float4*)(xs + 4);
        unsigned h0 = cvtpk(v0.x, v0.y), h1 = cvtpk(v0.z, v0.w);
        unsigned h2 = cvtpk(v1.x, v1.y), h3 = cvtpk(v1.z, v1.w);
        float q0 = v0.x - __uint_as_float(h0 << 16);
        float q1 = v0.y - __uint_as_float(h0 & 0xffff0000u);
        float q2 = v0.z - __uint_as_float(h1 << 16);
        float q3 = v0.w - __uint_as_float(h1 & 0xffff0000u);
        float q4 = v1.x - __uint_as_float(h2 << 16);
        float q5 = v1.y - __uint_as_float(h2 & 0xffff0000u);
        float q6 = v1.z - __uint_as_float(h3 << 16);
        float q7 = v1.w - __uint_as_float(h3 & 0xffff0000u);
        b8u4 H, L;
        H.u = (u32x4){h0, h1, h2, h3};
        L.u = (u32x4){cvtpk(q0,q1), cvtpk(q2,q3), cvtpk(q4,q5), cvtpk(q6,q7)};
        long bidx = (((long)wv*12 + kt)*64 + lane)*8;
        bf16x8 bh = *(const bf16x8*)&wcBh[bidx];
        bf16x8 bl = *(const bf16x8*)&wcBl[bidx];
        const int p = kt & 1;
        pacc[p] = __builtin_amdgcn_mfma_f32_16x16x32_bf16(H.b, bh, pacc[p], 0, 0, 0);
        pacc[p] = __builtin_amdgcn_mfma_f32_16x16x32_bf16(H.b, bl, pacc[p], 0, 0, 0);
        pacc[p] = __builtin_amdgcn_mfma_f32_16x16x32_bf16(L.b, bh, pacc[p], 0, 0, 0);
    }
    const int c = wv*16 + r16;
    #pragma unroll
    for (int r = 0; r < 4; r++) {
        int m = kgrp*4 + r;
        float mv = fmaxf(pacc[0][r] + pacc[1][r], 0.f) - in3[(m0 + m)*G3 + c];
        unsigned short hi = f2bf(mv);
        Dh[m][c] = hi;
        Dl[m][c] = f2bf(mv - __uint_as_float((unsigned int)hi << 16));
    }
    __syncthreads();

    f32x4 cacc[3];
    cacc[0] = cacc[1] = cacc[2] = (f32x4){0.f,0.f,0.f,0.f};
    #pragma unroll
    for (int kt = 0; kt < 4; kt++) {
        bf16x8 ah = *(const bf16x8*)&Dh[r16][kt*32 + kgrp*8];
        bf16x8 al = *(const bf16x8*)&Dl[r16][kt*32 + kgrp*8];
        #pragma unroll
        for (int j = 0; j < 3; j++) {
            long bidx = (((long)(wv*3 + j)*4 + kt)*64 + lane)*8;
            bf16x8 bh = *(const bf16x8*)&wlBh[bidx];
            bf16x8 bl = *(const bf16x8*)&wlBl[bidx];
            cacc[j] = __builtin_amdgcn_mfma_f32_16x16x32_bf16(ah, bh, cacc[j], 0, 0, 0);
            cacc[j] = __builtin_amdgcn_mfma_f32_16x16x32_bf16(ah, bl, cacc[j], 0, 0, 0);
            cacc[j] = __builtin_amdgcn_mfma_f32_16x16x32_bf16(al, bh, cacc[j], 0, 0, 0);
        }
    }
    #pragma unroll
    for (int j = 0; j < 3; j++) {
        int n = (wv*3 + j)*16 + r16;
        #pragma unroll
        for (int r = 0; r < 4; r++)
            corr[(m0 + kgrp*4 + r)*G3 + n] = cacc[j][r];
    }
}

// ================= fused xi(MFMA) + GRU scan (v8: no vmem in steps) =================
// 256 blocks x 512 threads (8 waves); block owns chains {a0, a0+256}.
// Per panel: phase A does ALL vmem (hOut writeback, eS, corr gather, stage x(p+1)
// pre-converted to bf16 hi/lo in XOR-swizzled LDS) behind 2 barriers; the 16 gate
// steps are pure LDS/MFMA/VALU, so per-step barriers drain only lgkmcnt.

#define MF(A,B,C) __builtin_amdgcn_mfma_f32_16x16x32_bf16((A),(B),(C),0,0,0)
#define Z4 ((f32x4){0.f,0.f,0.f,0.f})

// stage x rows [ROWBASE, ROWBASE+16) of both chains into xS[PAR] (bf16 hi/lo, swizzled)
#define STAGE(PAR, ROWBASE) do { \
    int rs_ = g >> 8, row_ = (g >> 4) & 15, cg_ = g & 15; \
    const float* xs_ = &x[((long)(a0 + rs_*256)*VN + (ROWBASE) + row_)*HN + cg_*8]; \
    float4 v0_ = *(const float4*)xs_; \
    float4 v1_ = *(const float4*)(xs_ + 4); \
    unsigned h0_ = cvtpk(v0_.x, v0_.y), h1_ = cvtpk(v0_.z, v0_.w); \
    unsigned h2_ = cvtpk(v1_.x, v1_.y), h3_ = cvtpk(v1_.z, v1_.w); \
    float q0_ = v0_.x - __uint_as_float(h0_ << 16); \
    float q1_ = v0_.y - __uint_as_float(h0_ & 0xffff0000u); \
    float q2_ = v0_.z - __uint_as_float(h1_ << 16); \
    float q3_ = v0_.w - __uint_as_float(h1_ & 0xffff0000u); \
    float q4_ = v1_.x - __uint_as_float(h2_ << 16); \
    float q5_ = v1_.y - __uint_as_float(h2_ & 0xffff0000u); \
    float q6_ = v1_.z - __uint_as_float(h3_ << 16); \
    float q7_ = v1_.w - __uint_as_float(h3_ & 0xffff0000u); \
    b8u4 H_, L_; \
    H_.u = (u32x4){h0_, h1_, h2_, h3_}; \
    L_.u = (u32x4){cvtpk(q0_,q1_), cvtpk(q2_,q3_), cvtpk(q4_,q5_), cvtpk(q6_,q7_)}; \
    int sc_ = (cg_*8) ^ ((row_ & 7) << 3); \
    *(bf16x8*)&xSh[PAR][rs_][row_][sc_] = H_.b; \
    *(bf16x8*)&xSl[PAR][rs_][row_][sc_] = L_.b; \
} while(0)

// one xi sub-GEMM item: A-frag from swizzled LDS, B-frag from L2. Pure LDS+MFMA.
#define XI_ITEM(RS, GI, KT) do { \
    int sc_ = ((KT)*32 + kgrp*8) ^ ((r16 & 7) << 3); \
    bf16x8 H_ = *(const bf16x8*)&xSh[np][RS][r16][sc_]; \
    bf16x8 L_ = *(const bf16x8*)&xSl[np][RS][r16][sc_]; \
    long bix_ = (((long)((GI)*8 + wv)*4 + (KT))*64 + lane)*8; \
    bf16x8 bh_ = *(const bf16x8*)&wsBh[bix_]; \
    bf16x8 bl_ = *(const bf16x8*)&wsBl[bix_]; \
    xacc##RS##GI = MF(H_, bh_, xacc##RS##GI); \
    xacc##RS##GI = MF(H_, bl_, xacc##RS##GI); \
    xacc##RS##GI = MF(L_, bh_, xacc##RS##GI); \
} while(0)

#define XI_STORE(PAR) do { \
    _Pragma("unroll") \
    for (int r_ = 0; r_ < 4; ++r_) { \
        xiP[PAR][0][kgrp*4 + r_][c]        = xacc00[r_] + biR; \
        xiP[PAR][0][kgrp*4 + r_][HN + c]   = xacc01[r_] + biZ; \
        xiP[PAR][0][kgrp*4 + r_][2*HN + c] = xacc02[r_] + biN; \
        xiP[PAR][1][kgrp*4 + r_][c]        = xacc10[r_] + biR; \
        xiP[PAR][1][kgrp*4 + r_][HN + c]   = xacc11[r_] + biZ; \
        xiP[PAR][1][kgrp*4 + r_][2*HN + c] = xacc12[r_] + biN; \
    } \
    xacc00 = Z4; xacc01 = Z4; xacc02 = Z4; \
    xacc10 = Z4; xacc11 = Z4; xacc12 = Z4; \
} while(0)

#define CORR_ADD(PAR) do { if (g < G3) { \
    for (int rs_ = 0; rs_ < 2; ++rs_) \
        for (int t_ = 0; t_ < TP; ++t_) { \
            int e_ = eS[rs_][t_]; \
            if (e_ >= 0) xiP[PAR][rs_][t_][g] += corr[(long)e_*G3 + g]; \
        } } } while(0)

#define STEP(T, ...) do { \
    const int arow_ = r16 & 1; \
    bf16x8 hA0_ = *(const bf16x8*)&hSh[cur][arow_][0*32 + kgrp*8]; \
    bf16x8 lA0_ = *(const bf16x8*)&hSl[cur][arow_][0*32 + kgrp*8]; \
    bf16x8 hA1_ = *(const bf16x8*)&hSh[cur][arow_][1*32 + kgrp*8]; \
    bf16x8 lA1_ = *(const bf16x8*)&hSl[cur][arow_][1*32 + kgrp*8]; \
    bf16x8 hA2_ = *(const bf16x8*)&hSh[cur][arow_][2*32 + kgrp*8]; \
    bf16x8 lA2_ = *(const bf16x8*)&hSl[cur][arow_][2*32 + kgrp*8]; \
    bf16x8 hA3_ = *(const bf16x8*)&hSh[cur][arow_][3*32 + kgrp*8]; \
    bf16x8 lA3_ = *(const bf16x8*)&hSl[cur][arow_][3*32 + kgrp*8]; \
    f32x4 gr0_ = Z4, gr1_ = Z4, gz0_ = Z4, gz1_ = Z4, gn0_ = Z4, gn1_ = Z4; \
    gr0_ = MF(hA0_, wBh[0], gr0_);  gr0_ = MF(hA0_, wBl[0], gr0_);  gr0_ = MF(lA0_, wBh[0], gr0_); \
    gr1_ = MF(hA1_, wBh[1], gr1_);  gr1_ = MF(hA1_, wBl[1], gr1_);  gr1_ = MF(lA1_, wBh[1], gr1_); \
    gr0_ = MF(hA2_, wBh[2], gr0_);  gr0_ = MF(hA2_, wBl[2], gr0_);  gr0_ = MF(lA2_, wBh[2], gr0_); \
    gr1_ = MF(hA3_, wBh[3], gr1_);  gr1_ = MF(hA3_, wBl[3], gr1_);  gr1_ = MF(lA3_, wBh[3], gr1_); \
    gz0_ = MF(hA0_, wBh[4], gz0_);  gz0_ = MF(hA0_, wBl[4], gz0_);  gz0_ = MF(lA0_, wBh[4], gz0_); \
    gz1_ = MF(hA1_, wBh[5], gz1_);  gz1_ = MF(hA1_, wBl[5], gz1_);  gz1_ = MF(lA1_, wBh[5], gz1_); \
    gz0_ = MF(hA2_, wBh[6], gz0_);  gz0_ = MF(hA2_, wBl[6], gz0_);  gz0_ = MF(lA2_, wBh[6], gz0_); \
    gz1_ = MF(hA3_, wBh[7], gz1_);  gz1_ = MF(hA3_, wBl[7], gz1_);  gz1_ = MF(lA3_, wBh[7], gz1_); \
    gn0_ = MF(hA0_, wBh[8], gn0_);  gn0_ = MF(hA0_, wBl[8], gn0_);  gn0_ = MF(lA0_, wBh[8], gn0_); \
    gn1_ = MF(hA1_, wBh[9], gn1_);  gn1_ = MF(hA1_, wBl[9], gn1_);  gn1_ = MF(lA1_, wBh[9], gn1_); \
    gn0_ = MF(hA2_, wBh[10], gn0_); gn0_ = MF(hA2_, wBl[10], gn0_); gn0_ = MF(lA2_, wBh[10], gn0_); \
    gn1_ = MF(hA3_, wBh[11], gn1_); gn1_ = MF(hA3_, wBl[11], gn1_); gn1_ = MF(lA3_, wBh[11], gn1_); \
    __VA_ARGS__ \
    float sR_ = gr0_[0] + gr1_[0], tR_ = gr0_[1] + gr1_[1]; \
    float sZ_ = gz0_[0] + gz1_[0], tZ_ = gz0_[1] + gz1_[1]; \
    float sN_ = gn0_[0] + gn1_[0], tN_ = gn0_[1] + gn1_[1]; \
    int ba_ = (lane & 15) << 2; \
    float mR_ = __int_as_float(__builtin_amdgcn_ds_bpermute(ba_, __float_as_int(tR_))); \
    float mZ_ = __int_as_float(__builtin_amdgcn_ds_bpermute(ba_, __float_as_int(tZ_))); \
    float mN_ = __int_as_float(__builtin_amdgcn_ds_bpermute(ba_, __float_as_int(tN_))); \
    float vR_ = (lane < 16) ? sR_ : mR_; \
    float vZ_ = (lane < 16) ? sZ_ : mZ_; \
    float vN_ = (lane < 16) ? sN_ : mN_; \
    if (lane < 32) { \
        int rs_ = lane >> 4; \
        float xr_ = xiP[cp][rs_][T][c]; \
        float xz_ = xiP[cp][rs_][T][HN + c]; \
        float xn_ = xiP[cp][rs_][T][2*HN + c]; \
        float r_ = fsigmoid(xr_ + vR_ + br); \
        float z_ = fsigmoid(xz_ + vZ_ + bz); \
        float n_ = ftanh(xn_ + r_*(vN_ + bn)); \
        float h_ = (1.f - z_)*n_ + z_*hprev; \
        hprev = h_; \
        hOut[rs_][T][c] = h_; \
        unsigned uh_ = cvtpk(h_, 0.f); \
        float fh_ = __uint_as_float(uh_ << 16); \
        unsigned ul_ = cvtpk(h_ - fh_, 0.f); \
        hSh[cur ^ 1][rs_][c] = (unsigned short)uh_; \
        hSl[cur ^ 1][rs_][c] = (unsigned short)ul_; \
    } \
    cur ^= 1; \
    __syncthreads(); \
} while(0)

__global__ __launch_bounds__(512) void k_scanf(
    float* __restrict__ x,
    const unsigned short* __restrict__ wsBh, const unsigned short* __restrict__ wsBl,
    const unsigned short* __restrict__ whBh, const unsigned short* __restrict__ whBl,
    const float* __restrict__ bih, const float* __restrict__ bhh,
    const float* __restrict__ corr, const int* __restrict__ map) {
    const int g = threadIdx.x;
    const int a0 = blockIdx.x;
    const int wv = g >> 6;
    const int lane = g & 63;
    const int r16 = lane & 15;
    const int kgrp = lane >> 4;

    __shared__ float xiP[2][2][TP][XIPAD];          // 99.3 KB
    __shared__ unsigned short xSh[2][2][TP][HN];    // 16 KB (parity, chain, row, swz col)
    __shared__ unsigned short xSl[2][2][TP][HN];    // 16 KB
    __shared__ unsigned short hSh[2][2][HN];        // [parity][chain][col]
    __shared__ unsigned short hSl[2][2][HN];
    __shared__ float hOut[2][TP][HN];               // 16 KB
    __shared__ int eS[2][TP];

    // resident whh B-frags: [gate 0..2][kt 0..3] hi/lo
    bf16x8 wBh[12], wBl[12];
    #pragma unroll
    for (int gi = 0; gi < 3; gi++)
        #pragma unroll
        for (int kt = 0; kt < 4; kt++) {
            long bidx = (((long)(gi*8 + wv)*4 + kt)*64 + lane)*8;
            wBh[gi*4+kt] = *(const bf16x8*)&whBh[bidx];
            wBl[gi*4+kt] = *(const bf16x8*)&whBl[bidx];
        }

    const int c = wv*16 + r16;
    const float br = bhh[c],  bz = bhh[HN + c],  bn = bhh[2*HN + c];
    const float biR = bih[c], biZ = bih[HN + c], biN = bih[2*HN + c];
    float hprev = 0.f;                  // lanes<32: chain (lane>>4)

    f32x4 xacc00 = Z4, xacc01 = Z4, xacc02 = Z4;
    f32x4 xacc10 = Z4, xacc11 = Z4, xacc12 = Z4;

    if (g < 2*HN) {
        ((unsigned short*)hSh)[g] = 0;
        ((unsigned short*)hSl)[g] = 0;
    }
    int cur = 0;

    // ---- prologue: stage panel 0, compute xi(0) ----
    STAGE(0, 0);
    __syncthreads();
    {
        const int np = 0;   // xi target parity for panel 0
        XI_ITEM(0,0,0); XI_ITEM(0,0,1); XI_ITEM(0,0,2); XI_ITEM(0,0,3);
        XI_ITEM(0,1,0); XI_ITEM(0,1,1); XI_ITEM(0,1,2); XI_ITEM(0,1,3);
        XI_ITEM(0,2,0); XI_ITEM(0,2,1); XI_ITEM(0,2,2); XI_ITEM(0,2,3);
        XI_ITEM(1,0,0); XI_ITEM(1,0,1); XI_ITEM(1,0,2); XI_ITEM(1,0,3);
        XI_ITEM(1,1,0); XI_ITEM(1,1,1); XI_ITEM(1,1,2); XI_ITEM(1,1,3);
        XI_ITEM(1,2,0); XI_ITEM(1,2,1); XI_ITEM(1,2,2); XI_ITEM(1,2,3);
        XI_STORE(0);
    }

    for (int p0 = 0; p0 < VN; p0 += TP) {
        const int cp = (p0 >> 4) & 1;
        const int np = cp ^ 1;
        const bool hasnext = (p0 + TP) < VN;

        // ---- phase A region 1: writeback(p-1), eS(p), stage x(p+1) ----
        if (p0 > 0) {
            int pp = p0 - TP;
            for (int idx = g; idx < 2*TP*32; idx += 512) {
                int rs = idx >> 9, j = idx & 511, t = j >> 5, c4 = j & 31;
                *(float4*)&x[((long)(a0 + rs*256)*VN + pp + t)*HN + c4*4] =
                    *(const float4*)&hOut[rs][t][c4*4];
            }
        }
        if (g < 32) eS[g >> 4][g & 15] = map[(long)(a0 + (g >> 4)*256)*VN + p0 + (g & 15)];
        if (hasnext) STAGE(np, p0 + TP);
        __syncthreads();

        // ---- phase A region 2: corr gather into xiP(p) ----
        CORR_ADD(cp);
        __syncthreads();

        // ---- 16 gate steps (pure LDS/MFMA/VALU), xi(p+1) interleaved ----
        STEP(0,  if (hasnext) { XI_ITEM(0,0,0); XI_ITEM(0,0,1); } );
        STEP(1,  if (hasnext) { XI_ITEM(0,0,2); } );
        STEP(2,  if (hasnext) { XI_ITEM(0,0,3); XI_ITEM(0,1,0); } );
        STEP(3,  if (hasnext) { XI_ITEM(0,1,1); } );
        STEP(4,  if (hasnext) { XI_ITEM(0,1,2); XI_ITEM(0,1,3); } );
        STEP(5,  if (hasnext) { XI_ITEM(0,2,0); } );
        STEP(6,  if (hasnext) { XI_ITEM(0,2,1); XI_ITEM(0,2,2); } );
        STEP(7,  if (hasnext) { XI_ITEM(0,2,3); } );
        STEP(8,  if (hasnext) { XI_ITEM(1,0,0); XI_ITEM(1,0,1); } );
        STEP(9,  if (hasnext) { XI_ITEM(1,0,2); } );
        STEP(10, if (hasnext) { XI_ITEM(1,0,3); XI_ITEM(1,1,0); } );
        STEP(11, if (hasnext) { XI_ITEM(1,1,1); } );
        STEP(12, if (hasnext) { XI_ITEM(1,1,2); XI_ITEM(1,1,3); } );
        STEP(13, if (hasnext) { XI_ITEM(1,2,0); } );
        STEP(14, if (hasnext) { XI_ITEM(1,2,1); XI_ITEM(1,2,2); } );
        STEP(15, if (hasnext) { XI_ITEM(1,2,3); XI_STORE(np); } );
    }
    // ---- final write-back ----
    {
        int pp = VN - TP;
        for (int idx = g; idx < 2*TP*32; idx += 512) {
            int rs = idx >> 9, j = idx & 511, t = j >> 5, c4 = j & 31;
            *(float4*)&x[((long)(a0 + rs*256)*VN + pp + t)*HN + c4*4] =
                *(const float4*)&hOut[rs][t][c4*4];
        }
    }
}

extern "C" void kernel_launch(void* const* d_in, const int* in_sizes, int n_in,
                              void* d_out, int out_size, void* d_ws, size_t ws_size,
                              hipStream_t stream) {
    const float* adj   = (const float*)d_in[0];
    const void*  edges = d_in[1];
    const float* emb   = (const float*)d_in[2];
    const float* w1    = (const float*)d_in[3];
    const float* w2    = (const float*)d_in[4];
    const float* w3    = (const float*)d_in[5];
    const float* wih   = (const float*)d_in[6];
    const float* whh   = (const float*)d_in[7];
    const float* bih   = (const float*)d_in[8];
    const float* bhh   = (const float*)d_in[9];

    float* x = (float*)d_out;          // x lives in d_out; scan updates it in place

    char* p = (char*)d_ws;
    auto alloc = [&](size_t bytes) { char* r = p; p += (bytes + 255) & ~255UL; return r; };
    float* in3    = (float*)alloc((size_t)EN*G3*4);
    float* corr   = (float*)alloc((size_t)EN*G3*4);
    float* colsum = (float*)alloc((size_t)VN*HN*4);
    int*   nnz    = (int*)  alloc((size_t)VN*4);
    int*   map    = (int*)  alloc((size_t)NROWS*4);
    int*   uA     = (int*)  alloc((size_t)EN*4);
    int*   vA     = (int*)  alloc((size_t)EN*4);
    unsigned short* wsBh = (unsigned short*)alloc((size_t)24*4*64*8*2);
    unsigned short* wsBl = (unsigned short*)alloc((size_t)24*4*64*8*2);
    unsigned short* whBh = (unsigned short*)alloc((size_t)24*4*64*8*2);
    unsigned short* whBl = (unsigned short*)alloc((size_t)24*4*64*8*2);
    unsigned short* wlBh = (unsigned short*)alloc((size_t)24*4*64*8*2);
    unsigned short* wlBl = (unsigned short*)alloc((size_t)24*4*64*8*2);
    unsigned short* wcBh = (unsigned short*)alloc((size_t)3*8*12*64*8*2);
    unsigned short* wcBl = (unsigned short*)alloc((size_t)3*8*12*64*8*2);

    k_edges<<<EN/256, 256, 0, stream>>>(edges, uA, vA);
    k_pack<<<(3*8*12*64*8 + 255)/256, 256, 0, stream>>>(w1, w2, w3, wih, whh,
        wsBh, wsBl, whBh, whBl, wlBh, wlBl, wcBh, wcBl);
    k_fill<<<NROWS/256, 256, 0, stream>>>(map, -1, NROWS);
    k_map<<<EN/256, 256, 0, stream>>>(uA, vA, map);
    k_embed<<<NROWS/2, 256, 0, stream>>>(adj, emb, x);

    for (int l = 0; l < LN; l++) {
        k_colsum<<<VN, 512, 0, stream>>>(x, colsum, nnz);
        k_edgein<<<EN/4, 256, 0, stream>>>(x, uA, vA, colsum, nnz, in3);
        k_msgcorr<<<EN/16, 512, 0, stream>>>(in3, wcBh + (long)l*8*12*64*8, wcBl + (long)l*8*12*64*8,
                                             wlBh, wlBl, corr);
        k_scanf<<<VN/2, 512, 0, stream>>>(x, wsBh, wsBl, whBh, whBl, bih, bhh, corr, map);
    }
}

// Round 11
// 1836.567 us; speedup vs baseline: 22.5756x; 1.2916x over previous
//
#include <hip/hip_runtime.h>

#define VN 512
#define EN 32768
#define FN 8
#define HN 128
#define G3 384
#define LN 3
#define TP 16
#define NROWS (VN*VN)   // 262144
#define XIPAD 388       // 4*388 % 32 == 16 -> 2-way LDS aliasing (free)

typedef _Float16 f16x8 __attribute__((ext_vector_type(8)));
typedef float f32x4  __attribute__((ext_vector_type(4)));

__device__ __forceinline__ unsigned short f2h(float f) {
    _Float16 h = (_Float16)f;
    return __builtin_bit_cast(unsigned short, h);
}
__device__ __forceinline__ float h2f(unsigned short u) {
    return (float)__builtin_bit_cast(_Float16, u);
}
__device__ __forceinline__ float fexp2(float x) {
    float r; asm("v_exp_f32 %0, %1" : "=v"(r) : "v"(x)); return r;
}
__device__ __forceinline__ float frcp(float x) {
    float r; asm("v_rcp_f32 %0, %1" : "=v"(r) : "v"(x)); return r;
}
__device__ __forceinline__ float fsigmoid(float x) {
    return frcp(1.f + fexp2(x * -1.44269504089f));
}
__device__ __forceinline__ float ftanh(float x) {
    return 1.f - 2.f * frcp(1.f + fexp2(x * 2.88539008178f));
}

// ---------------- generic int fill ----------------
__global__ void k_fill(int* __restrict__ p, int val, int n) {
    int i = blockIdx.x * 256 + threadIdx.x;
    if (i < n) p[i] = val;
}

// ---------------- edge canonicalize (+ int64 detection) ----------------
__global__ void k_edges(const void* __restrict__ raw, int* __restrict__ uo, int* __restrict__ vo) {
    const int* r32 = (const int*)raw;
    const long long* r64 = (const long long*)raw;
    int acc = 0;
    #pragma unroll
    for (int i = 1; i < 128; i += 2) acc |= r32[i];
    bool is64 = (acc == 0);
    int e = blockIdx.x * 256 + threadIdx.x;
    if (e < EN) {
        int u, v;
        if (is64) { u = (int)r64[2*e]; v = (int)r64[2*e+1]; }
        else      { u = r32[2*e];      v = r32[2*e+1]; }
        uo[e] = u; vo[e] = v;
    }
}

// ---------------- pack weight B-fragments (single f16, MFMA lane layout) ----------------
// frag layout: [..ntile..][ktile][lane][elem]: k = kt*32 + (lane>>4)*8 + e ; col = nt*16 + (lane&15)
__global__ void k_pack(const float* __restrict__ w1, const float* __restrict__ w2,
                       const float* __restrict__ w3, const float* __restrict__ wih,
                       const float* __restrict__ whh,
                       unsigned short* __restrict__ wsF, unsigned short* __restrict__ whF,
                       unsigned short* __restrict__ wlF, unsigned short* __restrict__ wcF) {
    int t = blockIdx.x * 256 + threadIdx.x;
    if (t < 3*8*12*64*8) {        // wcat frags [l][nt0..7][kt0..11]
        int e = t & 7, lane = (t >> 3) & 63;
        int frag = t >> 9;
        int kt = frag % 12;
        int rem = frag / 12;
        int nt = rem & 7;
        int l  = rem >> 3;
        int k  = kt*32 + (lane >> 4)*8 + e;
        int gc = nt*16 + (lane & 15);
        const float* w = (k < 128) ? w1 : (k < 256 ? w2 : w3);
        wcF[t] = f2h(w[((long)l*128 + gc)*128 + (k & 127)]);
    }
    if (t < 24*4*64*8) {          // wsum / whh / wl frags [nt0..23][kt0..3]
        int e = t & 7, lane = (t >> 3) & 63, kt = (t >> 9) & 3, nt = t >> 11;
        int k  = kt*32 + (lane >> 4)*8 + e;
        int gc = nt*16 + (lane & 15);
        wsF[t] = f2h(wih[gc*256 + k] + wih[gc*256 + 128 + k]);
        whF[t] = f2h(whh[gc*HN + k]);
        wlF[t] = f2h(wih[gc*256 + k]);
    }
}

// ---------------- winner map ----------------
__global__ void k_map(const int* __restrict__ uA, const int* __restrict__ vA, int* __restrict__ map) {
    int e = blockIdx.x * 256 + threadIdx.x;
    if (e < EN) atomicMax(&map[uA[e]*VN + vA[e]], e);
}

// ---------------- embed ----------------
__global__ __launch_bounds__(256) void k_embed(const float* __restrict__ adj,
                                               const float* __restrict__ emb,
                                               float* __restrict__ x) {
    __shared__ float semb[HN][FN];
    __shared__ float sadj[2][FN];
    int tid = threadIdx.x;
    for (int i = tid; i < HN*FN; i += 256) semb[i/FN][i%FN] = emb[i];
    if (tid < 16) sadj[tid>>3][tid&7] = adj[(long)blockIdx.x*16 + tid];
    __syncthreads();
    int p = tid >> 7;
    int h = tid & 127;
    float acc = 0.f;
    #pragma unroll
    for (int f = 0; f < FN; f++) acc += sadj[p][f]*semb[h][f];
    long row = (long)blockIdx.x*2 + p;
    x[row*HN + h] = acc;
}

// ---------------- colsum + nnz ----------------
__global__ __launch_bounds__(512) void k_colsum(const float* __restrict__ x,
                                                float* __restrict__ colsum, int* __restrict__ nnz) {
    int b = blockIdx.x;
    int tid = threadIdx.x;
    int h = tid & 127, q = tid >> 7;
    float s = 0.f; int c = 0;
    for (int a = q*128; a < q*128 + 128; a++) {
        float v = x[((long)a*VN + b)*HN + h];
        s += v; c += (v != 0.f) ? 1 : 0;
    }
    __shared__ float ss[4][128];
    __shared__ int sc[8];
    ss[q][h] = s;
    #pragma unroll
    for (int off = 32; off; off >>= 1) c += __shfl_down(c, off);
    if ((tid & 63) == 0) sc[tid>>6] = c;
    __syncthreads();
    if (tid < 128) colsum[b*HN + tid] = ss[0][tid]+ss[1][tid]+ss[2][tid]+ss[3][tid];
    if (tid == 0) { int t = 0; for (int i = 0; i < 8; i++) t += sc[i]; nnz[b] = t; }
}

// ---------------- edge inputs ----------------
__global__ __launch_bounds__(256) void k_edgein(const float* __restrict__ x,
    const int* __restrict__ uA, const int* __restrict__ vA,
    const float* __restrict__ colsum, const int* __restrict__ nnz, float* __restrict__ in3) {
    int w = threadIdx.x >> 6;
    int lane = threadIdx.x & 63;
    int e = blockIdx.x*4 + w;
    int u = uA[e], v = vA[e];
    const float* xuv = x + ((long)u*VN + v)*HN;
    const float* xvu = x + ((long)v*VN + u)*HN;
    float xu0 = xuv[lane], xu1 = xuv[lane+64];
    float xv0 = xvu[lane], xv1 = xvu[lane+64];
    int cnt_vu = __popcll(__ballot(xv0 != 0.f)) + __popcll(__ballot(xv1 != 0.f));
    int cnt_uv = __popcll(__ballot(xu0 != 0.f)) + __popcll(__ballot(xu1 != 0.f));
    float nin  = (float)(nnz[u] - cnt_vu) * (1.f/128.f); if (nin  == 0.f) nin  = 1.f;
    float nout = (float)(nnz[v] - cnt_uv) * (1.f/128.f); if (nout == 0.f) nout = 1.f;
    float* o = in3 + (long)e*G3;
    o[lane]        = xu0;  o[lane+64]      = xu1;
    o[128+lane]    = (colsum[u*HN+lane]    - xv0)/nin;
    o[128+lane+64] = (colsum[u*HN+lane+64] - xv1)/nin;
    o[256+lane]    = (colsum[v*HN+lane]    - xu0)/nout;
    o[256+lane+64] = (colsum[v*HN+lane+64] - xu1)/nout;
}

#define MF16(A,B,C) __builtin_amdgcn_mfma_f32_16x16x32_f16((A),(B),(C),0,0,0)
#define Z4 ((f32x4){0.f,0.f,0.f,0.f})

// ---------------- fused msg+corr (f16 MFMA) ----------------
__global__ __launch_bounds__(512) void k_msgcorr(
    const float* __restrict__ in3,
    const unsigned short* __restrict__ wcF, const unsigned short* __restrict__ wlF,
    float* __restrict__ corr) {
    const int g = threadIdx.x;
    const int wv = g >> 6;
    const int lane = g & 63;
    const int r16 = lane & 15;
    const int kgrp = lane >> 4;
    const long m0 = (long)blockIdx.x * 16;

    __shared__ unsigned short Dh[16][136];
    __shared__ unsigned short Dl[16][136];

    f32x4 pacc[2];
    pacc[0] = Z4; pacc[1] = Z4;
    #pragma unroll
    for (int kt = 0; kt < 12; kt++) {
        const float* xs = &in3[(m0 + r16)*G3 + kt*32 + kgrp*8];
        float4 v0 = *(const float4*)xs;
        float4 v1 = *(const float4*)(xs + 4);
        float vv[8] = {v0.x,v0.y,v0.z,v0.w,v1.x,v1.y,v1.z,v1.w};
        f16x8 H, L;
        #pragma unroll
        for (int j = 0; j < 8; j++) {
            _Float16 h = (_Float16)vv[j];
            H[j] = h;
            L[j] = (_Float16)(vv[j] - (float)h);
        }
        f16x8 bF = *(const f16x8*)&wcF[(((long)wv*12 + kt)*64 + lane)*8];
        const int p = kt & 1;
        pacc[p] = MF16(H, bF, pacc[p]);
        pacc[p] = MF16(L, bF, pacc[p]);
    }
    const int c = wv*16 + r16;
    #pragma unroll
    for (int r = 0; r < 4; r++) {
        int m = kgrp*4 + r;
        float mv = fmaxf(pacc[0][r] + pacc[1][r], 0.f) - in3[(m0 + m)*G3 + c];
        unsigned short hi = f2h(mv);
        Dh[m][c] = hi;
        Dl[m][c] = f2h(mv - h2f(hi));
    }
    __syncthreads();

    f32x4 cacc[3];
    cacc[0] = cacc[1] = cacc[2] = Z4;
    #pragma unroll
    for (int kt = 0; kt < 4; kt++) {
        f16x8 ah = *(const f16x8*)&Dh[r16][kt*32 + kgrp*8];
        f16x8 al = *(const f16x8*)&Dl[r16][kt*32 + kgrp*8];
        #pragma unroll
        for (int j = 0; j < 3; j++) {
            f16x8 bF = *(const f16x8*)&wlF[(((long)(wv*3 + j)*4 + kt)*64 + lane)*8];
            cacc[j] = MF16(ah, bF, cacc[j]);
            cacc[j] = MF16(al, bF, cacc[j]);
        }
    }
    #pragma unroll
    for (int j = 0; j < 3; j++) {
        int n = (wv*3 + j)*16 + r16;
        #pragma unroll
        for (int r = 0; r < 4; r++)
            corr[(m0 + kgrp*4 + r)*G3 + n] = cacc[j][r];
    }
}

// ================= fused xi(f16 MFMA) + GRU scan (v9) =================
// 256 blocks x 512 threads (8 waves); block owns chains {a0, a0+256}.
// f16 2-term split (A hi/lo, B single) -> 24 gh MFMA/wave/step (was 36).
// wsum AND whh B-frags resident in VGPRs -> steps have ZERO vmem.
// 4-bit XOR swizzle on x panel (slot = col8 ^ r16) -> conflict-free A reads.
// Single-buffered xiP/xS (XI_STORE in phase A) -> LDS 85 KB.

// stage x rows [ROWBASE, ROWBASE+16) of both chains into xS (f16 hi/lo, swizzled)
#define STAGE(ROWBASE) do { \
    int rs_ = g >> 8, row_ = (g >> 4) & 15, cg_ = g & 15; \
    const float* xs_ = &x[((long)(a0 + rs_*256)*VN + (ROWBASE) + row_)*HN + cg_*8]; \
    float4 v0_ = *(const float4*)xs_; \
    float4 v1_ = *(const float4*)(xs_ + 4); \
    float vv_[8] = {v0_.x,v0_.y,v0_.z,v0_.w,v1_.x,v1_.y,v1_.z,v1_.w}; \
    f16x8 H_, L_; \
    _Pragma("unroll") \
    for (int j_ = 0; j_ < 8; ++j_) { \
        _Float16 h_ = (_Float16)vv_[j_]; \
        H_[j_] = h_; \
        L_[j_] = (_Float16)(vv_[j_] - (float)h_); \
    } \
    int slot_ = cg_ ^ row_; \
    *(f16x8*)&xSh[rs_][row_][slot_*8] = H_; \
    *(f16x8*)&xSl[rs_][row_][slot_*8] = L_; \
} while(0)

// one xi sub-GEMM item: A-frag from swizzled LDS, B-frag resident VGPR. 2 MFMA.
#define XI_ITEM(RS, GI, KT) do { \
    int slot_ = ((KT)*4 + kgrp) ^ r16; \
    f16x8 H_ = *(const f16x8*)&xSh[RS][r16][slot_*8]; \
    f16x8 L_ = *(const f16x8*)&xSl[RS][r16][slot_*8]; \
    xacc##RS##GI = MF16(H_, wS[(GI)*4 + (KT)], xacc##RS##GI); \
    xacc##RS##GI = MF16(L_, wS[(GI)*4 + (KT)], xacc##RS##GI); \
} while(0)

#define XI_STORE() do { \
    _Pragma("unroll") \
    for (int r_ = 0; r_ < 4; ++r_) { \
        xiP[0][kgrp*4 + r_][c]        = xacc00[r_] + biR; \
        xiP[0][kgrp*4 + r_][HN + c]   = xacc01[r_] + biZ; \
        xiP[0][kgrp*4 + r_][2*HN + c] = xacc02[r_] + biN; \
        xiP[1][kgrp*4 + r_][c]        = xacc10[r_] + biR; \
        xiP[1][kgrp*4 + r_][HN + c]   = xacc11[r_] + biZ; \
        xiP[1][kgrp*4 + r_][2*HN + c] = xacc12[r_] + biN; \
    } \
    xacc00 = Z4; xacc01 = Z4; xacc02 = Z4; \
    xacc10 = Z4; xacc11 = Z4; xacc12 = Z4; \
} while(0)

#define CORR_ADD() do { if (g < G3) { \
    for (int rs_ = 0; rs_ < 2; ++rs_) \
        for (int t_ = 0; t_ < TP; ++t_) { \
            int e_ = eS[rs_][t_]; \
            if (e_ >= 0) xiP[rs_][t_][g] += corr[(long)e_*G3 + g]; \
        } } } while(0)

#define STEP(T, ...) do { \
    const int arow_ = r16 & 1; \
    f16x8 hA0_ = *(const f16x8*)&hSh[cur][arow_][0*32 + kgrp*8]; \
    f16x8 lA0_ = *(const f16x8*)&hSl[cur][arow_][0*32 + kgrp*8]; \
    f16x8 hA1_ = *(const f16x8*)&hSh[cur][arow_][1*32 + kgrp*8]; \
    f16x8 lA1_ = *(const f16x8*)&hSl[cur][arow_][1*32 + kgrp*8]; \
    f16x8 hA2_ = *(const f16x8*)&hSh[cur][arow_][2*32 + kgrp*8]; \
    f16x8 lA2_ = *(const f16x8*)&hSl[cur][arow_][2*32 + kgrp*8]; \
    f16x8 hA3_ = *(const f16x8*)&hSh[cur][arow_][3*32 + kgrp*8]; \
    f16x8 lA3_ = *(const f16x8*)&hSl[cur][arow_][3*32 + kgrp*8]; \
    f32x4 gr0_ = Z4, gr1_ = Z4, gz0_ = Z4, gz1_ = Z4, gn0_ = Z4, gn1_ = Z4; \
    __builtin_amdgcn_s_setprio(1); \
    gr0_ = MF16(hA0_, wH[0], gr0_);  gr0_ = MF16(lA0_, wH[0], gr0_); \
    gr1_ = MF16(hA1_, wH[1], gr1_);  gr1_ = MF16(lA1_, wH[1], gr1_); \
    gr0_ = MF16(hA2_, wH[2], gr0_);  gr0_ = MF16(lA2_, wH[2], gr0_); \
    gr1_ = MF16(hA3_, wH[3], gr1_);  gr1_ = MF16(lA3_, wH[3], gr1_); \
    gz0_ = MF16(hA0_, wH[4], gz0_);  gz0_ = MF16(lA0_, wH[4], gz0_); \
    gz1_ = MF16(hA1_, wH[5], gz1_);  gz1_ = MF16(lA1_, wH[5], gz1_); \
    gz0_ = MF16(hA2_, wH[6], gz0_);  gz0_ = MF16(lA2_, wH[6], gz0_); \
    gz1_ = MF16(hA3_, wH[7], gz1_);  gz1_ = MF16(lA3_, wH[7], gz1_); \
    gn0_ = MF16(hA0_, wH[8], gn0_);  gn0_ = MF16(lA0_, wH[8], gn0_); \
    gn1_ = MF16(hA1_, wH[9], gn1_);  gn1_ = MF16(lA1_, wH[9], gn1_); \
    gn0_ = MF16(hA2_, wH[10], gn0_); gn0_ = MF16(lA2_, wH[10], gn0_); \
    gn1_ = MF16(hA3_, wH[11], gn1_); gn1_ = MF16(lA3_, wH[11], gn1_); \
    __builtin_amdgcn_s_setprio(0); \
    __VA_ARGS__ \
    float sR_ = gr0_[0] + gr1_[0], tR_ = gr0_[1] + gr1_[1]; \
    float sZ_ = gz0_[0] + gz1_[0], tZ_ = gz0_[1] + gz1_[1]; \
    float sN_ = gn0_[0] + gn1_[0], tN_ = gn0_[1] + gn1_[1]; \
    int ba_ = (lane & 15) << 2; \
    float mR_ = __int_as_float(__builtin_amdgcn_ds_bpermute(ba_, __float_as_int(tR_))); \
    float mZ_ = __int_as_float(__builtin_amdgcn_ds_bpermute(ba_, __float_as_int(tZ_))); \
    float mN_ = __int_as_float(__builtin_amdgcn_ds_bpermute(ba_, __float_as_int(tN_))); \
    float vR_ = (lane < 16) ? sR_ : mR_; \
    float vZ_ = (lane < 16) ? sZ_ : mZ_; \
    float vN_ = (lane < 16) ? sN_ : mN_; \
    if (lane < 32) { \
        int rs_ = lane >> 4; \
        float xr_ = xiP[rs_][T][c]; \
        float xz_ = xiP[rs_][T][HN + c]; \
        float xn_ = xiP[rs_][T][2*HN + c]; \
        float r_ = fsigmoid(xr_ + vR_ + br); \
        float z_ = fsigmoid(xz_ + vZ_ + bz); \
        float n_ = ftanh(xn_ + r_*(vN_ + bn)); \
        float h_ = (1.f - z_)*n_ + z_*hprev; \
        hprev = h_; \
        hOut[rs_][T][c] = h_; \
        unsigned short uh_ = f2h(h_); \
        hSh[cur ^ 1][rs_][c] = uh_; \
        hSl[cur ^ 1][rs_][c] = f2h(h_ - h2f(uh_)); \
    } \
    cur ^= 1; \
    __syncthreads(); \
} while(0)

__global__ __launch_bounds__(512) void k_scanf(
    float* __restrict__ x,
    const unsigned short* __restrict__ wsF, const unsigned short* __restrict__ whF,
    const float* __restrict__ bih, const float* __restrict__ bhh,
    const float* __restrict__ corr, const int* __restrict__ map) {
    const int g = threadIdx.x;
    const int a0 = blockIdx.x;
    const int wv = g >> 6;
    const int lane = g & 63;
    const int r16 = lane & 15;
    const int kgrp = lane >> 4;

    __shared__ float xiP[2][TP][XIPAD];             // 49.7 KB (single buffer)
    __shared__ unsigned short xSh[2][TP][HN];       // 8 KB (chain, row, swz col)
    __shared__ unsigned short xSl[2][TP][HN];       // 8 KB
    __shared__ unsigned short hSh[2][2][HN];        // [parity][chain][col]
    __shared__ unsigned short hSl[2][2][HN];
    __shared__ float hOut[2][TP][HN];               // 16 KB
    __shared__ int eS[2][TP];

    // resident B-frags (single f16): whh wH[12], wsum wS[12] -> 96 VGPRs
    f16x8 wH[12], wS[12];
    #pragma unroll
    for (int gi = 0; gi < 3; gi++)
        #pragma unroll
        for (int kt = 0; kt < 4; kt++) {
            long bidx = (((long)(gi*8 + wv)*4 + kt)*64 + lane)*8;
            wH[gi*4+kt] = *(const f16x8*)&whF[bidx];
            wS[gi*4+kt] = *(const f16x8*)&wsF[bidx];
        }

    const int c = wv*16 + r16;
    const float br = bhh[c],  bz = bhh[HN + c],  bn = bhh[2*HN + c];
    const float biR = bih[c], biZ = bih[HN + c], biN = bih[2*HN + c];
    float hprev = 0.f;                  // lanes<32: chain (lane>>4)

    f32x4 xacc00 = Z4, xacc01 = Z4, xacc02 = Z4;
    f32x4 xacc10 = Z4, xacc11 = Z4, xacc12 = Z4;

    if (g < 2*HN) {
        ((unsigned short*)hSh)[g] = 0;
        ((unsigned short*)hSl)[g] = 0;
    }
    int cur = 0;

    // ---- prologue: stage panel 0, compute + store xi(0) ----
    STAGE(0);
    __syncthreads();
    XI_ITEM(0,0,0); XI_ITEM(0,0,1); XI_ITEM(0,0,2); XI_ITEM(0,0,3);
    XI_ITEM(0,1,0); XI_ITEM(0,1,1); XI_ITEM(0,1,2); XI_ITEM(0,1,3);
    XI_ITEM(0,2,0); XI_ITEM(0,2,1); XI_ITEM(0,2,2); XI_ITEM(0,2,3);
    XI_ITEM(1,0,0); XI_ITEM(1,0,1); XI_ITEM(1,0,2); XI_ITEM(1,0,3);
    XI_ITEM(1,1,0); XI_ITEM(1,1,1); XI_ITEM(1,1,2); XI_ITEM(1,1,3);
    XI_ITEM(1,2,0); XI_ITEM(1,2,1); XI_ITEM(1,2,2); XI_ITEM(1,2,3);
    XI_STORE();
    __syncthreads();

    for (int p0 = 0; p0 < VN; p0 += TP) {
        const bool hasnext = (p0 + TP) < VN;

        // ---- phase A region 1: writeback(p-1), XI_STORE(p) [p>0], eS(p), stage x(p+1) ----
        if (p0 > 0) {
            int pp = p0 - TP;
            for (int idx = g; idx < 2*TP*32; idx += 512) {
                int rs = idx >> 9, j = idx & 511, t = j >> 5, c4 = j & 31;
                *(float4*)&x[((long)(a0 + rs*256)*VN + pp + t)*HN + c4*4] =
                    *(const float4*)&hOut[rs][t][c4*4];
            }
            XI_STORE();     // xi(p), accumulated during panel p-1's steps
        }
        if (g < 32) eS[g >> 4][g & 15] = map[(long)(a0 + (g >> 4)*256)*VN + p0 + (g & 15)];
        if (hasnext) STAGE(p0 + TP);
        __syncthreads();

        // ---- phase A region 2: corr gather into xiP(p) ----
        CORR_ADD();
        __syncthreads();

        // ---- 16 gate steps (pure LDS/MFMA/VALU), xi(p+1) interleaved ----
        STEP(0,  if (hasnext) { XI_ITEM(0,0,0); XI_ITEM(0,0,1); } );
        STEP(1,  if (hasnext) { XI_ITEM(0,0,2); } );
        STEP(2,  if (hasnext) { XI_ITEM(0,0,3); XI_ITEM(0,1,0); } );
        STEP(3,  if (hasnext) { XI_ITEM(0,1,1); } );
        STEP(4,  if (hasnext) { XI_ITEM(0,1,2); XI_ITEM(0,1,3); } );
        STEP(5,  if (hasnext) { XI_ITEM(0,2,0); } );
        STEP(6,  if (hasnext) { XI_ITEM(0,2,1); XI_ITEM(0,2,2); } );
        STEP(7,  if (hasnext) { XI_ITEM(0,2,3); } );
        STEP(8,  if (hasnext) { XI_ITEM(1,0,0); XI_ITEM(1,0,1); } );
        STEP(9,  if (hasnext) { XI_ITEM(1,0,2); } );
        STEP(10, if (hasnext) { XI_ITEM(1,0,3); XI_ITEM(1,1,0); } );
        STEP(11, if (hasnext) { XI_ITEM(1,1,1); } );
        STEP(12, if (hasnext) { XI_ITEM(1,1,2); XI_ITEM(1,1,3); } );
        STEP(13, if (hasnext) { XI_ITEM(1,2,0); } );
        STEP(14, if (hasnext) { XI_ITEM(1,2,1); XI_ITEM(1,2,2); } );
        STEP(15, if (hasnext) { XI_ITEM(1,2,3); } );
    }
    // ---- final write-back ----
    {
        int pp = VN - TP;
        for (int idx = g; idx < 2*TP*32; idx += 512) {
            int rs = idx >> 9, j = idx & 511, t = j >> 5, c4 = j & 31;
            *(float4*)&x[((long)(a0 + rs*256)*VN + pp + t)*HN + c4*4] =
                *(const float4*)&hOut[rs][t][c4*4];
        }
    }
}

extern "C" void kernel_launch(void* const* d_in, const int* in_sizes, int n_in,
                              void* d_out, int out_size, void* d_ws, size_t ws_size,
                              hipStream_t stream) {
    const float* adj   = (const float*)d_in[0];
    const void*  edges = d_in[1];
    const float* emb   = (const float*)d_in[2];
    const float* w1    = (const float*)d_in[3];
    const float* w2    = (const float*)d_in[4];
    const float* w3    = (const float*)d_in[5];
    const float* wih   = (const float*)d_in[6];
    const float* whh   = (const float*)d_in[7];
    const float* bih   = (const float*)d_in[8];
    const float* bhh   = (const float*)d_in[9];

    float* x = (float*)d_out;          // x lives in d_out; scan updates it in place

    char* p = (char*)d_ws;
    auto alloc = [&](size_t bytes) { char* r = p; p += (bytes + 255) & ~255UL; return r; };
    float* in3    = (float*)alloc((size_t)EN*G3*4);
    float* corr   = (float*)alloc((size_t)EN*G3*4);
    float* colsum = (float*)alloc((size_t)VN*HN*4);
    int*   nnz    = (int*)  alloc((size_t)VN*4);
    int*   map    = (int*)  alloc((size_t)NROWS*4);
    int*   uA     = (int*)  alloc((size_t)EN*4);
    int*   vA     = (int*)  alloc((size_t)EN*4);
    unsigned short* wsF = (unsigned short*)alloc((size_t)24*4*64*8*2);
    unsigned short* whF = (unsigned short*)alloc((size_t)24*4*64*8*2);
    unsigned short* wlF = (unsigned short*)alloc((size_t)24*4*64*8*2);
    unsigned short* wcF = (unsigned short*)alloc((size_t)3*8*12*64*8*2);

    k_edges<<<EN/256, 256, 0, stream>>>(edges, uA, vA);
    k_pack<<<(3*8*12*64*8 + 255)/256, 256, 0, stream>>>(w1, w2, w3, wih, whh,
        wsF, whF, wlF, wcF);
    k_fill<<<NROWS/256, 256, 0, stream>>>(map, -1, NROWS);
    k_map<<<EN/256, 256, 0, stream>>>(uA, vA, map);
    k_embed<<<NROWS/2, 256, 0, stream>>>(adj, emb, x);

    for (int l = 0; l < LN; l++) {
        k_colsum<<<VN, 512, 0, stream>>>(x, colsum, nnz);
        k_edgein<<<EN/4, 256, 0, stream>>>(x, uA, vA, colsum, nnz, in3);
        k_msgcorr<<<EN/16, 512, 0, stream>>>(in3, wcF + (long)l*8*12*64*8, wlF, corr);
        k_scanf<<<VN/2, 512, 0, stream>>>(x, wsF, whF, bih, bhh, corr, map);
    }
}